// Round 10
// baseline (371.960 us; speedup 1.0000x reference)
//
#include <hip/hip_runtime.h>
#include <hip/hip_bf16.h>

// ---------------- problem constants ----------------
constexpr int Bg  = 8;       // graphs
constexpr int Nn  = 1024;    // nodes per graph
constexpr int Cc  = 256;     // channels
constexpr int Hh  = 8;       // heads
constexpr int DKh = 32;      // head dim
constexpr int Ee  = 131072;  // edges
constexpr int BNn = Bg * Nn; // 8192 total nodes
#define EPSV 1e-5f

typedef __attribute__((ext_vector_type(8))) short bf16x8;
typedef __attribute__((ext_vector_type(4))) float f32x4;

static __device__ __forceinline__ unsigned short f2b(float v) {
    __hip_bfloat16 h = __float2bfloat16(v);
    return __builtin_bit_cast(unsigned short, h);
}
static __device__ __forceinline__ float b2f(unsigned short u) {
    unsigned int x = ((unsigned int)u) << 16;
    return __builtin_bit_cast(float, x);
}
static __device__ __forceinline__ bf16x8 ldb8(const unsigned short* p) {
    return *(const bf16x8*)p;
}

// ---------------- fused prep: xconv + wconv + hist ----------------
__global__ __launch_bounds__(256) void prep_k(
    const float* __restrict__ x, unsigned short* __restrict__ xcat,
    const float* __restrict__ Wr, const float* __restrict__ Wn,
    const float* __restrict__ Wq, const float* __restrict__ Wk,
    const float* __restrict__ Wv, const float* __restrict__ Wo,
    const float* __restrict__ W1, const float* __restrict__ W2,
    unsigned short* __restrict__ WcatT,
    unsigned short* __restrict__ WqT, unsigned short* __restrict__ WkT,
    unsigned short* __restrict__ WvT, unsigned short* __restrict__ WoT,
    unsigned short* __restrict__ W1T, unsigned short* __restrict__ W2T,
    const int* __restrict__ ei, int* __restrict__ deg)
{
    int blk = blockIdx.x;
    if (blk < 2048) {
        int i = (blk * 256 + threadIdx.x) * 4;
        float4 v = *(const float4*)(x + i);
        int r = i >> 8, c = i & 255;
        ushort4 pk;
        pk.x = f2b(v.x); pk.y = f2b(v.y); pk.z = f2b(v.z); pk.w = f2b(v.w);
        *(ushort4*)(xcat + (size_t)r * 512 + c) = pk;
    } else if (blk < 4608) {
        int idx = (blk - 2048) * 256 + threadIdx.x;
        if (idx < 131072) {                      // WcatT [256][512]
            int n = idx >> 9, k = idx & 511;
            float v = (k < 256) ? Wr[k * 256 + n] : Wn[(k - 256) * 256 + n];
            WcatT[(size_t)n * 512 + k] = f2b(v);
        } else if (idx < 393216) {               // q,k,v,o
            int l = idx - 131072;
            int wsel = l >> 16; l &= 65535;
            int n = l >> 8, kk = l & 255;
            const float* S = wsel == 0 ? Wq : wsel == 1 ? Wk : wsel == 2 ? Wv : Wo;
            unsigned short* D = wsel == 0 ? WqT : wsel == 1 ? WkT : wsel == 2 ? WvT : WoT;
            D[n * 256 + kk] = f2b(S[kk * 256 + n]);
        } else if (idx < 524288) {               // W1 [256][512] -> W1T [512][256]
            int l = idx - 393216;
            int n = l >> 8, kk = l & 255;
            W1T[l] = f2b(W1[kk * 512 + n]);
        } else {                                 // W2 [512][256] -> W2T [256][512]
            int l = idx - 524288;
            int n = l >> 9, kk = l & 511;
            W2T[l] = f2b(W2[kk * 256 + n]);
        }
    } else {
        int e = (blk - 4608) * 256 + threadIdx.x;
        atomicAdd(&deg[ei[Ee + e]], 1);
    }
}

// ---------------- CSR scan (coalesced, interleaved buckets) ----------------
__global__ __launch_bounds__(256) void scan_k(
    const int* __restrict__ deg, int* __restrict__ rowst, int* __restrict__ cursor)
{
    __shared__ int partial[256];
    int t = threadIdx.x;
    int local[32];
    int s = 0;
    #pragma unroll
    for (int i = 0; i < 32; ++i) { local[i] = deg[i * 256 + t]; s += local[i]; }
    partial[t] = s;
    __syncthreads();
    for (int off = 1; off < 256; off <<= 1) {
        int v = (t >= off) ? partial[t - off] : 0;
        __syncthreads();
        partial[t] += v;
        __syncthreads();
    }
    int base = partial[t] - s;
    #pragma unroll
    for (int i = 0; i < 32; ++i) {
        int n = i * 256 + t;
        rowst[n] = base;
        cursor[n] = base;
        base += local[i];
    }
}

__global__ __launch_bounds__(256) void place_k(
    const int* __restrict__ ei, int* __restrict__ cursor, int* __restrict__ eidx)
{
    int e = blockIdx.x * 256 + threadIdx.x;
    int s = ei[e], d = ei[Ee + e];
    int pos = atomicAdd(&cursor[d], 1);
    eidx[pos] = s;
}

// ---------------- merged gather (blocks 0..2047) + QKV GEMM (2048..5119) ----------------
__global__ __launch_bounds__(256, 4) void gather_qkv_k(
    const float* __restrict__ x, const int* __restrict__ rowst,
    const int* __restrict__ deg, const int* __restrict__ eidx,
    unsigned short* __restrict__ xcat,
    const unsigned short* __restrict__ WT,
    const float* __restrict__ bq, const float* __restrict__ bk,
    const float* __restrict__ bv,
    unsigned short* __restrict__ qb, unsigned short* __restrict__ kb,
    unsigned short* __restrict__ vTb, float qscale)
{
    __shared__ unsigned short vtile[64][40];
    int blk = blockIdx.x;

    if (blk < 2048) {
        // gather: 4 nodes per block, one 64-lane wave each
        int n = blk * 4 + (threadIdx.x >> 6);
        int c4 = (threadIdx.x & 63) * 4;
        int b0 = rowst[n], d = deg[n];
        float4 acc = {0.f, 0.f, 0.f, 0.f};
        int i = 0;
        for (; i + 4 <= d; i += 4) {
            int s0 = eidx[b0 + i], s1 = eidx[b0 + i + 1];
            int s2 = eidx[b0 + i + 2], s3 = eidx[b0 + i + 3];
            float4 a0 = *(const float4*)(x + (size_t)s0 * Cc + c4);
            float4 a1 = *(const float4*)(x + (size_t)s1 * Cc + c4);
            float4 a2 = *(const float4*)(x + (size_t)s2 * Cc + c4);
            float4 a3 = *(const float4*)(x + (size_t)s3 * Cc + c4);
            acc.x += (a0.x + a1.x) + (a2.x + a3.x);
            acc.y += (a0.y + a1.y) + (a2.y + a3.y);
            acc.z += (a0.z + a1.z) + (a2.z + a3.z);
            acc.w += (a0.w + a1.w) + (a2.w + a3.w);
        }
        for (; i < d; ++i) {
            int s = eidx[b0 + i];
            float4 a = *(const float4*)(x + (size_t)s * Cc + c4);
            acc.x += a.x; acc.y += a.y; acc.z += a.z; acc.w += a.w;
        }
        ushort4 pk;
        pk.x = f2b(acc.x); pk.y = f2b(acc.y); pk.z = f2b(acc.z); pk.w = f2b(acc.w);
        *(ushort4*)(xcat + (size_t)n * 512 + 256 + c4) = pk;
        return;
    }

    // QKV GEMM, N=768 = [q|k|v]; reads xcat low half only (lda=512, K=256)
    int qblk = blk - 2048;
    const int n0 = (qblk % 12) * 64;
    const int m0 = (qblk / 12) * 32;
    const int t = threadIdx.x;
    const int wave = t >> 6, lane = t & 63;
    const int tl = lane & 15, g = lane >> 4;
    const int wr = wave >> 1, wc = wave & 1;
    const int which = n0 >> 8;               // 0:q 1:k 2:v
    const int K = 256, lda = 512;

    f32x4 acc[2] = {};

    const unsigned short* a0 = xcat + (size_t)(m0 + wr * 16 + tl) * lda + g * 8;
    const unsigned short* b0 = WT + (size_t)(n0 + wc * 32 + tl) * K + g * 8;
    const unsigned short* b1 = b0 + (size_t)16 * K;

    for (int k0 = 0; k0 < K; k0 += 32) {
        bf16x8 af  = ldb8(a0 + k0);
        bf16x8 bf0 = ldb8(b0 + k0), bf1 = ldb8(b1 + k0);
        acc[0] = __builtin_amdgcn_mfma_f32_16x16x32_bf16(af, bf0, acc[0], 0, 0, 0);
        acc[1] = __builtin_amdgcn_mfma_f32_16x16x32_bf16(af, bf1, acc[1], 0, 0, 0);
    }

    const float* bias = which == 0 ? bq : which == 1 ? bk : bv;
    const float sc = which == 0 ? qscale : 1.f;

    if (which < 2) {
        unsigned short* dst = which == 0 ? qb : kb;
        #pragma unroll
        for (int c16 = 0; c16 < 2; ++c16)
            #pragma unroll
            for (int reg = 0; reg < 4; ++reg) {
                int row = m0 + wr * 16 + g * 4 + reg;
                int col = (n0 & 255) + wc * 32 + c16 * 16 + tl;
                dst[(size_t)row * Cc + col] = f2b((acc[c16][reg] + bias[col]) * sc);
            }
    } else {
        #pragma unroll
        for (int c16 = 0; c16 < 2; ++c16)
            #pragma unroll
            for (int reg = 0; reg < 4; ++reg) {
                int colL = wc * 32 + c16 * 16 + tl;
                int rowL = wr * 16 + g * 4 + reg;
                vtile[colL][rowL] = f2b(acc[c16][reg] + bias[(n0 & 255) + colL]);
            }
        __syncthreads();
        int clocal = t >> 2, q = t & 3;
        int colg = (n0 & 255) + clocal;
        int hh = colg >> 5, dd = colg & 31;
        int bg = m0 >> 10, nb = (m0 & 1023) + q * 8;
        ushort4 u0 = *(ushort4*)&vtile[clocal][q * 8];
        ushort4 u1 = *(ushort4*)&vtile[clocal][q * 8 + 4];
        unsigned short* dst = vTb + ((size_t)((bg * Hh + hh) * DKh + dd)) * Nn + nb;
        *(ushort4*)dst = u0;
        *(ushort4*)(dst + 4) = u1;
    }
}

// ---------------- merged attention (blocks 0..511) + h1pre GEMM (512..1023) ----------------
// R25 (resubmit; prior round was a broker/container failure, not a kernel
// failure): producer-consumer wave specialization. R24 falsified all
// bandwidth theories (traffic cut 2x with zero time change; attn ~97us).
// Issue accounting: VALU work = 20% of cycles; the other ~80% is barrier
// stall. Cause: staging threads (waves 0-3) issue [sph_load, K, V] and
// vmcnt is an IN-ORDER counter -> every wait-for-K also waits the cold-HBM
// sph load, serializing HBM latency into 4 of 8 compute waves each iter.
// Fix: a dedicated 9th wave (t>=512, block=576) does ONLY sph staging
// (pure sph vmcnt chain, stall overlaps consumer compute); the 8 compute
// waves now have a pure K/V (L2-fast) chain. Producer is one tile ahead,
// load+write in the SAME producer iteration => no cross-barrier register
// liveness (avoids R23's scratch spill).
__global__ __launch_bounds__(576, 6) void attn_h1_k(
    const unsigned short* __restrict__ q, const unsigned short* __restrict__ k,
    const unsigned short* __restrict__ vT, const float* __restrict__ sph,
    unsigned short* __restrict__ op0,
    const unsigned short* __restrict__ xcat, const unsigned short* __restrict__ WcatT,
    const float* __restrict__ x, unsigned short* __restrict__ h1preb,
    float* __restrict__ gsum, float* __restrict__ gsq)
{
    __shared__ float Sph[2][16][68];
    __shared__ unsigned short Ps[Hh][16][72];
    float* csum = (float*)&Ps[0][0][0];     // [2][64], aliased (gemm branch only)
    float* csq  = csum + 128;

    const int blk = blockIdx.x;
    const int t = threadIdx.x;
    const int wave = t >> 6;
    const int lane = t & 63;
    const int tl = lane & 15, g = lane >> 4;

    if (blk < 512) {
        // ---------- attention: 16 q-rows, full m-range, graph pinned to XCD ----------
        const int b  = blk & 7;             // graph == XCD (round-robin dispatch)
        const int n0 = (blk >> 3) * 16;     // 64 row-tiles per graph
        const int w  = wave;
        const float* sbase = sph + ((size_t)b * Nn + n0) * Nn;

        // producer lane geometry (wave 8): 4 loads x (4 rows x 16 lanes x 16B)
        const int pr = lane >> 4;           // row group 0..3
        const int pc = (lane & 15) * 4;     // col within 64

        if (t >= 512) {
            // prologue: stage tile 0 into buffer 0
            const float* src = sbase + pc;
            #pragma unroll
            for (int j = 0; j < 4; ++j)
                *(float4*)&Sph[0][pr * 4 + j][pc] =
                    *(const float4*)(src + (size_t)(pr * 4 + j) * Nn);
        }
        __syncthreads();

        if (t >= 512) {
            // -------- producer wave: pure sph staging, one tile ahead --------
            for (int i = 0; i < 16; ++i) {
                if (i < 15) {
                    const float* src = sbase + (i + 1) * 64 + pc;
                    float4 a0 = *(const float4*)(src + (size_t)(pr * 4 + 0) * Nn);
                    float4 a1 = *(const float4*)(src + (size_t)(pr * 4 + 1) * Nn);
                    float4 a2 = *(const float4*)(src + (size_t)(pr * 4 + 2) * Nn);
                    float4 a3 = *(const float4*)(src + (size_t)(pr * 4 + 3) * Nn);
                    int nb = (i + 1) & 1;
                    *(float4*)&Sph[nb][pr * 4 + 0][pc] = a0;
                    *(float4*)&Sph[nb][pr * 4 + 1][pc] = a1;
                    *(float4*)&Sph[nb][pr * 4 + 2][pc] = a2;
                    *(float4*)&Sph[nb][pr * 4 + 3][pc] = a3;
                }
                __syncthreads();
            }
            return;
        }

        // -------- consumer waves 0..7: pure K/V vmcnt chain --------
        bf16x8 qf = ldb8(q + ((size_t)(b * Nn + n0 + tl)) * Cc + w * DKh + g * 8);

        float lsum = 0.f;
        f32x4 oacc[2] = {};

        const unsigned short* kbase = k + ((size_t)(b * Nn) + tl) * Cc + w * DKh + g * 8;
        const unsigned short* vbase = vT + ((size_t)((b * Hh + w) * DKh) + tl) * Nn + g * 8;

        for (int i = 0; i < 16; ++i) {
            const int m0 = i * 64;
            const int cur = i & 1;

            f32x4 st[4];
            #pragma unroll
            for (int mg = 0; mg < 4; ++mg) {
                bf16x8 ka = ldb8(kbase + (size_t)(m0 + mg * 16) * Cc);
                f32x4 z = {0.f, 0.f, 0.f, 0.f};
                st[mg] = __builtin_amdgcn_mfma_f32_16x16x32_bf16(ka, qf, z, 0, 0, 0);
            }

            #pragma unroll
            for (int mg = 0; mg < 4; ++mg) {
                float4 sp = *(const float4*)&Sph[cur][tl][mg * 16 + g * 4];
                float p0 = exp2f(st[mg][0] * sp.x);
                float p1 = exp2f(st[mg][1] * sp.y);
                float p2 = exp2f(st[mg][2] * sp.z);
                float p3 = exp2f(st[mg][3] * sp.w);
                lsum += (p0 + p1) + (p2 + p3);
                ushort4 pk;
                pk.x = f2b(p0); pk.y = f2b(p1); pk.z = f2b(p2); pk.w = f2b(p3);
                *(ushort4*)&Ps[w][tl][mg * 16 + g * 4] = pk;
            }

            #pragma unroll
            for (int ks = 0; ks < 2; ++ks) {
                bf16x8 pa = ldb8(&Ps[w][tl][ks * 32 + g * 8]);
                #pragma unroll
                for (int cg = 0; cg < 2; ++cg) {
                    bf16x8 vb = ldb8(vbase + (size_t)(cg * 16) * Nn + m0 + ks * 32);
                    oacc[cg] = __builtin_amdgcn_mfma_f32_16x16x32_bf16(pa, vb, oacc[cg], 0, 0, 0);
                }
            }

            __syncthreads();   // producer's tile i+1 visible; Sph[cur]/Ps reads done
        }

        // full-row softmax denominator -> normalize O in-register.
        lsum += __shfl_xor(lsum, 16);
        lsum += __shfl_xor(lsum, 32);      // every lane: sum for q-row tl
        float* shl = (float*)&Ps[w][0][0]; // per-wave scratch (Ps dead now)
        if (g == 0) shl[tl] = lsum;        // wave-local write->read, no barrier
        #pragma unroll
        for (int r = 0; r < 4; ++r) {
            float inv = 1.f / shl[g * 4 + r];   // O row = g*4+r
            #pragma unroll
            for (int cg = 0; cg < 2; ++cg)
                op0[((size_t)(b * Nn + n0 + g * 4 + r)) * Cc + w * DKh + cg * 16 + tl]
                    = f2b(oacc[cg][r] * inv);
        }
        return;
    }

    // ---------- h1pre GEMM: two 32x64 tiles per block (threads 0..511) ----------
    const int half = wave >> 2;
    const int w4 = wave & 3;
    const int wr = w4 >> 1, wc = w4 & 1;
    const int tid = (blk - 512) * 2 + half;    // 0..1023
    const int n0 = (tid & 3) * 64;
    const int m0 = (tid >> 2) * 32;
    const int K = 512, N = Cc;

    if (t < 128) { csum[t] = 0.f; csq[t] = 0.f; }
    __syncthreads();

    if (t < 512) {
        f32x4 acc[2] = {};

        const unsigned short* a0 = xcat + (size_t)(m0 + wr * 16 + tl) * 512 + g * 8;
        const unsigned short* b0 = WcatT + (size_t)(n0 + wc * 32 + tl) * K + g * 8;
        const unsigned short* b1 = b0 + (size_t)16 * K;

        for (int k0 = 0; k0 < K; k0 += 32) {
            bf16x8 af  = ldb8(a0 + k0);
            bf16x8 bf0 = ldb8(b0 + k0), bf1 = ldb8(b1 + k0);
            acc[0] = __builtin_amdgcn_mfma_f32_16x16x32_bf16(af, bf0, acc[0], 0, 0, 0);
            acc[1] = __builtin_amdgcn_mfma_f32_16x16x32_bf16(af, bf1, acc[1], 0, 0, 0);
        }

        #pragma unroll
        for (int c16 = 0; c16 < 2; ++c16) {
            int colL = wc * 32 + c16 * 16 + tl;
            int col  = n0 + colL;
            float ls = 0.f, lq = 0.f;
            #pragma unroll
            for (int reg = 0; reg < 4; ++reg) {
                int row = m0 + wr * 16 + g * 4 + reg;
                size_t idx = (size_t)row * N + col;
                float v = acc[c16][reg] + x[idx];
                ls += v; lq += v * v;               // stats in fp32 (pre-rounding)
                h1preb[idx] = f2b(v);
            }
            atomicAdd(&csum[half * 64 + colL], ls);
            atomicAdd(&csq[half * 64 + colL],  lq);
        }
    }
    __syncthreads();
    if (t < 128) {
        int h2 = t >> 6;
        int tid2 = (blk - 512) * 2 + h2;
        int n0h = (tid2 & 3) * 64;
        atomicAdd(&gsum[n0h + (t & 63)], csum[t]);
        atomicAdd(&gsq[n0h + (t & 63)],  csq[t]);
    }
}

// ---------------- MFMA GEMM, 32x64 tile, optional bf16 residual + BN-stats ----------------
// TAG: 1 = mlp1 (N=512), 2 = mlp2 (K=512, bf16 residual addb = osb).
template<int TAG>
__global__ __launch_bounds__(256, 4) void gemm_mfma_k(
    const unsigned short* __restrict__ A, const unsigned short* __restrict__ WT,
    const float* __restrict__ bias, const unsigned short* __restrict__ addb,
    float* __restrict__ outf, unsigned short* __restrict__ outb,
    float* __restrict__ gsum, float* __restrict__ gsq,
    int M, int K, int lda, int N, int relu, float oscale)
{
    const int t = threadIdx.x;
    const int wave = t >> 6, lane = t & 63;
    const int tl = lane & 15, g = lane >> 4;
    const int wr = wave >> 1, wc = wave & 1;
    const int m0 = blockIdx.y * 32, n0 = blockIdx.x * 64;

    __shared__ float csum[64], csq[64];
    if (gsum) {
        if (t < 64) { csum[t] = 0.f; csq[t] = 0.f; }
        __syncthreads();
    }

    f32x4 acc[2] = {};

    const unsigned short* a0 = A  + (size_t)(m0 + wr * 16 + tl) * lda + g * 8;
    const unsigned short* b0 = WT + (size_t)(n0 + wc * 32 + tl) * K + g * 8;
    const unsigned short* b1 = b0 + (size_t)16 * K;

    for (int k0 = 0; k0 < K; k0 += 32) {
        bf16x8 af  = ldb8(a0 + k0);
        bf16x8 bf0 = ldb8(b0 + k0), bf1 = ldb8(b1 + k0);
        acc[0] = __builtin_amdgcn_mfma_f32_16x16x32_bf16(af, bf0, acc[0], 0, 0, 0);
        acc[1] = __builtin_amdgcn_mfma_f32_16x16x32_bf16(af, bf1, acc[1], 0, 0, 0);
    }

    #pragma unroll
    for (int c16 = 0; c16 < 2; ++c16) {
        int colL = wc * 32 + c16 * 16 + tl;
        int col  = n0 + colL;
        float ls = 0.f, lq = 0.f;
        #pragma unroll
        for (int reg = 0; reg < 4; ++reg) {
            int row = m0 + wr * 16 + g * 4 + reg;
            float v = acc[c16][reg];
            if (bias) v += bias[col];
            v *= oscale;
            size_t idx = (size_t)row * N + col;
            if (addb) v += b2f(addb[idx]);
            ls += v; lq += v * v;
            if (relu) v = fmaxf(v, 0.f);
            if (outf) outf[idx] = v;
            if (outb) outb[idx] = f2b(v);
        }
        if (gsum) { atomicAdd(&csum[colL], ls); atomicAdd(&csq[colL], lq); }
    }
    if (gsum) {
        __syncthreads();
        if (t < 64) {
            atomicAdd(&gsum[n0 + t], csum[t]);
            atomicAdd(&gsq[n0 + t],  csq[t]);
        }
    }
}

// ---------------- Wo GEMM (A = normalized bf16 O) + fp32 residual + BN2 stats ----------------
__global__ __launch_bounds__(256, 4) void gemm_attnA_k(
    const unsigned short* __restrict__ op0,
    const unsigned short* __restrict__ WT, const float* __restrict__ bias,
    const float* __restrict__ add1, unsigned short* __restrict__ h2preb,
    float* __restrict__ gsum, float* __restrict__ gsq)
{
    const int K = Cc, N = Cc;
    const int t = threadIdx.x;
    const int wave = t >> 6, lane = t & 63;
    const int tl = lane & 15, g = lane >> 4;
    const int wr = wave >> 1, wc = wave & 1;
    const int m0 = blockIdx.y * 32, n0 = blockIdx.x * 64;

    __shared__ float csum[64], csq[64];
    if (t < 64) { csum[t] = 0.f; csq[t] = 0.f; }
    __syncthreads();

    f32x4 acc[2] = {};

    const int arow = m0 + wr * 16 + tl;
    const unsigned short* a0b = op0 + (size_t)arow * K + g * 8;
    const unsigned short* b0 = WT + (size_t)(n0 + wc * 32 + tl) * K + g * 8;
    const unsigned short* b1 = b0 + (size_t)16 * K;

    for (int k0 = 0; k0 < K; k0 += 32) {
        bf16x8 af  = ldb8(a0b + k0);
        bf16x8 bf0 = ldb8(b0 + k0), bf1 = ldb8(b1 + k0);
        acc[0] = __builtin_amdgcn_mfma_f32_16x16x32_bf16(af, bf0, acc[0], 0, 0, 0);
        acc[1] = __builtin_amdgcn_mfma_f32_16x16x32_bf16(af, bf1, acc[1], 0, 0, 0);
    }

    #pragma unroll
    for (int c16 = 0; c16 < 2; ++c16) {
        int colL = wc * 32 + c16 * 16 + tl;
        int col  = n0 + colL;
        float ls = 0.f, lq = 0.f;
        #pragma unroll
        for (int reg = 0; reg < 4; ++reg) {
            int row = m0 + wr * 16 + g * 4 + reg;
            float v = acc[c16][reg] + bias[col];
            size_t idx = (size_t)row * N + col;
            v += add1[idx];
            ls += v; lq += v * v;               // stats in fp32 (pre-rounding)
            h2preb[idx] = f2b(v);
        }
        atomicAdd(&csum[colL], ls); atomicAdd(&csq[colL], lq);
    }
    __syncthreads();
    if (t < 64) {
        atomicAdd(&gsum[n0 + t], csum[t]);
        atomicAdd(&gsq[n0 + t],  csq[t]);
    }
}

// ---------------- BN apply (single, float4) ----------------
__global__ __launch_bounds__(256) void bn_apply_k(
    const float* __restrict__ h, const float* __restrict__ gsum,
    const float* __restrict__ gsq, const float* __restrict__ gamma,
    const float* __restrict__ beta, float* __restrict__ outf)
{
    size_t i4 = ((size_t)blockIdx.x * 256 + threadIdx.x) * 4;
    int ch = (int)(i4 & (Cc - 1));
    float4 hv = *(const float4*)(h + i4);
    float4 sm = *(const float4*)(gsum + ch);
    float4 sq = *(const float4*)(gsq + ch);
    float4 ga = *(const float4*)(gamma + ch);
    float4 be = *(const float4*)(beta + ch);
    float4 o;
    {
        float m = sm.x * (1.f / BNn), var = sq.x * (1.f / BNn) - m * m;
        o.x = (hv.x - m) * rsqrtf(var + EPSV) * ga.x + be.x;
    }
    {
        float m = sm.y * (1.f / BNn), var = sq.y * (1.f / BNn) - m * m;
        o.y = (hv.y - m) * rsqrtf(var + EPSV) * ga.y + be.y;
    }
    {
        float m = sm.z * (1.f / BNn), var = sq.z * (1.f / BNn) - m * m;
        o.z = (hv.z - m) * rsqrtf(var + EPSV) * ga.z + be.z;
    }
    {
        float m = sm.w * (1.f / BNn), var = sq.w * (1.f / BNn) - m * m;
        o.w = (hv.w - m) * rsqrtf(var + EPSV) * ga.w + be.w;
    }
    *(float4*)(outf + i4) = o;
}

// ---------------- fused BN1+BN2 apply (bf16 in / bf16 out, 12 MB total) ----------------
__global__ __launch_bounds__(256) void bn_apply12_k(
    const unsigned short* __restrict__ h1preb, const unsigned short* __restrict__ h2preb,
    const float* __restrict__ stats,
    const float* __restrict__ g1, const float* __restrict__ be1,
    const float* __restrict__ g2, const float* __restrict__ be2,
    unsigned short* __restrict__ outb)
{
    size_t i4 = ((size_t)blockIdx.x * 256 + threadIdx.x) * 4;
    int ch = (int)(i4 & (Cc - 1));
    ushort4 u1 = *(const ushort4*)(h1preb + i4);
    ushort4 u2 = *(const ushort4*)(h2preb + i4);
    float4 s1m = *(const float4*)(stats + ch);
    float4 s1q = *(const float4*)(stats + 256 + ch);
    float4 s2m = *(const float4*)(stats + 512 + ch);
    float4 s2q = *(const float4*)(stats + 768 + ch);
    float4 G1 = *(const float4*)(g1 + ch),  B1 = *(const float4*)(be1 + ch);
    float4 G2 = *(const float4*)(g2 + ch),  B2 = *(const float4*)(be2 + ch);
    ushort4 pk;
    #define BN12C(comp, ucomp) { \
        float m1 = s1m.comp * (1.f / BNn), v1 = s1q.comp * (1.f / BNn) - m1 * m1; \
        float m2 = s2m.comp * (1.f / BNn), v2 = s2q.comp * (1.f / BNn) - m2 * m2; \
        float o = (b2f(u1.ucomp) - m1) * rsqrtf(v1 + EPSV) * G1.comp + B1.comp \
                + (b2f(u2.ucomp) - m2) * rsqrtf(v2 + EPSV) * G2.comp + B2.comp; \
        pk.ucomp = f2b(o); }
    BN12C(x, x) BN12C(y, y) BN12C(z, z) BN12C(w, w)
    #undef BN12C
    *(ushort4*)(outb + i4) = pk;
}

// ---------------- launch ----------------
extern "C" void kernel_launch(void* const* d_in, const int* in_sizes, int n_in,
                              void* d_out, int out_size, void* d_ws, size_t ws_size,
                              hipStream_t stream)
{
    const float* x   = (const float*)d_in[0];
    const int*   ei  = (const int*)  d_in[1];
    const float* sph = (const float*)d_in[2];
    const float* Wr  = (const float*)d_in[3];
    const float* Wn  = (const float*)d_in[4];
    const float* Wq  = (const float*)d_in[5];
    const float* bq  = (const float*)d_in[6];
    const float* Wk  = (const float*)d_in[7];
    const float* bk  = (const float*)d_in[8];
    const float* Wv  = (const float*)d_in[9];
    const float* bv  = (const float*)d_in[10];
    const float* Wo  = (const float*)d_in[11];
    const float* bo  = (const float*)d_in[12];
    const float* W1  = (const float*)d_in[13];
    const float* b1  = (const float*)d_in[14];
    const float* W2  = (const float*)d_in[15];
    const float* b2  = (const float*)d_in[16];
    const float* g1  = (const float*)d_in[17];
    const float* be1 = (const float*)d_in[18];
    const float* g2  = (const float*)d_in[19];
    const float* be2 = (const float*)d_in[20];
    const float* g3  = (const float*)d_in[21];
    const float* be3 = (const float*)d_in[22];
    float* out = (float*)d_out;

    const size_t SL = (size_t)BNn * Cc;  // 2M elements

    float* ws = (float*)d_ws;
    float* s1 = ws;                  // op0b (bf16, 4MB)
    float* s2 = s1 + SL;             // h1preb (bf16) then out2 (fp32)
    float* s3 = s2 + SL;             // h2preb (bf16)

    int*   deg      = (int*)(s3 + SL);          // 8192
    float* statsAll = (float*)(deg + 8192);     // 1536
    int*   rowst    = (int*)(statsAll + 1536);  // 8192 (+pad)
    int*   cursor   = rowst + 8256;             // 8192
    int*   eidx     = cursor + 8192;            // 131072

    unsigned short* xcat = (unsigned short*)(eidx + 131072); // [8192][512]; reused as hid
    unsigned short* qb   = xcat + 2 * SL;
    unsigned short* kb   = qb + SL;                          // reused as osb
    unsigned short* vTb  = kb + SL;
    unsigned short* osb  = kb;
    unsigned short* hid  = xcat;

    unsigned short* WcatT = vTb + SL;         // 256x512
    unsigned short* WqT   = WcatT + 131072;   // WqT|WkT|WvT contiguous = [768][256]
    unsigned short* WkT   = WqT + 65536;
    unsigned short* WvT   = WkT + 65536;
    unsigned short* WoT   = WvT + 65536;
    unsigned short* W1T   = WoT + 65536;
    unsigned short* W2T   = W1T + 131072;
    unsigned short* op0b   = (unsigned short*)s1;
    unsigned short* h1preb = (unsigned short*)s2;   // 4MB of s2; dead before out2
    unsigned short* h2preb = (unsigned short*)s3;

    dim3 gN256(4, 256);
    dim3 gN512(8, 256);

    const float QSCALE = 0.17677669529663687f * 1.4426950408889634f;

    // 1) zero deg + all BN stats in one memset
    hipMemsetAsync(deg, 0, (8192 + 1536) * sizeof(float), stream);
    // 2) fused converts + histogram
    prep_k<<<5120, 256, 0, stream>>>(x, xcat, Wr, Wn, Wq, Wk, Wv, Wo, W1, W2,
                                     WcatT, WqT, WkT, WvT, WoT, W1T, W2T, ei, deg);
    // 3-4) CSR scan / place
    scan_k<<<1, 256, 0, stream>>>(deg, rowst, cursor);
    place_k<<<Ee / 256, 256, 0, stream>>>(ei, cursor, eidx);
    // 5) gather (xcat hi) || QKV GEMM (xcat lo -> qb,kb,vTb)  — independent
    gather_qkv_k<<<5120, 256, 0, stream>>>(x, rowst, deg, eidx, xcat,
                                           WqT, bq, bk, bv, qb, kb, vTb, QSCALE);
    // 6) attention (producer-wave sph staging) || h1pre GEMM
    attn_h1_k<<<1024, 576, 0, stream>>>(qb, kb, vTb, sph, op0b,
                                        xcat, WcatT, x, h1preb,
                                        statsAll, statsAll + 256);
    // 7) h2pre = O @ Wo + bo + x -> bf16, + BN2 stats
    gemm_attnA_k<<<gN256, 256, 0, stream>>>(op0b, WoT, bo, x,
                                            h2preb, statsAll + 512, statsAll + 768);
    // 8) osb = bn1(h1pre) + bn2(h2pre)   (bf16 in/out, 12 MB pass)
    bn_apply12_k<<<(int)(SL / 1024), 256, 0, stream>>>(h1preb, h2preb, statsAll,
                                                       g1, be1, g2, be2, osb);
    // 9) hidden = relu(osb @ W1 + b1) -> hid (bf16)
    gemm_mfma_k<1><<<gN512, 256, 0, stream>>>(osb, W1T, b1, nullptr,
                                              nullptr, hid, nullptr, nullptr,
                                              BNn, Cc, Cc, 2 * Cc, 1, 1.f);
    // 10) out2 = hid @ W2 + b2 + osb(residual, bf16) -> s2 fp32, + BN3 stats
    gemm_mfma_k<2><<<gN256, 256, 0, stream>>>(hid, W2T, b2, osb,
                                              s2, nullptr, statsAll + 1024, statsAll + 1280,
                                              BNn, 2 * Cc, 2 * Cc, Cc, 0, 1.f);
    // 11) d_out = BN3(out2)
    bn_apply_k<<<(int)(SL / 1024), 256, 0, stream>>>(s2, statsAll + 1024,
                                                     statsAll + 1280, g3, be3, out);
}

// Round 11
// 358.865 us; speedup vs baseline: 1.0365x; 1.0365x over previous
//
#include <hip/hip_runtime.h>
#include <hip/hip_bf16.h>

// ---------------- problem constants ----------------
constexpr int Bg  = 8;       // graphs
constexpr int Nn  = 1024;    // nodes per graph
constexpr int Cc  = 256;     // channels
constexpr int Hh  = 8;       // heads
constexpr int DKh = 32;      // head dim
constexpr int Ee  = 131072;  // edges
constexpr int BNn = Bg * Nn; // 8192 total nodes
#define EPSV 1e-5f

typedef __attribute__((ext_vector_type(8))) short bf16x8;
typedef __attribute__((ext_vector_type(4))) float f32x4;

static __device__ __forceinline__ unsigned short f2b(float v) {
    __hip_bfloat16 h = __float2bfloat16(v);
    return __builtin_bit_cast(unsigned short, h);
}
static __device__ __forceinline__ float b2f(unsigned short u) {
    unsigned int x = ((unsigned int)u) << 16;
    return __builtin_bit_cast(float, x);
}
static __device__ __forceinline__ bf16x8 ldb8(const unsigned short* p) {
    return *(const bf16x8*)p;
}

// ---------------- fused prep: xconv + wconv + hist ----------------
__global__ __launch_bounds__(256) void prep_k(
    const float* __restrict__ x, unsigned short* __restrict__ xcat,
    const float* __restrict__ Wr, const float* __restrict__ Wn,
    const float* __restrict__ Wq, const float* __restrict__ Wk,
    const float* __restrict__ Wv, const float* __restrict__ Wo,
    const float* __restrict__ W1, const float* __restrict__ W2,
    unsigned short* __restrict__ WcatT,
    unsigned short* __restrict__ WqT, unsigned short* __restrict__ WkT,
    unsigned short* __restrict__ WvT, unsigned short* __restrict__ WoT,
    unsigned short* __restrict__ W1T, unsigned short* __restrict__ W2T,
    const int* __restrict__ ei, int* __restrict__ deg)
{
    int blk = blockIdx.x;
    if (blk < 2048) {
        int i = (blk * 256 + threadIdx.x) * 4;
        float4 v = *(const float4*)(x + i);
        int r = i >> 8, c = i & 255;
        ushort4 pk;
        pk.x = f2b(v.x); pk.y = f2b(v.y); pk.z = f2b(v.z); pk.w = f2b(v.w);
        *(ushort4*)(xcat + (size_t)r * 512 + c) = pk;
    } else if (blk < 4608) {
        int idx = (blk - 2048) * 256 + threadIdx.x;
        if (idx < 131072) {                      // WcatT [256][512]
            int n = idx >> 9, k = idx & 511;
            float v = (k < 256) ? Wr[k * 256 + n] : Wn[(k - 256) * 256 + n];
            WcatT[(size_t)n * 512 + k] = f2b(v);
        } else if (idx < 393216) {               // q,k,v,o
            int l = idx - 131072;
            int wsel = l >> 16; l &= 65535;
            int n = l >> 8, kk = l & 255;
            const float* S = wsel == 0 ? Wq : wsel == 1 ? Wk : wsel == 2 ? Wv : Wo;
            unsigned short* D = wsel == 0 ? WqT : wsel == 1 ? WkT : wsel == 2 ? WvT : WoT;
            D[n * 256 + kk] = f2b(S[kk * 256 + n]);
        } else if (idx < 524288) {               // W1 [256][512] -> W1T [512][256]
            int l = idx - 393216;
            int n = l >> 8, kk = l & 255;
            W1T[l] = f2b(W1[kk * 512 + n]);
        } else {                                 // W2 [512][256] -> W2T [256][512]
            int l = idx - 524288;
            int n = l >> 9, kk = l & 511;
            W2T[l] = f2b(W2[kk * 256 + n]);
        }
    } else {
        int e = (blk - 4608) * 256 + threadIdx.x;
        atomicAdd(&deg[ei[Ee + e]], 1);
    }
}

// ---------------- CSR scan (coalesced, interleaved buckets) ----------------
__global__ __launch_bounds__(256) void scan_k(
    const int* __restrict__ deg, int* __restrict__ rowst, int* __restrict__ cursor)
{
    __shared__ int partial[256];
    int t = threadIdx.x;
    int local[32];
    int s = 0;
    #pragma unroll
    for (int i = 0; i < 32; ++i) { local[i] = deg[i * 256 + t]; s += local[i]; }
    partial[t] = s;
    __syncthreads();
    for (int off = 1; off < 256; off <<= 1) {
        int v = (t >= off) ? partial[t - off] : 0;
        __syncthreads();
        partial[t] += v;
        __syncthreads();
    }
    int base = partial[t] - s;
    #pragma unroll
    for (int i = 0; i < 32; ++i) {
        int n = i * 256 + t;
        rowst[n] = base;
        cursor[n] = base;
        base += local[i];
    }
}

__global__ __launch_bounds__(256) void place_k(
    const int* __restrict__ ei, int* __restrict__ cursor, int* __restrict__ eidx)
{
    int e = blockIdx.x * 256 + threadIdx.x;
    int s = ei[e], d = ei[Ee + e];
    int pos = atomicAdd(&cursor[d], 1);
    eidx[pos] = s;
}

// ---------------- merged gather (blocks 0..2047) + QKV GEMM (2048..5119) ----------------
__global__ __launch_bounds__(256, 4) void gather_qkv_k(
    const float* __restrict__ x, const int* __restrict__ rowst,
    const int* __restrict__ deg, const int* __restrict__ eidx,
    unsigned short* __restrict__ xcat,
    const unsigned short* __restrict__ WT,
    const float* __restrict__ bq, const float* __restrict__ bk,
    const float* __restrict__ bv,
    unsigned short* __restrict__ qb, unsigned short* __restrict__ kb,
    unsigned short* __restrict__ vTb, float qscale)
{
    __shared__ unsigned short vtile[64][40];
    int blk = blockIdx.x;

    if (blk < 2048) {
        // gather: 4 nodes per block, one 64-lane wave each
        int n = blk * 4 + (threadIdx.x >> 6);
        int c4 = (threadIdx.x & 63) * 4;
        int b0 = rowst[n], d = deg[n];
        float4 acc = {0.f, 0.f, 0.f, 0.f};
        int i = 0;
        for (; i + 4 <= d; i += 4) {
            int s0 = eidx[b0 + i], s1 = eidx[b0 + i + 1];
            int s2 = eidx[b0 + i + 2], s3 = eidx[b0 + i + 3];
            float4 a0 = *(const float4*)(x + (size_t)s0 * Cc + c4);
            float4 a1 = *(const float4*)(x + (size_t)s1 * Cc + c4);
            float4 a2 = *(const float4*)(x + (size_t)s2 * Cc + c4);
            float4 a3 = *(const float4*)(x + (size_t)s3 * Cc + c4);
            acc.x += (a0.x + a1.x) + (a2.x + a3.x);
            acc.y += (a0.y + a1.y) + (a2.y + a3.y);
            acc.z += (a0.z + a1.z) + (a2.z + a3.z);
            acc.w += (a0.w + a1.w) + (a2.w + a3.w);
        }
        for (; i < d; ++i) {
            int s = eidx[b0 + i];
            float4 a = *(const float4*)(x + (size_t)s * Cc + c4);
            acc.x += a.x; acc.y += a.y; acc.z += a.z; acc.w += a.w;
        }
        ushort4 pk;
        pk.x = f2b(acc.x); pk.y = f2b(acc.y); pk.z = f2b(acc.z); pk.w = f2b(acc.w);
        *(ushort4*)(xcat + (size_t)n * 512 + 256 + c4) = pk;
        return;
    }

    // QKV GEMM, N=768 = [q|k|v]; reads xcat low half only (lda=512, K=256)
    int qblk = blk - 2048;
    const int n0 = (qblk % 12) * 64;
    const int m0 = (qblk / 12) * 32;
    const int t = threadIdx.x;
    const int wave = t >> 6, lane = t & 63;
    const int tl = lane & 15, g = lane >> 4;
    const int wr = wave >> 1, wc = wave & 1;
    const int which = n0 >> 8;               // 0:q 1:k 2:v
    const int K = 256, lda = 512;

    f32x4 acc[2] = {};

    const unsigned short* a0 = xcat + (size_t)(m0 + wr * 16 + tl) * lda + g * 8;
    const unsigned short* b0 = WT + (size_t)(n0 + wc * 32 + tl) * K + g * 8;
    const unsigned short* b1 = b0 + (size_t)16 * K;

    for (int k0 = 0; k0 < K; k0 += 32) {
        bf16x8 af  = ldb8(a0 + k0);
        bf16x8 bf0 = ldb8(b0 + k0), bf1 = ldb8(b1 + k0);
        acc[0] = __builtin_amdgcn_mfma_f32_16x16x32_bf16(af, bf0, acc[0], 0, 0, 0);
        acc[1] = __builtin_amdgcn_mfma_f32_16x16x32_bf16(af, bf1, acc[1], 0, 0, 0);
    }

    const float* bias = which == 0 ? bq : which == 1 ? bk : bv;
    const float sc = which == 0 ? qscale : 1.f;

    if (which < 2) {
        unsigned short* dst = which == 0 ? qb : kb;
        #pragma unroll
        for (int c16 = 0; c16 < 2; ++c16)
            #pragma unroll
            for (int reg = 0; reg < 4; ++reg) {
                int row = m0 + wr * 16 + g * 4 + reg;
                int col = (n0 & 255) + wc * 32 + c16 * 16 + tl;
                dst[(size_t)row * Cc + col] = f2b((acc[c16][reg] + bias[col]) * sc);
            }
    } else {
        #pragma unroll
        for (int c16 = 0; c16 < 2; ++c16)
            #pragma unroll
            for (int reg = 0; reg < 4; ++reg) {
                int colL = wc * 32 + c16 * 16 + tl;
                int rowL = wr * 16 + g * 4 + reg;
                vtile[colL][rowL] = f2b(acc[c16][reg] + bias[(n0 & 255) + colL]);
            }
        __syncthreads();
        int clocal = t >> 2, q = t & 3;
        int colg = (n0 & 255) + clocal;
        int hh = colg >> 5, dd = colg & 31;
        int bg = m0 >> 10, nb = (m0 & 1023) + q * 8;
        ushort4 u0 = *(ushort4*)&vtile[clocal][q * 8];
        ushort4 u1 = *(ushort4*)&vtile[clocal][q * 8 + 4];
        unsigned short* dst = vTb + ((size_t)((bg * Hh + hh) * DKh + dd)) * Nn + nb;
        *(ushort4*)dst = u0;
        *(ushort4*)(dst + 4) = u1;
    }
}

// ---------------- merged attention (blocks 0..511) + h1pre GEMM (512..1023) ----------------
// R26 = R24 + two issue-side levers (all schedule levers are falsified —
// attn invariant ~97us across R19-R25). Counter math: VALUBusy 20% at 16
// waves/CU => ~350 VALU inst/iter/wave (exp2f is a ~10-op libcall x16 +
// RNE f2b x16 + packing). Fixes:
//  (1) exp2f -> __builtin_amdgcn_exp2f (raw v_exp_f32, 1 inst; QSCALE
//      already folds 1/ln2; bf16 downstream swallows 1-ulp).
//  (2) m-step 64 -> 128: halves iteration/barrier count (16 -> 8), halving
//      whatever fixed per-iteration overhead survives. PV runs in two
//      64-halves reusing the SAME per-wave Ps buffer (no barrier between
//      halves, st[4] liveness unchanged -> no VGPR pressure).
// LDS: Sph[2][16][132] (16.9KB) + Ps (18.4KB) = 35.3KB -> 4 blocks/CU.
__global__ __launch_bounds__(512, 8) void attn_h1_k(
    const unsigned short* __restrict__ q, const unsigned short* __restrict__ k,
    const unsigned short* __restrict__ vT, const float* __restrict__ sph,
    unsigned short* __restrict__ op0,
    const unsigned short* __restrict__ xcat, const unsigned short* __restrict__ WcatT,
    const float* __restrict__ x, unsigned short* __restrict__ h1preb,
    float* __restrict__ gsum, float* __restrict__ gsq)
{
    __shared__ float Sph[2][16][132];          // 2x16x132x4 = 16896 B
    __shared__ unsigned short Ps[Hh][16][72];  // 18432 B
    float* csum = (float*)&Ps[0][0][0];     // [2][64], aliased (gemm branch only)
    float* csq  = csum + 128;

    const int blk = blockIdx.x;
    const int t = threadIdx.x;
    const int wave = t >> 6;
    const int lane = t & 63;
    const int tl = lane & 15, g = lane >> 4;

    if (blk < 512) {
        // ---------- attention: 16 q-rows, full m-range, graph pinned to XCD ----------
        const int b  = blk & 7;             // graph == XCD (round-robin dispatch)
        const int n0 = (blk >> 3) * 16;     // 64 row-tiles per graph
        const int w  = wave;

        bf16x8 qf = ldb8(q + ((size_t)(b * Nn + n0 + tl)) * Cc + w * DKh + g * 8);

        float lsum = 0.f;
        f32x4 oacc[2] = {};

        const unsigned short* kbase = k + ((size_t)(b * Nn) + tl) * Cc + w * DKh + g * 8;
        const unsigned short* vbase = vT + ((size_t)((b * Hh + w) * DKh) + tl) * Nn + g * 8;
        const float* sbase = sph + ((size_t)b * Nn + n0) * Nn;

        // prologue: stage sph tile 0 (16x128) into buffer 0; 256 thr x 2 float4
        if (t < 256) {
            int r1 = t >> 4, c1 = (t & 15) * 8;
            const float* src = sbase + (size_t)r1 * Nn + c1;
            *(float4*)&Sph[0][r1][c1]     = *(const float4*)src;
            *(float4*)&Sph[0][r1][c1 + 4] = *(const float4*)(src + 4);
        }
        __syncthreads();

        int cur = 0;
        for (int it = 0; it < 8; ++it) {
            const int m0 = it * 128;
            // stage NEXT 16x128 tile into the other buffer
            if (it < 7 && t < 256) {
                int r1 = t >> 4, c1 = (t & 15) * 8;
                const float* src = sbase + (size_t)r1 * Nn + m0 + 128 + c1;
                *(float4*)&Sph[cur ^ 1][r1][c1]     = *(const float4*)src;
                *(float4*)&Sph[cur ^ 1][r1][c1 + 4] = *(const float4*)(src + 4);
            }

            #pragma unroll
            for (int half = 0; half < 2; ++half) {
                const int mh = m0 + half * 64;

                f32x4 st[4];
                #pragma unroll
                for (int mg = 0; mg < 4; ++mg) {
                    bf16x8 ka = ldb8(kbase + (size_t)(mh + mg * 16) * Cc);
                    f32x4 z = {0.f, 0.f, 0.f, 0.f};
                    st[mg] = __builtin_amdgcn_mfma_f32_16x16x32_bf16(ka, qf, z, 0, 0, 0);
                }

                #pragma unroll
                for (int mg = 0; mg < 4; ++mg) {
                    float4 sp = *(const float4*)&Sph[cur][tl][half * 64 + mg * 16 + g * 4];
                    float p0 = __builtin_amdgcn_exp2f(st[mg][0] * sp.x);
                    float p1 = __builtin_amdgcn_exp2f(st[mg][1] * sp.y);
                    float p2 = __builtin_amdgcn_exp2f(st[mg][2] * sp.z);
                    float p3 = __builtin_amdgcn_exp2f(st[mg][3] * sp.w);
                    lsum += (p0 + p1) + (p2 + p3);
                    ushort4 pk;
                    pk.x = f2b(p0); pk.y = f2b(p1); pk.z = f2b(p2); pk.w = f2b(p3);
                    *(ushort4*)&Ps[w][tl][mg * 16 + g * 4] = pk;
                }

                #pragma unroll
                for (int ks = 0; ks < 2; ++ks) {
                    bf16x8 pa = ldb8(&Ps[w][tl][ks * 32 + g * 8]);
                    #pragma unroll
                    for (int cg = 0; cg < 2; ++cg) {
                        bf16x8 vb = ldb8(vbase + (size_t)(cg * 16) * Nn + mh + ks * 32);
                        oacc[cg] = __builtin_amdgcn_mfma_f32_16x16x32_bf16(pa, vb, oacc[cg], 0, 0, 0);
                    }
                }
            }

            __syncthreads();   // staging writes visible; Sph[cur]/Ps reads complete
            cur ^= 1;
        }

        // full-row softmax denominator -> normalize O in-register.
        lsum += __shfl_xor(lsum, 16);
        lsum += __shfl_xor(lsum, 32);      // every lane: sum for q-row tl
        float* shl = (float*)&Ps[w][0][0]; // per-wave scratch (Ps dead now)
        if (g == 0) shl[tl] = lsum;        // wave-local write->read, no barrier
        #pragma unroll
        for (int r = 0; r < 4; ++r) {
            float inv = 1.f / shl[g * 4 + r];   // O row = g*4+r
            #pragma unroll
            for (int cg = 0; cg < 2; ++cg)
                op0[((size_t)(b * Nn + n0 + g * 4 + r)) * Cc + w * DKh + cg * 16 + tl]
                    = f2b(oacc[cg][r] * inv);
        }
        return;
    }

    // ---------- h1pre GEMM: two 32x64 tiles per block ----------
    const int half = wave >> 2;
    const int w4 = wave & 3;
    const int wr = w4 >> 1, wc = w4 & 1;
    const int tid = (blk - 512) * 2 + half;    // 0..1023
    const int n0 = (tid & 3) * 64;
    const int m0 = (tid >> 2) * 32;
    const int K = 512, N = Cc;

    if (t < 128) { csum[t] = 0.f; csq[t] = 0.f; }
    __syncthreads();

    f32x4 acc[2] = {};

    const unsigned short* a0 = xcat + (size_t)(m0 + wr * 16 + tl) * 512 + g * 8;
    const unsigned short* b0 = WcatT + (size_t)(n0 + wc * 32 + tl) * K + g * 8;
    const unsigned short* b1 = b0 + (size_t)16 * K;

    for (int k0 = 0; k0 < K; k0 += 32) {
        bf16x8 af  = ldb8(a0 + k0);
        bf16x8 bf0 = ldb8(b0 + k0), bf1 = ldb8(b1 + k0);
        acc[0] = __builtin_amdgcn_mfma_f32_16x16x32_bf16(af, bf0, acc[0], 0, 0, 0);
        acc[1] = __builtin_amdgcn_mfma_f32_16x16x32_bf16(af, bf1, acc[1], 0, 0, 0);
    }

    #pragma unroll
    for (int c16 = 0; c16 < 2; ++c16) {
        int colL = wc * 32 + c16 * 16 + tl;
        int col  = n0 + colL;
        float ls = 0.f, lq = 0.f;
        #pragma unroll
        for (int reg = 0; reg < 4; ++reg) {
            int row = m0 + wr * 16 + g * 4 + reg;
            size_t idx = (size_t)row * N + col;
            float v = acc[c16][reg] + x[idx];
            ls += v; lq += v * v;               // stats in fp32 (pre-rounding)
            h1preb[idx] = f2b(v);
        }
        atomicAdd(&csum[half * 64 + colL], ls);
        atomicAdd(&csq[half * 64 + colL],  lq);
    }
    __syncthreads();
    if (t < 128) {
        int h2 = t >> 6;
        int tid2 = (blk - 512) * 2 + h2;
        int n0h = (tid2 & 3) * 64;
        atomicAdd(&gsum[n0h + (t & 63)], csum[t]);
        atomicAdd(&gsq[n0h + (t & 63)],  csq[t]);
    }
}

// ---------------- MFMA GEMM, 32x64 tile, optional bf16 residual + BN-stats ----------------
// TAG: 1 = mlp1 (N=512), 2 = mlp2 (K=512, bf16 residual addb = osb).
template<int TAG>
__global__ __launch_bounds__(256, 4) void gemm_mfma_k(
    const unsigned short* __restrict__ A, const unsigned short* __restrict__ WT,
    const float* __restrict__ bias, const unsigned short* __restrict__ addb,
    float* __restrict__ outf, unsigned short* __restrict__ outb,
    float* __restrict__ gsum, float* __restrict__ gsq,
    int M, int K, int lda, int N, int relu, float oscale)
{
    const int t = threadIdx.x;
    const int wave = t >> 6, lane = t & 63;
    const int tl = lane & 15, g = lane >> 4;
    const int wr = wave >> 1, wc = wave & 1;
    const int m0 = blockIdx.y * 32, n0 = blockIdx.x * 64;

    __shared__ float csum[64], csq[64];
    if (gsum) {
        if (t < 64) { csum[t] = 0.f; csq[t] = 0.f; }
        __syncthreads();
    }

    f32x4 acc[2] = {};

    const unsigned short* a0 = A  + (size_t)(m0 + wr * 16 + tl) * lda + g * 8;
    const unsigned short* b0 = WT + (size_t)(n0 + wc * 32 + tl) * K + g * 8;
    const unsigned short* b1 = b0 + (size_t)16 * K;

    for (int k0 = 0; k0 < K; k0 += 32) {
        bf16x8 af  = ldb8(a0 + k0);
        bf16x8 bf0 = ldb8(b0 + k0), bf1 = ldb8(b1 + k0);
        acc[0] = __builtin_amdgcn_mfma_f32_16x16x32_bf16(af, bf0, acc[0], 0, 0, 0);
        acc[1] = __builtin_amdgcn_mfma_f32_16x16x32_bf16(af, bf1, acc[1], 0, 0, 0);
    }

    #pragma unroll
    for (int c16 = 0; c16 < 2; ++c16) {
        int colL = wc * 32 + c16 * 16 + tl;
        int col  = n0 + colL;
        float ls = 0.f, lq = 0.f;
        #pragma unroll
        for (int reg = 0; reg < 4; ++reg) {
            int row = m0 + wr * 16 + g * 4 + reg;
            float v = acc[c16][reg];
            if (bias) v += bias[col];
            v *= oscale;
            size_t idx = (size_t)row * N + col;
            if (addb) v += b2f(addb[idx]);
            ls += v; lq += v * v;
            if (relu) v = fmaxf(v, 0.f);
            if (outf) outf[idx] = v;
            if (outb) outb[idx] = f2b(v);
        }
        if (gsum) { atomicAdd(&csum[colL], ls); atomicAdd(&csq[colL], lq); }
    }
    if (gsum) {
        __syncthreads();
        if (t < 64) {
            atomicAdd(&gsum[n0 + t], csum[t]);
            atomicAdd(&gsq[n0 + t],  csq[t]);
        }
    }
}

// ---------------- Wo GEMM (A = normalized bf16 O) + fp32 residual + BN2 stats ----------------
__global__ __launch_bounds__(256, 4) void gemm_attnA_k(
    const unsigned short* __restrict__ op0,
    const unsigned short* __restrict__ WT, const float* __restrict__ bias,
    const float* __restrict__ add1, unsigned short* __restrict__ h2preb,
    float* __restrict__ gsum, float* __restrict__ gsq)
{
    const int K = Cc, N = Cc;
    const int t = threadIdx.x;
    const int wave = t >> 6, lane = t & 63;
    const int tl = lane & 15, g = lane >> 4;
    const int wr = wave >> 1, wc = wave & 1;
    const int m0 = blockIdx.y * 32, n0 = blockIdx.x * 64;

    __shared__ float csum[64], csq[64];
    if (t < 64) { csum[t] = 0.f; csq[t] = 0.f; }
    __syncthreads();

    f32x4 acc[2] = {};

    const int arow = m0 + wr * 16 + tl;
    const unsigned short* a0b = op0 + (size_t)arow * K + g * 8;
    const unsigned short* b0 = WT + (size_t)(n0 + wc * 32 + tl) * K + g * 8;
    const unsigned short* b1 = b0 + (size_t)16 * K;

    for (int k0 = 0; k0 < K; k0 += 32) {
        bf16x8 af  = ldb8(a0b + k0);
        bf16x8 bf0 = ldb8(b0 + k0), bf1 = ldb8(b1 + k0);
        acc[0] = __builtin_amdgcn_mfma_f32_16x16x32_bf16(af, bf0, acc[0], 0, 0, 0);
        acc[1] = __builtin_amdgcn_mfma_f32_16x16x32_bf16(af, bf1, acc[1], 0, 0, 0);
    }

    #pragma unroll
    for (int c16 = 0; c16 < 2; ++c16) {
        int colL = wc * 32 + c16 * 16 + tl;
        int col  = n0 + colL;
        float ls = 0.f, lq = 0.f;
        #pragma unroll
        for (int reg = 0; reg < 4; ++reg) {
            int row = m0 + wr * 16 + g * 4 + reg;
            float v = acc[c16][reg] + bias[col];
            size_t idx = (size_t)row * N + col;
            v += add1[idx];
            ls += v; lq += v * v;               // stats in fp32 (pre-rounding)
            h2preb[idx] = f2b(v);
        }
        atomicAdd(&csum[colL], ls); atomicAdd(&csq[colL], lq);
    }
    __syncthreads();
    if (t < 64) {
        atomicAdd(&gsum[n0 + t], csum[t]);
        atomicAdd(&gsq[n0 + t],  csq[t]);
    }
}

// ---------------- BN apply (single, float4) ----------------
__global__ __launch_bounds__(256) void bn_apply_k(
    const float* __restrict__ h, const float* __restrict__ gsum,
    const float* __restrict__ gsq, const float* __restrict__ gamma,
    const float* __restrict__ beta, float* __restrict__ outf)
{
    size_t i4 = ((size_t)blockIdx.x * 256 + threadIdx.x) * 4;
    int ch = (int)(i4 & (Cc - 1));
    float4 hv = *(const float4*)(h + i4);
    float4 sm = *(const float4*)(gsum + ch);
    float4 sq = *(const float4*)(gsq + ch);
    float4 ga = *(const float4*)(gamma + ch);
    float4 be = *(const float4*)(beta + ch);
    float4 o;
    {
        float m = sm.x * (1.f / BNn), var = sq.x * (1.f / BNn) - m * m;
        o.x = (hv.x - m) * rsqrtf(var + EPSV) * ga.x + be.x;
    }
    {
        float m = sm.y * (1.f / BNn), var = sq.y * (1.f / BNn) - m * m;
        o.y = (hv.y - m) * rsqrtf(var + EPSV) * ga.y + be.y;
    }
    {
        float m = sm.z * (1.f / BNn), var = sq.z * (1.f / BNn) - m * m;
        o.z = (hv.z - m) * rsqrtf(var + EPSV) * ga.z + be.z;
    }
    {
        float m = sm.w * (1.f / BNn), var = sq.w * (1.f / BNn) - m * m;
        o.w = (hv.w - m) * rsqrtf(var + EPSV) * ga.w + be.w;
    }
    *(float4*)(outf + i4) = o;
}

// ---------------- fused BN1+BN2 apply (bf16 in / bf16 out, 12 MB total) ----------------
__global__ __launch_bounds__(256) void bn_apply12_k(
    const unsigned short* __restrict__ h1preb, const unsigned short* __restrict__ h2preb,
    const float* __restrict__ stats,
    const float* __restrict__ g1, const float* __restrict__ be1,
    const float* __restrict__ g2, const float* __restrict__ be2,
    unsigned short* __restrict__ outb)
{
    size_t i4 = ((size_t)blockIdx.x * 256 + threadIdx.x) * 4;
    int ch = (int)(i4 & (Cc - 1));
    ushort4 u1 = *(const ushort4*)(h1preb + i4);
    ushort4 u2 = *(const ushort4*)(h2preb + i4);
    float4 s1m = *(const float4*)(stats + ch);
    float4 s1q = *(const float4*)(stats + 256 + ch);
    float4 s2m = *(const float4*)(stats + 512 + ch);
    float4 s2q = *(const float4*)(stats + 768 + ch);
    float4 G1 = *(const float4*)(g1 + ch),  B1 = *(const float4*)(be1 + ch);
    float4 G2 = *(const float4*)(g2 + ch),  B2 = *(const float4*)(be2 + ch);
    ushort4 pk;
    #define BN12C(comp, ucomp) { \
        float m1 = s1m.comp * (1.f / BNn), v1 = s1q.comp * (1.f / BNn) - m1 * m1; \
        float m2 = s2m.comp * (1.f / BNn), v2 = s2q.comp * (1.f / BNn) - m2 * m2; \
        float o = (b2f(u1.ucomp) - m1) * rsqrtf(v1 + EPSV) * G1.comp + B1.comp \
                + (b2f(u2.ucomp) - m2) * rsqrtf(v2 + EPSV) * G2.comp + B2.comp; \
        pk.ucomp = f2b(o); }
    BN12C(x, x) BN12C(y, y) BN12C(z, z) BN12C(w, w)
    #undef BN12C
    *(ushort4*)(outb + i4) = pk;
}

// ---------------- launch ----------------
extern "C" void kernel_launch(void* const* d_in, const int* in_sizes, int n_in,
                              void* d_out, int out_size, void* d_ws, size_t ws_size,
                              hipStream_t stream)
{
    const float* x   = (const float*)d_in[0];
    const int*   ei  = (const int*)  d_in[1];
    const float* sph = (const float*)d_in[2];
    const float* Wr  = (const float*)d_in[3];
    const float* Wn  = (const float*)d_in[4];
    const float* Wq  = (const float*)d_in[5];
    const float* bq  = (const float*)d_in[6];
    const float* Wk  = (const float*)d_in[7];
    const float* bk  = (const float*)d_in[8];
    const float* Wv  = (const float*)d_in[9];
    const float* bv  = (const float*)d_in[10];
    const float* Wo  = (const float*)d_in[11];
    const float* bo  = (const float*)d_in[12];
    const float* W1  = (const float*)d_in[13];
    const float* b1  = (const float*)d_in[14];
    const float* W2  = (const float*)d_in[15];
    const float* b2  = (const float*)d_in[16];
    const float* g1  = (const float*)d_in[17];
    const float* be1 = (const float*)d_in[18];
    const float* g2  = (const float*)d_in[19];
    const float* be2 = (const float*)d_in[20];
    const float* g3  = (const float*)d_in[21];
    const float* be3 = (const float*)d_in[22];
    float* out = (float*)d_out;

    const size_t SL = (size_t)BNn * Cc;  // 2M elements

    float* ws = (float*)d_ws;
    float* s1 = ws;                  // op0b (bf16, 4MB)
    float* s2 = s1 + SL;             // h1preb (bf16) then out2 (fp32)
    float* s3 = s2 + SL;             // h2preb (bf16)

    int*   deg      = (int*)(s3 + SL);          // 8192
    float* statsAll = (float*)(deg + 8192);     // 1536
    int*   rowst    = (int*)(statsAll + 1536);  // 8192 (+pad)
    int*   cursor   = rowst + 8256;             // 8192
    int*   eidx     = cursor + 8192;            // 131072

    unsigned short* xcat = (unsigned short*)(eidx + 131072); // [8192][512]; reused as hid
    unsigned short* qb   = xcat + 2 * SL;
    unsigned short* kb   = qb + SL;                          // reused as osb
    unsigned short* vTb  = kb + SL;
    unsigned short* osb  = kb;
    unsigned short* hid  = xcat;

    unsigned short* WcatT = vTb + SL;         // 256x512
    unsigned short* WqT   = WcatT + 131072;   // WqT|WkT|WvT contiguous = [768][256]
    unsigned short* WkT   = WqT + 65536;
    unsigned short* WvT   = WkT + 65536;
    unsigned short* WoT   = WvT + 65536;
    unsigned short* W1T   = WoT + 65536;
    unsigned short* W2T   = W1T + 131072;
    unsigned short* op0b   = (unsigned short*)s1;
    unsigned short* h1preb = (unsigned short*)s2;   // 4MB of s2; dead before out2
    unsigned short* h2preb = (unsigned short*)s3;

    dim3 gN256(4, 256);
    dim3 gN512(8, 256);

    const float QSCALE = 0.17677669529663687f * 1.4426950408889634f;

    // 1) zero deg + all BN stats in one memset
    hipMemsetAsync(deg, 0, (8192 + 1536) * sizeof(float), stream);
    // 2) fused converts + histogram
    prep_k<<<5120, 256, 0, stream>>>(x, xcat, Wr, Wn, Wq, Wk, Wv, Wo, W1, W2,
                                     WcatT, WqT, WkT, WvT, WoT, W1T, W2T, ei, deg);
    // 3-4) CSR scan / place
    scan_k<<<1, 256, 0, stream>>>(deg, rowst, cursor);
    place_k<<<Ee / 256, 256, 0, stream>>>(ei, cursor, eidx);
    // 5) gather (xcat hi) || QKV GEMM (xcat lo -> qb,kb,vTb)  — independent
    gather_qkv_k<<<5120, 256, 0, stream>>>(x, rowst, deg, eidx, xcat,
                                           WqT, bq, bk, bv, qb, kb, vTb, QSCALE);
    // 6) attention (m-step 128, raw v_exp) || h1pre GEMM — 1024 blocks
    attn_h1_k<<<1024, 512, 0, stream>>>(qb, kb, vTb, sph, op0b,
                                        xcat, WcatT, x, h1preb,
                                        statsAll, statsAll + 256);
    // 7) h2pre = O @ Wo + bo + x -> bf16, + BN2 stats
    gemm_attnA_k<<<gN256, 256, 0, stream>>>(op0b, WoT, bo, x,
                                            h2preb, statsAll + 512, statsAll + 768);
    // 8) osb = bn1(h1pre) + bn2(h2pre)   (bf16 in/out, 12 MB pass)
    bn_apply12_k<<<(int)(SL / 1024), 256, 0, stream>>>(h1preb, h2preb, statsAll,
                                                       g1, be1, g2, be2, osb);
    // 9) hidden = relu(osb @ W1 + b1) -> hid (bf16)
    gemm_mfma_k<1><<<gN512, 256, 0, stream>>>(osb, W1T, b1, nullptr,
                                              nullptr, hid, nullptr, nullptr,
                                              BNn, Cc, Cc, 2 * Cc, 1, 1.f);
    // 10) out2 = hid @ W2 + b2 + osb(residual, bf16) -> s2 fp32, + BN3 stats
    gemm_mfma_k<2><<<gN256, 256, 0, stream>>>(hid, W2T, b2, osb,
                                              s2, nullptr, statsAll + 1024, statsAll + 1280,
                                              BNn, 2 * Cc, 2 * Cc, Cc, 0, 1.f);
    // 11) d_out = BN3(out2)
    bn_apply_k<<<(int)(SL / 1024), 256, 0, stream>>>(s2, statsAll + 1024,
                                                     statsAll + 1280, g3, be3, out);
}

// Round 12
// 358.671 us; speedup vs baseline: 1.0371x; 1.0005x over previous
//
#include <hip/hip_runtime.h>
#include <hip/hip_bf16.h>

// ---------------- problem constants ----------------
constexpr int Bg  = 8;       // graphs
constexpr int Nn  = 1024;    // nodes per graph
constexpr int Cc  = 256;     // channels
constexpr int Hh  = 8;       // heads
constexpr int DKh = 32;      // head dim
constexpr int Ee  = 131072;  // edges
constexpr int BNn = Bg * Nn; // 8192 total nodes
#define EPSV 1e-5f

typedef __attribute__((ext_vector_type(8))) short bf16x8;
typedef __attribute__((ext_vector_type(4))) float f32x4;

static __device__ __forceinline__ unsigned short f2b(float v) {
    __hip_bfloat16 h = __float2bfloat16(v);
    return __builtin_bit_cast(unsigned short, h);
}
static __device__ __forceinline__ float b2f(unsigned short u) {
    unsigned int x = ((unsigned int)u) << 16;
    return __builtin_bit_cast(float, x);
}
static __device__ __forceinline__ bf16x8 ldb8(const unsigned short* p) {
    return *(const bf16x8*)p;
}

// ---------------- fused prep: xconv + wconv + hist ----------------
__global__ __launch_bounds__(256) void prep_k(
    const float* __restrict__ x, unsigned short* __restrict__ xcat,
    const float* __restrict__ Wr, const float* __restrict__ Wn,
    const float* __restrict__ Wq, const float* __restrict__ Wk,
    const float* __restrict__ Wv, const float* __restrict__ Wo,
    const float* __restrict__ W1, const float* __restrict__ W2,
    unsigned short* __restrict__ WcatT,
    unsigned short* __restrict__ WqT, unsigned short* __restrict__ WkT,
    unsigned short* __restrict__ WvT, unsigned short* __restrict__ WoT,
    unsigned short* __restrict__ W1T, unsigned short* __restrict__ W2T,
    const int* __restrict__ ei, int* __restrict__ deg)
{
    int blk = blockIdx.x;
    if (blk < 2048) {
        int i = (blk * 256 + threadIdx.x) * 4;
        float4 v = *(const float4*)(x + i);
        int r = i >> 8, c = i & 255;
        ushort4 pk;
        pk.x = f2b(v.x); pk.y = f2b(v.y); pk.z = f2b(v.z); pk.w = f2b(v.w);
        *(ushort4*)(xcat + (size_t)r * 512 + c) = pk;
    } else if (blk < 4608) {
        int idx = (blk - 2048) * 256 + threadIdx.x;
        if (idx < 131072) {                      // WcatT [256][512]
            int n = idx >> 9, k = idx & 511;
            float v = (k < 256) ? Wr[k * 256 + n] : Wn[(k - 256) * 256 + n];
            WcatT[(size_t)n * 512 + k] = f2b(v);
        } else if (idx < 393216) {               // q,k,v,o
            int l = idx - 131072;
            int wsel = l >> 16; l &= 65535;
            int n = l >> 8, kk = l & 255;
            const float* S = wsel == 0 ? Wq : wsel == 1 ? Wk : wsel == 2 ? Wv : Wo;
            unsigned short* D = wsel == 0 ? WqT : wsel == 1 ? WkT : wsel == 2 ? WvT : WoT;
            D[n * 256 + kk] = f2b(S[kk * 256 + n]);
        } else if (idx < 524288) {               // W1 [256][512] -> W1T [512][256]
            int l = idx - 393216;
            int n = l >> 8, kk = l & 255;
            W1T[l] = f2b(W1[kk * 512 + n]);
        } else {                                 // W2 [512][256] -> W2T [256][512]
            int l = idx - 524288;
            int n = l >> 9, kk = l & 511;
            W2T[l] = f2b(W2[kk * 256 + n]);
        }
    } else {
        int e = (blk - 4608) * 256 + threadIdx.x;
        atomicAdd(&deg[ei[Ee + e]], 1);
    }
}

// ---------------- CSR scan (coalesced, interleaved buckets) ----------------
__global__ __launch_bounds__(256) void scan_k(
    const int* __restrict__ deg, int* __restrict__ rowst, int* __restrict__ cursor)
{
    __shared__ int partial[256];
    int t = threadIdx.x;
    int local[32];
    int s = 0;
    #pragma unroll
    for (int i = 0; i < 32; ++i) { local[i] = deg[i * 256 + t]; s += local[i]; }
    partial[t] = s;
    __syncthreads();
    for (int off = 1; off < 256; off <<= 1) {
        int v = (t >= off) ? partial[t - off] : 0;
        __syncthreads();
        partial[t] += v;
        __syncthreads();
    }
    int base = partial[t] - s;
    #pragma unroll
    for (int i = 0; i < 32; ++i) {
        int n = i * 256 + t;
        rowst[n] = base;
        cursor[n] = base;
        base += local[i];
    }
}

__global__ __launch_bounds__(256) void place_k(
    const int* __restrict__ ei, int* __restrict__ cursor, int* __restrict__ eidx)
{
    int e = blockIdx.x * 256 + threadIdx.x;
    int s = ei[e], d = ei[Ee + e];
    int pos = atomicAdd(&cursor[d], 1);
    eidx[pos] = s;
}

// ---------------- merged gather (blocks 0..2047) + QKV GEMM (2048..5119) ----------------
// R27: gather now reads xcat (bf16, 512B/row) instead of x (fp32, 1KB/row):
// halves the 134MB random-read traffic. Accuracy: agg feeds a bf16 MFMA, so
// inputs are bf16-rounded anyway; by linearity pre-vs-post-round summation
// differs well below the existing error band (fp32 accumulate kept).
__global__ __launch_bounds__(256, 4) void gather_qkv_k(
    const float* __restrict__ x, const int* __restrict__ rowst,
    const int* __restrict__ deg, const int* __restrict__ eidx,
    unsigned short* __restrict__ xcat,
    const unsigned short* __restrict__ WT,
    const float* __restrict__ bq, const float* __restrict__ bk,
    const float* __restrict__ bv,
    unsigned short* __restrict__ qb, unsigned short* __restrict__ kb,
    unsigned short* __restrict__ vTb, float qscale)
{
    __shared__ unsigned short vtile[64][40];
    int blk = blockIdx.x;

    if (blk < 2048) {
        // gather: 4 nodes per block, one 64-lane wave each (bf16 source)
        int n = blk * 4 + (threadIdx.x >> 6);
        int c4 = (threadIdx.x & 63) * 4;
        int b0 = rowst[n], d = deg[n];
        float4 acc = {0.f, 0.f, 0.f, 0.f};
        int i = 0;
        for (; i + 4 <= d; i += 4) {
            int s0 = eidx[b0 + i], s1 = eidx[b0 + i + 1];
            int s2 = eidx[b0 + i + 2], s3 = eidx[b0 + i + 3];
            ushort4 a0 = *(const ushort4*)(xcat + (size_t)s0 * 512 + c4);
            ushort4 a1 = *(const ushort4*)(xcat + (size_t)s1 * 512 + c4);
            ushort4 a2 = *(const ushort4*)(xcat + (size_t)s2 * 512 + c4);
            ushort4 a3 = *(const ushort4*)(xcat + (size_t)s3 * 512 + c4);
            acc.x += (b2f(a0.x) + b2f(a1.x)) + (b2f(a2.x) + b2f(a3.x));
            acc.y += (b2f(a0.y) + b2f(a1.y)) + (b2f(a2.y) + b2f(a3.y));
            acc.z += (b2f(a0.z) + b2f(a1.z)) + (b2f(a2.z) + b2f(a3.z));
            acc.w += (b2f(a0.w) + b2f(a1.w)) + (b2f(a2.w) + b2f(a3.w));
        }
        for (; i < d; ++i) {
            int s = eidx[b0 + i];
            ushort4 a = *(const ushort4*)(xcat + (size_t)s * 512 + c4);
            acc.x += b2f(a.x); acc.y += b2f(a.y);
            acc.z += b2f(a.z); acc.w += b2f(a.w);
        }
        ushort4 pk;
        pk.x = f2b(acc.x); pk.y = f2b(acc.y); pk.z = f2b(acc.z); pk.w = f2b(acc.w);
        *(ushort4*)(xcat + (size_t)n * 512 + 256 + c4) = pk;
        return;
    }

    // QKV GEMM, N=768 = [q|k|v]; reads xcat low half only (lda=512, K=256)
    int qblk = blk - 2048;
    const int n0 = (qblk % 12) * 64;
    const int m0 = (qblk / 12) * 32;
    const int t = threadIdx.x;
    const int wave = t >> 6, lane = t & 63;
    const int tl = lane & 15, g = lane >> 4;
    const int wr = wave >> 1, wc = wave & 1;
    const int which = n0 >> 8;               // 0:q 1:k 2:v
    const int K = 256, lda = 512;

    f32x4 acc[2] = {};

    const unsigned short* a0 = xcat + (size_t)(m0 + wr * 16 + tl) * lda + g * 8;
    const unsigned short* b0 = WT + (size_t)(n0 + wc * 32 + tl) * K + g * 8;
    const unsigned short* b1 = b0 + (size_t)16 * K;

    for (int k0 = 0; k0 < K; k0 += 32) {
        bf16x8 af  = ldb8(a0 + k0);
        bf16x8 bf0 = ldb8(b0 + k0), bf1 = ldb8(b1 + k0);
        acc[0] = __builtin_amdgcn_mfma_f32_16x16x32_bf16(af, bf0, acc[0], 0, 0, 0);
        acc[1] = __builtin_amdgcn_mfma_f32_16x16x32_bf16(af, bf1, acc[1], 0, 0, 0);
    }

    const float* bias = which == 0 ? bq : which == 1 ? bk : bv;
    const float sc = which == 0 ? qscale : 1.f;

    if (which < 2) {
        unsigned short* dst = which == 0 ? qb : kb;
        #pragma unroll
        for (int c16 = 0; c16 < 2; ++c16)
            #pragma unroll
            for (int reg = 0; reg < 4; ++reg) {
                int row = m0 + wr * 16 + g * 4 + reg;
                int col = (n0 & 255) + wc * 32 + c16 * 16 + tl;
                dst[(size_t)row * Cc + col] = f2b((acc[c16][reg] + bias[col]) * sc);
            }
    } else {
        #pragma unroll
        for (int c16 = 0; c16 < 2; ++c16)
            #pragma unroll
            for (int reg = 0; reg < 4; ++reg) {
                int colL = wc * 32 + c16 * 16 + tl;
                int rowL = wr * 16 + g * 4 + reg;
                vtile[colL][rowL] = f2b(acc[c16][reg] + bias[(n0 & 255) + colL]);
            }
        __syncthreads();
        int clocal = t >> 2, q = t & 3;
        int colg = (n0 & 255) + clocal;
        int hh = colg >> 5, dd = colg & 31;
        int bg = m0 >> 10, nb = (m0 & 1023) + q * 8;
        ushort4 u0 = *(ushort4*)&vtile[clocal][q * 8];
        ushort4 u1 = *(ushort4*)&vtile[clocal][q * 8 + 4];
        unsigned short* dst = vTb + ((size_t)((bg * Hh + hh) * DKh + dd)) * Nn + nb;
        *(ushort4*)dst = u0;
        *(ushort4*)(dst + 4) = u1;
    }
}

// ---------------- merged attention (blocks 0..511) + h1pre GEMM (512..767) ----------------
// R27: the untouched half of this dispatch — the h1pre GEMM — is the prime
// suspect for the ~92us floor (8 rounds of attn-side changes were all
// invariant). Old layout: 1024 tiles of 32x64, A-rows re-read 4x across
// n-tiles = 32MB of 1KB-stride L3 gathers. New: 256 blocks x one 32x256
// tile — A read ONCE (8MB), B (WcatT 256KB) L2-resident, MFMA:load 4:5.
// If the dispatch drops, GEMM was the pole; if not, GEMM is exonerated at
// zero cost. Attn side unchanged from R26 (m-step 128, raw v_exp, XCD pin).
__global__ __launch_bounds__(512, 8) void attn_h1_k(
    const unsigned short* __restrict__ q, const unsigned short* __restrict__ k,
    const unsigned short* __restrict__ vT, const float* __restrict__ sph,
    unsigned short* __restrict__ op0,
    const unsigned short* __restrict__ xcat, const unsigned short* __restrict__ WcatT,
    const float* __restrict__ x, unsigned short* __restrict__ h1preb,
    float* __restrict__ gsum, float* __restrict__ gsq)
{
    __shared__ float Sph[2][16][132];          // 2x16x132x4 = 16896 B
    __shared__ unsigned short Ps[Hh][16][72];  // 18432 B
    float* csum = (float*)&Ps[0][0][0];     // [256], aliased (gemm branch only)
    float* csq  = csum + 256;

    const int blk = blockIdx.x;
    const int t = threadIdx.x;
    const int wave = t >> 6;
    const int lane = t & 63;
    const int tl = lane & 15, g = lane >> 4;

    if (blk < 512) {
        // ---------- attention: 16 q-rows, full m-range, graph pinned to XCD ----------
        const int b  = blk & 7;             // graph == XCD (round-robin dispatch)
        const int n0 = (blk >> 3) * 16;     // 64 row-tiles per graph
        const int w  = wave;

        bf16x8 qf = ldb8(q + ((size_t)(b * Nn + n0 + tl)) * Cc + w * DKh + g * 8);

        float lsum = 0.f;
        f32x4 oacc[2] = {};

        const unsigned short* kbase = k + ((size_t)(b * Nn) + tl) * Cc + w * DKh + g * 8;
        const unsigned short* vbase = vT + ((size_t)((b * Hh + w) * DKh) + tl) * Nn + g * 8;
        const float* sbase = sph + ((size_t)b * Nn + n0) * Nn;

        // prologue: stage sph tile 0 (16x128) into buffer 0; 256 thr x 2 float4
        if (t < 256) {
            int r1 = t >> 4, c1 = (t & 15) * 8;
            const float* src = sbase + (size_t)r1 * Nn + c1;
            *(float4*)&Sph[0][r1][c1]     = *(const float4*)src;
            *(float4*)&Sph[0][r1][c1 + 4] = *(const float4*)(src + 4);
        }
        __syncthreads();

        int cur = 0;
        for (int it = 0; it < 8; ++it) {
            const int m0 = it * 128;
            // stage NEXT 16x128 tile into the other buffer
            if (it < 7 && t < 256) {
                int r1 = t >> 4, c1 = (t & 15) * 8;
                const float* src = sbase + (size_t)r1 * Nn + m0 + 128 + c1;
                *(float4*)&Sph[cur ^ 1][r1][c1]     = *(const float4*)src;
                *(float4*)&Sph[cur ^ 1][r1][c1 + 4] = *(const float4*)(src + 4);
            }

            #pragma unroll
            for (int half = 0; half < 2; ++half) {
                const int mh = m0 + half * 64;

                f32x4 st[4];
                #pragma unroll
                for (int mg = 0; mg < 4; ++mg) {
                    bf16x8 ka = ldb8(kbase + (size_t)(mh + mg * 16) * Cc);
                    f32x4 z = {0.f, 0.f, 0.f, 0.f};
                    st[mg] = __builtin_amdgcn_mfma_f32_16x16x32_bf16(ka, qf, z, 0, 0, 0);
                }

                #pragma unroll
                for (int mg = 0; mg < 4; ++mg) {
                    float4 sp = *(const float4*)&Sph[cur][tl][half * 64 + mg * 16 + g * 4];
                    float p0 = __builtin_amdgcn_exp2f(st[mg][0] * sp.x);
                    float p1 = __builtin_amdgcn_exp2f(st[mg][1] * sp.y);
                    float p2 = __builtin_amdgcn_exp2f(st[mg][2] * sp.z);
                    float p3 = __builtin_amdgcn_exp2f(st[mg][3] * sp.w);
                    lsum += (p0 + p1) + (p2 + p3);
                    ushort4 pk;
                    pk.x = f2b(p0); pk.y = f2b(p1); pk.z = f2b(p2); pk.w = f2b(p3);
                    *(ushort4*)&Ps[w][tl][mg * 16 + g * 4] = pk;
                }

                #pragma unroll
                for (int ks = 0; ks < 2; ++ks) {
                    bf16x8 pa = ldb8(&Ps[w][tl][ks * 32 + g * 8]);
                    #pragma unroll
                    for (int cg = 0; cg < 2; ++cg) {
                        bf16x8 vb = ldb8(vbase + (size_t)(cg * 16) * Nn + mh + ks * 32);
                        oacc[cg] = __builtin_amdgcn_mfma_f32_16x16x32_bf16(pa, vb, oacc[cg], 0, 0, 0);
                    }
                }
            }

            __syncthreads();   // staging writes visible; Sph[cur]/Ps reads complete
            cur ^= 1;
        }

        // full-row softmax denominator -> normalize O in-register.
        lsum += __shfl_xor(lsum, 16);
        lsum += __shfl_xor(lsum, 32);      // every lane: sum for q-row tl
        float* shl = (float*)&Ps[w][0][0]; // per-wave scratch (Ps dead now)
        if (g == 0) shl[tl] = lsum;        // wave-local write->read, no barrier
        #pragma unroll
        for (int r = 0; r < 4; ++r) {
            float inv = 1.f / shl[g * 4 + r];   // O row = g*4+r
            #pragma unroll
            for (int cg = 0; cg < 2; ++cg)
                op0[((size_t)(b * Nn + n0 + g * 4 + r)) * Cc + w * DKh + cg * 16 + tl]
                    = f2b(oacc[cg][r] * inv);
        }
        return;
    }

    // ---------- h1pre GEMM: one 32x256 tile per block (A read once) ----------
    const int wrg = wave >> 2;              // 0..1 row group
    const int wcg = wave & 3;               // 0..3 col group (64 cols each)
    const int m0g = (blk - 512) * 32;
    const int K = 512, N = Cc;

    if (t < 256) { csum[t] = 0.f; csq[t] = 0.f; }
    __syncthreads();

    f32x4 acc[4] = {};

    const unsigned short* a0 = xcat + (size_t)(m0g + wrg * 16 + tl) * 512 + g * 8;
    const unsigned short* bb = WcatT + (size_t)(wcg * 64 + tl) * K + g * 8;

    for (int k0 = 0; k0 < K; k0 += 32) {
        bf16x8 af = ldb8(a0 + k0);
        #pragma unroll
        for (int c16 = 0; c16 < 4; ++c16) {
            bf16x8 bf = ldb8(bb + (size_t)(c16 * 16) * K + k0);
            acc[c16] = __builtin_amdgcn_mfma_f32_16x16x32_bf16(af, bf, acc[c16], 0, 0, 0);
        }
    }

    #pragma unroll
    for (int c16 = 0; c16 < 4; ++c16) {
        int col = wcg * 64 + c16 * 16 + tl;
        float ls = 0.f, lq = 0.f;
        #pragma unroll
        for (int reg = 0; reg < 4; ++reg) {
            int row = m0g + wrg * 16 + g * 4 + reg;
            size_t idx = (size_t)row * N + col;
            float v = acc[c16][reg] + x[idx];
            ls += v; lq += v * v;               // stats in fp32 (pre-rounding)
            h1preb[idx] = f2b(v);
        }
        atomicAdd(&csum[col], ls);
        atomicAdd(&csq[col],  lq);
    }
    __syncthreads();
    if (t < 256) {
        atomicAdd(&gsum[t], csum[t]);
        atomicAdd(&gsq[t],  csq[t]);
    }
}

// ---------------- MFMA GEMM, 32x64 tile, optional bf16 residual + BN-stats ----------------
// TAG: 1 = mlp1 (N=512), 2 = mlp2 (K=512, bf16 residual addb = osb).
template<int TAG>
__global__ __launch_bounds__(256, 4) void gemm_mfma_k(
    const unsigned short* __restrict__ A, const unsigned short* __restrict__ WT,
    const float* __restrict__ bias, const unsigned short* __restrict__ addb,
    float* __restrict__ outf, unsigned short* __restrict__ outb,
    float* __restrict__ gsum, float* __restrict__ gsq,
    int M, int K, int lda, int N, int relu, float oscale)
{
    const int t = threadIdx.x;
    const int wave = t >> 6, lane = t & 63;
    const int tl = lane & 15, g = lane >> 4;
    const int wr = wave >> 1, wc = wave & 1;
    const int m0 = blockIdx.y * 32, n0 = blockIdx.x * 64;

    __shared__ float csum[64], csq[64];
    if (gsum) {
        if (t < 64) { csum[t] = 0.f; csq[t] = 0.f; }
        __syncthreads();
    }

    f32x4 acc[2] = {};

    const unsigned short* a0 = A  + (size_t)(m0 + wr * 16 + tl) * lda + g * 8;
    const unsigned short* b0 = WT + (size_t)(n0 + wc * 32 + tl) * K + g * 8;
    const unsigned short* b1 = b0 + (size_t)16 * K;

    for (int k0 = 0; k0 < K; k0 += 32) {
        bf16x8 af  = ldb8(a0 + k0);
        bf16x8 bf0 = ldb8(b0 + k0), bf1 = ldb8(b1 + k0);
        acc[0] = __builtin_amdgcn_mfma_f32_16x16x32_bf16(af, bf0, acc[0], 0, 0, 0);
        acc[1] = __builtin_amdgcn_mfma_f32_16x16x32_bf16(af, bf1, acc[1], 0, 0, 0);
    }

    #pragma unroll
    for (int c16 = 0; c16 < 2; ++c16) {
        int colL = wc * 32 + c16 * 16 + tl;
        int col  = n0 + colL;
        float ls = 0.f, lq = 0.f;
        #pragma unroll
        for (int reg = 0; reg < 4; ++reg) {
            int row = m0 + wr * 16 + g * 4 + reg;
            float v = acc[c16][reg];
            if (bias) v += bias[col];
            v *= oscale;
            size_t idx = (size_t)row * N + col;
            if (addb) v += b2f(addb[idx]);
            ls += v; lq += v * v;
            if (relu) v = fmaxf(v, 0.f);
            if (outf) outf[idx] = v;
            if (outb) outb[idx] = f2b(v);
        }
        if (gsum) { atomicAdd(&csum[colL], ls); atomicAdd(&csq[colL], lq); }
    }
    if (gsum) {
        __syncthreads();
        if (t < 64) {
            atomicAdd(&gsum[n0 + t], csum[t]);
            atomicAdd(&gsq[n0 + t],  csq[t]);
        }
    }
}

// ---------------- Wo GEMM (A = normalized bf16 O) + fp32 residual + BN2 stats ----------------
__global__ __launch_bounds__(256, 4) void gemm_attnA_k(
    const unsigned short* __restrict__ op0,
    const unsigned short* __restrict__ WT, const float* __restrict__ bias,
    const float* __restrict__ add1, unsigned short* __restrict__ h2preb,
    float* __restrict__ gsum, float* __restrict__ gsq)
{
    const int K = Cc, N = Cc;
    const int t = threadIdx.x;
    const int wave = t >> 6, lane = t & 63;
    const int tl = lane & 15, g = lane >> 4;
    const int wr = wave >> 1, wc = wave & 1;
    const int m0 = blockIdx.y * 32, n0 = blockIdx.x * 64;

    __shared__ float csum[64], csq[64];
    if (t < 64) { csum[t] = 0.f; csq[t] = 0.f; }
    __syncthreads();

    f32x4 acc[2] = {};

    const int arow = m0 + wr * 16 + tl;
    const unsigned short* a0b = op0 + (size_t)arow * K + g * 8;
    const unsigned short* b0 = WT + (size_t)(n0 + wc * 32 + tl) * K + g * 8;
    const unsigned short* b1 = b0 + (size_t)16 * K;

    for (int k0 = 0; k0 < K; k0 += 32) {
        bf16x8 af  = ldb8(a0b + k0);
        bf16x8 bf0 = ldb8(b0 + k0), bf1 = ldb8(b1 + k0);
        acc[0] = __builtin_amdgcn_mfma_f32_16x16x32_bf16(af, bf0, acc[0], 0, 0, 0);
        acc[1] = __builtin_amdgcn_mfma_f32_16x16x32_bf16(af, bf1, acc[1], 0, 0, 0);
    }

    #pragma unroll
    for (int c16 = 0; c16 < 2; ++c16) {
        int colL = wc * 32 + c16 * 16 + tl;
        int col  = n0 + colL;
        float ls = 0.f, lq = 0.f;
        #pragma unroll
        for (int reg = 0; reg < 4; ++reg) {
            int row = m0 + wr * 16 + g * 4 + reg;
            float v = acc[c16][reg] + bias[col];
            size_t idx = (size_t)row * N + col;
            v += add1[idx];
            ls += v; lq += v * v;               // stats in fp32 (pre-rounding)
            h2preb[idx] = f2b(v);
        }
        atomicAdd(&csum[colL], ls); atomicAdd(&csq[colL], lq);
    }
    __syncthreads();
    if (t < 64) {
        atomicAdd(&gsum[n0 + t], csum[t]);
        atomicAdd(&gsq[n0 + t],  csq[t]);
    }
}

// ---------------- BN apply (single, float4) ----------------
__global__ __launch_bounds__(256) void bn_apply_k(
    const float* __restrict__ h, const float* __restrict__ gsum,
    const float* __restrict__ gsq, const float* __restrict__ gamma,
    const float* __restrict__ beta, float* __restrict__ outf)
{
    size_t i4 = ((size_t)blockIdx.x * 256 + threadIdx.x) * 4;
    int ch = (int)(i4 & (Cc - 1));
    float4 hv = *(const float4*)(h + i4);
    float4 sm = *(const float4*)(gsum + ch);
    float4 sq = *(const float4*)(gsq + ch);
    float4 ga = *(const float4*)(gamma + ch);
    float4 be = *(const float4*)(beta + ch);
    float4 o;
    {
        float m = sm.x * (1.f / BNn), var = sq.x * (1.f / BNn) - m * m;
        o.x = (hv.x - m) * rsqrtf(var + EPSV) * ga.x + be.x;
    }
    {
        float m = sm.y * (1.f / BNn), var = sq.y * (1.f / BNn) - m * m;
        o.y = (hv.y - m) * rsqrtf(var + EPSV) * ga.y + be.y;
    }
    {
        float m = sm.z * (1.f / BNn), var = sq.z * (1.f / BNn) - m * m;
        o.z = (hv.z - m) * rsqrtf(var + EPSV) * ga.z + be.z;
    }
    {
        float m = sm.w * (1.f / BNn), var = sq.w * (1.f / BNn) - m * m;
        o.w = (hv.w - m) * rsqrtf(var + EPSV) * ga.w + be.w;
    }
    *(float4*)(outf + i4) = o;
}

// ---------------- fused BN1+BN2 apply (bf16 in / bf16 out, 12 MB total) ----------------
__global__ __launch_bounds__(256) void bn_apply12_k(
    const unsigned short* __restrict__ h1preb, const unsigned short* __restrict__ h2preb,
    const float* __restrict__ stats,
    const float* __restrict__ g1, const float* __restrict__ be1,
    const float* __restrict__ g2, const float* __restrict__ be2,
    unsigned short* __restrict__ outb)
{
    size_t i4 = ((size_t)blockIdx.x * 256 + threadIdx.x) * 4;
    int ch = (int)(i4 & (Cc - 1));
    ushort4 u1 = *(const ushort4*)(h1preb + i4);
    ushort4 u2 = *(const ushort4*)(h2preb + i4);
    float4 s1m = *(const float4*)(stats + ch);
    float4 s1q = *(const float4*)(stats + 256 + ch);
    float4 s2m = *(const float4*)(stats + 512 + ch);
    float4 s2q = *(const float4*)(stats + 768 + ch);
    float4 G1 = *(const float4*)(g1 + ch),  B1 = *(const float4*)(be1 + ch);
    float4 G2 = *(const float4*)(g2 + ch),  B2 = *(const float4*)(be2 + ch);
    ushort4 pk;
    #define BN12C(comp, ucomp) { \
        float m1 = s1m.comp * (1.f / BNn), v1 = s1q.comp * (1.f / BNn) - m1 * m1; \
        float m2 = s2m.comp * (1.f / BNn), v2 = s2q.comp * (1.f / BNn) - m2 * m2; \
        float o = (b2f(u1.ucomp) - m1) * rsqrtf(v1 + EPSV) * G1.comp + B1.comp \
                + (b2f(u2.ucomp) - m2) * rsqrtf(v2 + EPSV) * G2.comp + B2.comp; \
        pk.ucomp = f2b(o); }
    BN12C(x, x) BN12C(y, y) BN12C(z, z) BN12C(w, w)
    #undef BN12C
    *(ushort4*)(outb + i4) = pk;
}

// ---------------- launch ----------------
extern "C" void kernel_launch(void* const* d_in, const int* in_sizes, int n_in,
                              void* d_out, int out_size, void* d_ws, size_t ws_size,
                              hipStream_t stream)
{
    const float* x   = (const float*)d_in[0];
    const int*   ei  = (const int*)  d_in[1];
    const float* sph = (const float*)d_in[2];
    const float* Wr  = (const float*)d_in[3];
    const float* Wn  = (const float*)d_in[4];
    const float* Wq  = (const float*)d_in[5];
    const float* bq  = (const float*)d_in[6];
    const float* Wk  = (const float*)d_in[7];
    const float* bk  = (const float*)d_in[8];
    const float* Wv  = (const float*)d_in[9];
    const float* bv  = (const float*)d_in[10];
    const float* Wo  = (const float*)d_in[11];
    const float* bo  = (const float*)d_in[12];
    const float* W1  = (const float*)d_in[13];
    const float* b1  = (const float*)d_in[14];
    const float* W2  = (const float*)d_in[15];
    const float* b2  = (const float*)d_in[16];
    const float* g1  = (const float*)d_in[17];
    const float* be1 = (const float*)d_in[18];
    const float* g2  = (const float*)d_in[19];
    const float* be2 = (const float*)d_in[20];
    const float* g3  = (const float*)d_in[21];
    const float* be3 = (const float*)d_in[22];
    float* out = (float*)d_out;

    const size_t SL = (size_t)BNn * Cc;  // 2M elements

    float* ws = (float*)d_ws;
    float* s1 = ws;                  // op0b (bf16, 4MB)
    float* s2 = s1 + SL;             // h1preb (bf16) then out2 (fp32)
    float* s3 = s2 + SL;             // h2preb (bf16)

    int*   deg      = (int*)(s3 + SL);          // 8192
    float* statsAll = (float*)(deg + 8192);     // 1536
    int*   rowst    = (int*)(statsAll + 1536);  // 8192 (+pad)
    int*   cursor   = rowst + 8256;             // 8192
    int*   eidx     = cursor + 8192;            // 131072

    unsigned short* xcat = (unsigned short*)(eidx + 131072); // [8192][512]; reused as hid
    unsigned short* qb   = xcat + 2 * SL;
    unsigned short* kb   = qb + SL;                          // reused as osb
    unsigned short* vTb  = kb + SL;
    unsigned short* osb  = kb;
    unsigned short* hid  = xcat;

    unsigned short* WcatT = vTb + SL;         // 256x512
    unsigned short* WqT   = WcatT + 131072;   // WqT|WkT|WvT contiguous = [768][256]
    unsigned short* WkT   = WqT + 65536;
    unsigned short* WvT   = WkT + 65536;
    unsigned short* WoT   = WvT + 65536;
    unsigned short* W1T   = WoT + 65536;
    unsigned short* W2T   = W1T + 131072;
    unsigned short* op0b   = (unsigned short*)s1;
    unsigned short* h1preb = (unsigned short*)s2;   // 4MB of s2; dead before out2
    unsigned short* h2preb = (unsigned short*)s3;

    dim3 gN256(4, 256);
    dim3 gN512(8, 256);

    const float QSCALE = 0.17677669529663687f * 1.4426950408889634f;

    // 1) zero deg + all BN stats in one memset
    hipMemsetAsync(deg, 0, (8192 + 1536) * sizeof(float), stream);
    // 2) fused converts + histogram
    prep_k<<<5120, 256, 0, stream>>>(x, xcat, Wr, Wn, Wq, Wk, Wv, Wo, W1, W2,
                                     WcatT, WqT, WkT, WvT, WoT, W1T, W2T, ei, deg);
    // 3-4) CSR scan / place
    scan_k<<<1, 256, 0, stream>>>(deg, rowst, cursor);
    place_k<<<Ee / 256, 256, 0, stream>>>(ei, cursor, eidx);
    // 5) gather (xcat hi, bf16 source) || QKV GEMM (xcat lo -> qb,kb,vTb)
    gather_qkv_k<<<5120, 256, 0, stream>>>(x, rowst, deg, eidx, xcat,
                                           WqT, bq, bk, bv, qb, kb, vTb, QSCALE);
    // 6) attention || h1pre GEMM (32x256 tiles, A read once) — 768 blocks
    attn_h1_k<<<768, 512, 0, stream>>>(qb, kb, vTb, sph, op0b,
                                       xcat, WcatT, x, h1preb,
                                       statsAll, statsAll + 256);
    // 7) h2pre = O @ Wo + bo + x -> bf16, + BN2 stats
    gemm_attnA_k<<<gN256, 256, 0, stream>>>(op0b, WoT, bo, x,
                                            h2preb, statsAll + 512, statsAll + 768);
    // 8) osb = bn1(h1pre) + bn2(h2pre)   (bf16 in/out, 12 MB pass)
    bn_apply12_k<<<(int)(SL / 1024), 256, 0, stream>>>(h1preb, h2preb, statsAll,
                                                       g1, be1, g2, be2, osb);
    // 9) hidden = relu(osb @ W1 + b1) -> hid (bf16)
    gemm_mfma_k<1><<<gN512, 256, 0, stream>>>(osb, W1T, b1, nullptr,
                                              nullptr, hid, nullptr, nullptr,
                                              BNn, Cc, Cc, 2 * Cc, 1, 1.f);
    // 10) out2 = hid @ W2 + b2 + osb(residual, bf16) -> s2 fp32, + BN3 stats
    gemm_mfma_k<2><<<gN256, 256, 0, stream>>>(hid, W2T, b2, osb,
                                              s2, nullptr, statsAll + 1024, statsAll + 1280,
                                              BNn, 2 * Cc, 2 * Cc, Cc, 0, 1.f);
    // 11) d_out = BN3(out2)
    bn_apply_k<<<(int)(SL / 1024), 256, 0, stream>>>(s2, statsAll + 1024,
                                                     statsAll + 1280, g3, be3, out);
}

// Round 13
// 358.557 us; speedup vs baseline: 1.0374x; 1.0003x over previous
//
#include <hip/hip_runtime.h>
#include <hip/hip_bf16.h>

// ---------------- problem constants ----------------
constexpr int Bg  = 8;       // graphs
constexpr int Nn  = 1024;    // nodes per graph
constexpr int Cc  = 256;     // channels
constexpr int Hh  = 8;       // heads
constexpr int DKh = 32;      // head dim
constexpr int Ee  = 131072;  // edges
constexpr int BNn = Bg * Nn; // 8192 total nodes
#define EPSV 1e-5f

typedef __attribute__((ext_vector_type(8))) short bf16x8;
typedef __attribute__((ext_vector_type(4))) float f32x4;

static __device__ __forceinline__ unsigned short f2b(float v) {
    __hip_bfloat16 h = __float2bfloat16(v);
    return __builtin_bit_cast(unsigned short, h);
}
static __device__ __forceinline__ float b2f(unsigned short u) {
    unsigned int x = ((unsigned int)u) << 16;
    return __builtin_bit_cast(float, x);
}
static __device__ __forceinline__ bf16x8 ldb8(const unsigned short* p) {
    return *(const bf16x8*)p;
}

// ---------------- fused prep: xconv + wconv + hist ----------------
__global__ __launch_bounds__(256) void prep_k(
    const float* __restrict__ x, unsigned short* __restrict__ xcat,
    const float* __restrict__ Wr, const float* __restrict__ Wn,
    const float* __restrict__ Wq, const float* __restrict__ Wk,
    const float* __restrict__ Wv, const float* __restrict__ Wo,
    const float* __restrict__ W1, const float* __restrict__ W2,
    unsigned short* __restrict__ WcatT,
    unsigned short* __restrict__ WqT, unsigned short* __restrict__ WkT,
    unsigned short* __restrict__ WvT, unsigned short* __restrict__ WoT,
    unsigned short* __restrict__ W1T, unsigned short* __restrict__ W2T,
    const int* __restrict__ ei, int* __restrict__ deg)
{
    int blk = blockIdx.x;
    if (blk < 2048) {
        int i = (blk * 256 + threadIdx.x) * 4;
        float4 v = *(const float4*)(x + i);
        int r = i >> 8, c = i & 255;
        ushort4 pk;
        pk.x = f2b(v.x); pk.y = f2b(v.y); pk.z = f2b(v.z); pk.w = f2b(v.w);
        *(ushort4*)(xcat + (size_t)r * 512 + c) = pk;
    } else if (blk < 4608) {
        int idx = (blk - 2048) * 256 + threadIdx.x;
        if (idx < 131072) {                      // WcatT [256][512]
            int n = idx >> 9, k = idx & 511;
            float v = (k < 256) ? Wr[k * 256 + n] : Wn[(k - 256) * 256 + n];
            WcatT[(size_t)n * 512 + k] = f2b(v);
        } else if (idx < 393216) {               // q,k,v,o
            int l = idx - 131072;
            int wsel = l >> 16; l &= 65535;
            int n = l >> 8, kk = l & 255;
            const float* S = wsel == 0 ? Wq : wsel == 1 ? Wk : wsel == 2 ? Wv : Wo;
            unsigned short* D = wsel == 0 ? WqT : wsel == 1 ? WkT : wsel == 2 ? WvT : WoT;
            D[n * 256 + kk] = f2b(S[kk * 256 + n]);
        } else if (idx < 524288) {               // W1 [256][512] -> W1T [512][256]
            int l = idx - 393216;
            int n = l >> 8, kk = l & 255;
            W1T[l] = f2b(W1[kk * 512 + n]);
        } else {                                 // W2 [512][256] -> W2T [256][512]
            int l = idx - 524288;
            int n = l >> 9, kk = l & 511;
            W2T[l] = f2b(W2[kk * 256 + n]);
        }
    } else {
        int e = (blk - 4608) * 256 + threadIdx.x;
        atomicAdd(&deg[ei[Ee + e]], 1);
    }
}

// ---------------- CSR scan (coalesced, interleaved buckets) ----------------
__global__ __launch_bounds__(256) void scan_k(
    const int* __restrict__ deg, int* __restrict__ rowst, int* __restrict__ cursor)
{
    __shared__ int partial[256];
    int t = threadIdx.x;
    int local[32];
    int s = 0;
    #pragma unroll
    for (int i = 0; i < 32; ++i) { local[i] = deg[i * 256 + t]; s += local[i]; }
    partial[t] = s;
    __syncthreads();
    for (int off = 1; off < 256; off <<= 1) {
        int v = (t >= off) ? partial[t - off] : 0;
        __syncthreads();
        partial[t] += v;
        __syncthreads();
    }
    int base = partial[t] - s;
    #pragma unroll
    for (int i = 0; i < 32; ++i) {
        int n = i * 256 + t;
        rowst[n] = base;
        cursor[n] = base;
        base += local[i];
    }
}

__global__ __launch_bounds__(256) void place_k(
    const int* __restrict__ ei, int* __restrict__ cursor, int* __restrict__ eidx)
{
    int e = blockIdx.x * 256 + threadIdx.x;
    int s = ei[e], d = ei[Ee + e];
    int pos = atomicAdd(&cursor[d], 1);
    eidx[pos] = s;
}

// ---------------- merged gather (blocks 0..2047) + QKV GEMM (2048..5119) ----------------
__global__ __launch_bounds__(256, 4) void gather_qkv_k(
    const float* __restrict__ x, const int* __restrict__ rowst,
    const int* __restrict__ deg, const int* __restrict__ eidx,
    unsigned short* __restrict__ xcat,
    const unsigned short* __restrict__ WT,
    const float* __restrict__ bq, const float* __restrict__ bk,
    const float* __restrict__ bv,
    unsigned short* __restrict__ qb, unsigned short* __restrict__ kb,
    unsigned short* __restrict__ vTb, float qscale)
{
    __shared__ unsigned short vtile[64][40];
    int blk = blockIdx.x;

    if (blk < 2048) {
        // gather: 4 nodes per block, one 64-lane wave each (bf16 source)
        int n = blk * 4 + (threadIdx.x >> 6);
        int c4 = (threadIdx.x & 63) * 4;
        int b0 = rowst[n], d = deg[n];
        float4 acc = {0.f, 0.f, 0.f, 0.f};
        int i = 0;
        for (; i + 4 <= d; i += 4) {
            int s0 = eidx[b0 + i], s1 = eidx[b0 + i + 1];
            int s2 = eidx[b0 + i + 2], s3 = eidx[b0 + i + 3];
            ushort4 a0 = *(const ushort4*)(xcat + (size_t)s0 * 512 + c4);
            ushort4 a1 = *(const ushort4*)(xcat + (size_t)s1 * 512 + c4);
            ushort4 a2 = *(const ushort4*)(xcat + (size_t)s2 * 512 + c4);
            ushort4 a3 = *(const ushort4*)(xcat + (size_t)s3 * 512 + c4);
            acc.x += (b2f(a0.x) + b2f(a1.x)) + (b2f(a2.x) + b2f(a3.x));
            acc.y += (b2f(a0.y) + b2f(a1.y)) + (b2f(a2.y) + b2f(a3.y));
            acc.z += (b2f(a0.z) + b2f(a1.z)) + (b2f(a2.z) + b2f(a3.z));
            acc.w += (b2f(a0.w) + b2f(a1.w)) + (b2f(a2.w) + b2f(a3.w));
        }
        for (; i < d; ++i) {
            int s = eidx[b0 + i];
            ushort4 a = *(const ushort4*)(xcat + (size_t)s * 512 + c4);
            acc.x += b2f(a.x); acc.y += b2f(a.y);
            acc.z += b2f(a.z); acc.w += b2f(a.w);
        }
        ushort4 pk;
        pk.x = f2b(acc.x); pk.y = f2b(acc.y); pk.z = f2b(acc.z); pk.w = f2b(acc.w);
        *(ushort4*)(xcat + (size_t)n * 512 + 256 + c4) = pk;
        return;
    }

    // QKV GEMM, N=768 = [q|k|v]; reads xcat low half only (lda=512, K=256)
    int qblk = blk - 2048;
    const int n0 = (qblk % 12) * 64;
    const int m0 = (qblk / 12) * 32;
    const int t = threadIdx.x;
    const int wave = t >> 6, lane = t & 63;
    const int tl = lane & 15, g = lane >> 4;
    const int wr = wave >> 1, wc = wave & 1;
    const int which = n0 >> 8;               // 0:q 1:k 2:v
    const int K = 256, lda = 512;

    f32x4 acc[2] = {};

    const unsigned short* a0 = xcat + (size_t)(m0 + wr * 16 + tl) * lda + g * 8;
    const unsigned short* b0 = WT + (size_t)(n0 + wc * 32 + tl) * K + g * 8;
    const unsigned short* b1 = b0 + (size_t)16 * K;

    for (int k0 = 0; k0 < K; k0 += 32) {
        bf16x8 af  = ldb8(a0 + k0);
        bf16x8 bf0 = ldb8(b0 + k0), bf1 = ldb8(b1 + k0);
        acc[0] = __builtin_amdgcn_mfma_f32_16x16x32_bf16(af, bf0, acc[0], 0, 0, 0);
        acc[1] = __builtin_amdgcn_mfma_f32_16x16x32_bf16(af, bf1, acc[1], 0, 0, 0);
    }

    const float* bias = which == 0 ? bq : which == 1 ? bk : bv;
    const float sc = which == 0 ? qscale : 1.f;

    if (which < 2) {
        unsigned short* dst = which == 0 ? qb : kb;
        #pragma unroll
        for (int c16 = 0; c16 < 2; ++c16)
            #pragma unroll
            for (int reg = 0; reg < 4; ++reg) {
                int row = m0 + wr * 16 + g * 4 + reg;
                int col = (n0 & 255) + wc * 32 + c16 * 16 + tl;
                dst[(size_t)row * Cc + col] = f2b((acc[c16][reg] + bias[col]) * sc);
            }
    } else {
        #pragma unroll
        for (int c16 = 0; c16 < 2; ++c16)
            #pragma unroll
            for (int reg = 0; reg < 4; ++reg) {
                int colL = wc * 32 + c16 * 16 + tl;
                int rowL = wr * 16 + g * 4 + reg;
                vtile[colL][rowL] = f2b(acc[c16][reg] + bias[(n0 & 255) + colL]);
            }
        __syncthreads();
        int clocal = t >> 2, q = t & 3;
        int colg = (n0 & 255) + clocal;
        int hh = colg >> 5, dd = colg & 31;
        int bg = m0 >> 10, nb = (m0 & 1023) + q * 8;
        ushort4 u0 = *(ushort4*)&vtile[clocal][q * 8];
        ushort4 u1 = *(ushort4*)&vtile[clocal][q * 8 + 4];
        unsigned short* dst = vTb + ((size_t)((bg * Hh + hh) * DKh + dd)) * Nn + nb;
        *(ushort4*)dst = u0;
        *(ushort4*)(dst + 4) = u1;
    }
}

// ---------------- merged attention (blocks 0..511) + h1pre GEMM (512..767) ----------------
// R28: in-wave load-latency pipelining. The smoking gun across R19-R27 was
// VGPR_Count=32: the compiler had NO register budget to prefetch, so each
// half-step serialized K-load(~300cy) -> QK -> softmax -> V-load(~300cy)
// -> PV, x16. Invisible to barrier/traffic/occupancy levers (all null).
// Fixes: (1) K double-buffered in registers (kaA/kaB, 2-half unrolled body,
// static indices); (2) V loads hoisted ABOVE softmax (issued before the K
// prefetch so PV's vmcnt wait doesn't drain it); (3) sph staged by waves
// 0-1 only, load-at-top/ds_write-at-bottom (T14, same-iteration lifetime,
// no cross-barrier spill); 6 of 8 waves have a pure K/V vmcnt chain.
// VGPR ~100 -> launch_bounds(512,4): 2 blocks/CU. Occupancy is not the
// lever (R20/R25 proved it); per-wave MLP is.
__global__ __launch_bounds__(512, 4) void attn_h1_k(
    const unsigned short* __restrict__ q, const unsigned short* __restrict__ k,
    const unsigned short* __restrict__ vT, const float* __restrict__ sph,
    unsigned short* __restrict__ op0,
    const unsigned short* __restrict__ xcat, const unsigned short* __restrict__ WcatT,
    const float* __restrict__ x, unsigned short* __restrict__ h1preb,
    float* __restrict__ gsum, float* __restrict__ gsq)
{
    __shared__ float Sph[2][16][132];          // 16896 B
    __shared__ unsigned short Ps[Hh][16][72];  // 18432 B
    float* csum = (float*)&Ps[0][0][0];     // [256], aliased (gemm branch only)
    float* csq  = csum + 256;

    const int blk = blockIdx.x;
    const int t = threadIdx.x;
    const int wave = t >> 6;
    const int lane = t & 63;
    const int tl = lane & 15, g = lane >> 4;

    if (blk < 512) {
        // ---------- attention: 16 q-rows, full m-range, graph pinned to XCD ----------
        const int b  = blk & 7;             // graph == XCD (round-robin dispatch)
        const int n0 = (blk >> 3) * 16;     // 64 row-tiles per graph
        const int w  = wave;

        bf16x8 qf = ldb8(q + ((size_t)(b * Nn + n0 + tl)) * Cc + w * DKh + g * 8);

        float lsum = 0.f;
        f32x4 oacc[2] = {};

        const unsigned short* kbase = k + ((size_t)(b * Nn) + tl) * Cc + w * DKh + g * 8;
        const unsigned short* vbase = vT + ((size_t)((b * Hh + w) * DKh) + tl) * Nn + g * 8;
        const float* sbase = sph + ((size_t)b * Nn + n0) * Nn;

        // sph staging geometry: waves 0-1 (t<128), 4 float4/thread per tile
        const int sr = t >> 3, sc = (t & 7) * 16;

        // prologue: stage sph tile 0 (16x128) into buffer 0
        if (t < 128) {
            const float* src = sbase + (size_t)sr * Nn + sc;
            *(float4*)&Sph[0][sr][sc + 0]  = *(const float4*)(src + 0);
            *(float4*)&Sph[0][sr][sc + 4]  = *(const float4*)(src + 4);
            *(float4*)&Sph[0][sr][sc + 8]  = *(const float4*)(src + 8);
            *(float4*)&Sph[0][sr][sc + 12] = *(const float4*)(src + 12);
        }

        // K preload for half-step 0 (m = 0..63)
        bf16x8 kaA[4], kaB[4];
        #pragma unroll
        for (int mg = 0; mg < 4; ++mg)
            kaA[mg] = ldb8(kbase + (size_t)(mg * 16) * Cc);

        __syncthreads();

        int cur = 0;
        for (int it = 0; it < 8; ++it) {
            // sph loads for tile it+1 at TOP (ds_write deferred to bottom)
            float4 s0, s1, s2, s3;
            if (t < 128 && it < 7) {
                const float* src = sbase + (size_t)sr * Nn + (it + 1) * 128 + sc;
                s0 = *(const float4*)(src + 0);
                s1 = *(const float4*)(src + 4);
                s2 = *(const float4*)(src + 8);
                s3 = *(const float4*)(src + 12);
            }

            // ======== half 0: compute with kaA @ mh, prefetch kaB @ mh+64 ========
            {
                const int mh = it * 128;
                // V loads first (PV's wait won't drain the K prefetch)
                bf16x8 v00 = ldb8(vbase + mh);
                bf16x8 v10 = ldb8(vbase + (size_t)16 * Nn + mh);
                bf16x8 v01 = ldb8(vbase + mh + 32);
                bf16x8 v11 = ldb8(vbase + (size_t)16 * Nn + mh + 32);
                // K prefetch for half 1
                kaB[0] = ldb8(kbase + (size_t)(mh + 64)  * Cc);
                kaB[1] = ldb8(kbase + (size_t)(mh + 80)  * Cc);
                kaB[2] = ldb8(kbase + (size_t)(mh + 96)  * Cc);
                kaB[3] = ldb8(kbase + (size_t)(mh + 112) * Cc);

                f32x4 st[4];
                #pragma unroll
                for (int mg = 0; mg < 4; ++mg) {
                    f32x4 z = {0.f, 0.f, 0.f, 0.f};
                    st[mg] = __builtin_amdgcn_mfma_f32_16x16x32_bf16(kaA[mg], qf, z, 0, 0, 0);
                }
                #pragma unroll
                for (int mg = 0; mg < 4; ++mg) {
                    float4 sp = *(const float4*)&Sph[cur][tl][mg * 16 + g * 4];
                    float p0 = __builtin_amdgcn_exp2f(st[mg][0] * sp.x);
                    float p1 = __builtin_amdgcn_exp2f(st[mg][1] * sp.y);
                    float p2 = __builtin_amdgcn_exp2f(st[mg][2] * sp.z);
                    float p3 = __builtin_amdgcn_exp2f(st[mg][3] * sp.w);
                    lsum += (p0 + p1) + (p2 + p3);
                    ushort4 pk;
                    pk.x = f2b(p0); pk.y = f2b(p1); pk.z = f2b(p2); pk.w = f2b(p3);
                    *(ushort4*)&Ps[w][tl][mg * 16 + g * 4] = pk;
                }
                bf16x8 pa0 = ldb8(&Ps[w][tl][g * 8]);
                oacc[0] = __builtin_amdgcn_mfma_f32_16x16x32_bf16(pa0, v00, oacc[0], 0, 0, 0);
                oacc[1] = __builtin_amdgcn_mfma_f32_16x16x32_bf16(pa0, v10, oacc[1], 0, 0, 0);
                bf16x8 pa1 = ldb8(&Ps[w][tl][32 + g * 8]);
                oacc[0] = __builtin_amdgcn_mfma_f32_16x16x32_bf16(pa1, v01, oacc[0], 0, 0, 0);
                oacc[1] = __builtin_amdgcn_mfma_f32_16x16x32_bf16(pa1, v11, oacc[1], 0, 0, 0);
            }

            // ======== half 1: compute with kaB @ mh, prefetch kaA @ mh+64 ========
            {
                const int mh = it * 128 + 64;
                bf16x8 v00 = ldb8(vbase + mh);
                bf16x8 v10 = ldb8(vbase + (size_t)16 * Nn + mh);
                bf16x8 v01 = ldb8(vbase + mh + 32);
                bf16x8 v11 = ldb8(vbase + (size_t)16 * Nn + mh + 32);
                if (it < 7) {
                    kaA[0] = ldb8(kbase + (size_t)(mh + 64)  * Cc);
                    kaA[1] = ldb8(kbase + (size_t)(mh + 80)  * Cc);
                    kaA[2] = ldb8(kbase + (size_t)(mh + 96)  * Cc);
                    kaA[3] = ldb8(kbase + (size_t)(mh + 112) * Cc);
                }

                f32x4 st[4];
                #pragma unroll
                for (int mg = 0; mg < 4; ++mg) {
                    f32x4 z = {0.f, 0.f, 0.f, 0.f};
                    st[mg] = __builtin_amdgcn_mfma_f32_16x16x32_bf16(kaB[mg], qf, z, 0, 0, 0);
                }
                #pragma unroll
                for (int mg = 0; mg < 4; ++mg) {
                    float4 sp = *(const float4*)&Sph[cur][tl][64 + mg * 16 + g * 4];
                    float p0 = __builtin_amdgcn_exp2f(st[mg][0] * sp.x);
                    float p1 = __builtin_amdgcn_exp2f(st[mg][1] * sp.y);
                    float p2 = __builtin_amdgcn_exp2f(st[mg][2] * sp.z);
                    float p3 = __builtin_amdgcn_exp2f(st[mg][3] * sp.w);
                    lsum += (p0 + p1) + (p2 + p3);
                    ushort4 pk;
                    pk.x = f2b(p0); pk.y = f2b(p1); pk.z = f2b(p2); pk.w = f2b(p3);
                    *(ushort4*)&Ps[w][tl][mg * 16 + g * 4] = pk;
                }
                bf16x8 pa0 = ldb8(&Ps[w][tl][g * 8]);
                oacc[0] = __builtin_amdgcn_mfma_f32_16x16x32_bf16(pa0, v00, oacc[0], 0, 0, 0);
                oacc[1] = __builtin_amdgcn_mfma_f32_16x16x32_bf16(pa0, v10, oacc[1], 0, 0, 0);
                bf16x8 pa1 = ldb8(&Ps[w][tl][32 + g * 8]);
                oacc[0] = __builtin_amdgcn_mfma_f32_16x16x32_bf16(pa1, v01, oacc[0], 0, 0, 0);
                oacc[1] = __builtin_amdgcn_mfma_f32_16x16x32_bf16(pa1, v11, oacc[1], 0, 0, 0);
            }

            // sph ds_write at BOTTOM (loads issued at top have flown under compute)
            if (t < 128 && it < 7) {
                float* dst = &Sph[cur ^ 1][sr][sc];
                *(float4*)(dst + 0)  = s0;
                *(float4*)(dst + 4)  = s1;
                *(float4*)(dst + 8)  = s2;
                *(float4*)(dst + 12) = s3;
            }
            __syncthreads();   // staging visible; Sph[cur]/Ps reads complete
            cur ^= 1;
        }

        // full-row softmax denominator -> normalize O in-register.
        lsum += __shfl_xor(lsum, 16);
        lsum += __shfl_xor(lsum, 32);      // every lane: sum for q-row tl
        float* shl = (float*)&Ps[w][0][0]; // per-wave scratch (Ps dead now)
        if (g == 0) shl[tl] = lsum;        // wave-local write->read, no barrier
        #pragma unroll
        for (int r = 0; r < 4; ++r) {
            float inv = 1.f / shl[g * 4 + r];   // O row = g*4+r
            #pragma unroll
            for (int cg = 0; cg < 2; ++cg)
                op0[((size_t)(b * Nn + n0 + g * 4 + r)) * Cc + w * DKh + cg * 16 + tl]
                    = f2b(oacc[cg][r] * inv);
        }
        return;
    }

    // ---------- h1pre GEMM: one 32x256 tile per block (A read once) ----------
    const int wrg = wave >> 2;              // 0..1 row group
    const int wcg = wave & 3;               // 0..3 col group (64 cols each)
    const int m0g = (blk - 512) * 32;
    const int K = 512, N = Cc;

    if (t < 256) { csum[t] = 0.f; csq[t] = 0.f; }
    __syncthreads();

    f32x4 acc[4] = {};

    const unsigned short* a0 = xcat + (size_t)(m0g + wrg * 16 + tl) * 512 + g * 8;
    const unsigned short* bb = WcatT + (size_t)(wcg * 64 + tl) * K + g * 8;

    for (int k0 = 0; k0 < K; k0 += 32) {
        bf16x8 af = ldb8(a0 + k0);
        #pragma unroll
        for (int c16 = 0; c16 < 4; ++c16) {
            bf16x8 bf = ldb8(bb + (size_t)(c16 * 16) * K + k0);
            acc[c16] = __builtin_amdgcn_mfma_f32_16x16x32_bf16(af, bf, acc[c16], 0, 0, 0);
        }
    }

    #pragma unroll
    for (int c16 = 0; c16 < 4; ++c16) {
        int col = wcg * 64 + c16 * 16 + tl;
        float ls = 0.f, lq = 0.f;
        #pragma unroll
        for (int reg = 0; reg < 4; ++reg) {
            int row = m0g + wrg * 16 + g * 4 + reg;
            size_t idx = (size_t)row * N + col;
            float v = acc[c16][reg] + x[idx];
            ls += v; lq += v * v;               // stats in fp32 (pre-rounding)
            h1preb[idx] = f2b(v);
        }
        atomicAdd(&csum[col], ls);
        atomicAdd(&csq[col],  lq);
    }
    __syncthreads();
    if (t < 256) {
        atomicAdd(&gsum[t], csum[t]);
        atomicAdd(&gsq[t],  csq[t]);
    }
}

// ---------------- MFMA GEMM, 32x64 tile, optional bf16 residual + BN-stats ----------------
// TAG: 1 = mlp1 (N=512), 2 = mlp2 (K=512, bf16 residual addb = osb).
template<int TAG>
__global__ __launch_bounds__(256, 4) void gemm_mfma_k(
    const unsigned short* __restrict__ A, const unsigned short* __restrict__ WT,
    const float* __restrict__ bias, const unsigned short* __restrict__ addb,
    float* __restrict__ outf, unsigned short* __restrict__ outb,
    float* __restrict__ gsum, float* __restrict__ gsq,
    int M, int K, int lda, int N, int relu, float oscale)
{
    const int t = threadIdx.x;
    const int wave = t >> 6, lane = t & 63;
    const int tl = lane & 15, g = lane >> 4;
    const int wr = wave >> 1, wc = wave & 1;
    const int m0 = blockIdx.y * 32, n0 = blockIdx.x * 64;

    __shared__ float csum[64], csq[64];
    if (gsum) {
        if (t < 64) { csum[t] = 0.f; csq[t] = 0.f; }
        __syncthreads();
    }

    f32x4 acc[2] = {};

    const unsigned short* a0 = A  + (size_t)(m0 + wr * 16 + tl) * lda + g * 8;
    const unsigned short* b0 = WT + (size_t)(n0 + wc * 32 + tl) * K + g * 8;
    const unsigned short* b1 = b0 + (size_t)16 * K;

    for (int k0 = 0; k0 < K; k0 += 32) {
        bf16x8 af  = ldb8(a0 + k0);
        bf16x8 bf0 = ldb8(b0 + k0), bf1 = ldb8(b1 + k0);
        acc[0] = __builtin_amdgcn_mfma_f32_16x16x32_bf16(af, bf0, acc[0], 0, 0, 0);
        acc[1] = __builtin_amdgcn_mfma_f32_16x16x32_bf16(af, bf1, acc[1], 0, 0, 0);
    }

    #pragma unroll
    for (int c16 = 0; c16 < 2; ++c16) {
        int colL = wc * 32 + c16 * 16 + tl;
        int col  = n0 + colL;
        float ls = 0.f, lq = 0.f;
        #pragma unroll
        for (int reg = 0; reg < 4; ++reg) {
            int row = m0 + wr * 16 + g * 4 + reg;
            float v = acc[c16][reg];
            if (bias) v += bias[col];
            v *= oscale;
            size_t idx = (size_t)row * N + col;
            if (addb) v += b2f(addb[idx]);
            ls += v; lq += v * v;
            if (relu) v = fmaxf(v, 0.f);
            if (outf) outf[idx] = v;
            if (outb) outb[idx] = f2b(v);
        }
        if (gsum) { atomicAdd(&csum[colL], ls); atomicAdd(&csq[colL], lq); }
    }
    if (gsum) {
        __syncthreads();
        if (t < 64) {
            atomicAdd(&gsum[n0 + t], csum[t]);
            atomicAdd(&gsq[n0 + t],  csq[t]);
        }
    }
}

// ---------------- Wo GEMM (A = normalized bf16 O) + fp32 residual + BN2 stats ----------------
__global__ __launch_bounds__(256, 4) void gemm_attnA_k(
    const unsigned short* __restrict__ op0,
    const unsigned short* __restrict__ WT, const float* __restrict__ bias,
    const float* __restrict__ add1, unsigned short* __restrict__ h2preb,
    float* __restrict__ gsum, float* __restrict__ gsq)
{
    const int K = Cc, N = Cc;
    const int t = threadIdx.x;
    const int wave = t >> 6, lane = t & 63;
    const int tl = lane & 15, g = lane >> 4;
    const int wr = wave >> 1, wc = wave & 1;
    const int m0 = blockIdx.y * 32, n0 = blockIdx.x * 64;

    __shared__ float csum[64], csq[64];
    if (t < 64) { csum[t] = 0.f; csq[t] = 0.f; }
    __syncthreads();

    f32x4 acc[2] = {};

    const int arow = m0 + wr * 16 + tl;
    const unsigned short* a0b = op0 + (size_t)arow * K + g * 8;
    const unsigned short* b0 = WT + (size_t)(n0 + wc * 32 + tl) * K + g * 8;
    const unsigned short* b1 = b0 + (size_t)16 * K;

    for (int k0 = 0; k0 < K; k0 += 32) {
        bf16x8 af  = ldb8(a0b + k0);
        bf16x8 bf0 = ldb8(b0 + k0), bf1 = ldb8(b1 + k0);
        acc[0] = __builtin_amdgcn_mfma_f32_16x16x32_bf16(af, bf0, acc[0], 0, 0, 0);
        acc[1] = __builtin_amdgcn_mfma_f32_16x16x32_bf16(af, bf1, acc[1], 0, 0, 0);
    }

    #pragma unroll
    for (int c16 = 0; c16 < 2; ++c16) {
        int colL = wc * 32 + c16 * 16 + tl;
        int col  = n0 + colL;
        float ls = 0.f, lq = 0.f;
        #pragma unroll
        for (int reg = 0; reg < 4; ++reg) {
            int row = m0 + wr * 16 + g * 4 + reg;
            float v = acc[c16][reg] + bias[col];
            size_t idx = (size_t)row * N + col;
            v += add1[idx];
            ls += v; lq += v * v;               // stats in fp32 (pre-rounding)
            h2preb[idx] = f2b(v);
        }
        atomicAdd(&csum[colL], ls); atomicAdd(&csq[colL], lq);
    }
    __syncthreads();
    if (t < 64) {
        atomicAdd(&gsum[n0 + t], csum[t]);
        atomicAdd(&gsq[n0 + t],  csq[t]);
    }
}

// ---------------- BN apply (single, float4) ----------------
__global__ __launch_bounds__(256) void bn_apply_k(
    const float* __restrict__ h, const float* __restrict__ gsum,
    const float* __restrict__ gsq, const float* __restrict__ gamma,
    const float* __restrict__ beta, float* __restrict__ outf)
{
    size_t i4 = ((size_t)blockIdx.x * 256 + threadIdx.x) * 4;
    int ch = (int)(i4 & (Cc - 1));
    float4 hv = *(const float4*)(h + i4);
    float4 sm = *(const float4*)(gsum + ch);
    float4 sq = *(const float4*)(gsq + ch);
    float4 ga = *(const float4*)(gamma + ch);
    float4 be = *(const float4*)(beta + ch);
    float4 o;
    {
        float m = sm.x * (1.f / BNn), var = sq.x * (1.f / BNn) - m * m;
        o.x = (hv.x - m) * rsqrtf(var + EPSV) * ga.x + be.x;
    }
    {
        float m = sm.y * (1.f / BNn), var = sq.y * (1.f / BNn) - m * m;
        o.y = (hv.y - m) * rsqrtf(var + EPSV) * ga.y + be.y;
    }
    {
        float m = sm.z * (1.f / BNn), var = sq.z * (1.f / BNn) - m * m;
        o.z = (hv.z - m) * rsqrtf(var + EPSV) * ga.z + be.z;
    }
    {
        float m = sm.w * (1.f / BNn), var = sq.w * (1.f / BNn) - m * m;
        o.w = (hv.w - m) * rsqrtf(var + EPSV) * ga.w + be.w;
    }
    *(float4*)(outf + i4) = o;
}

// ---------------- fused BN1+BN2 apply (bf16 in / bf16 out, 12 MB total) ----------------
__global__ __launch_bounds__(256) void bn_apply12_k(
    const unsigned short* __restrict__ h1preb, const unsigned short* __restrict__ h2preb,
    const float* __restrict__ stats,
    const float* __restrict__ g1, const float* __restrict__ be1,
    const float* __restrict__ g2, const float* __restrict__ be2,
    unsigned short* __restrict__ outb)
{
    size_t i4 = ((size_t)blockIdx.x * 256 + threadIdx.x) * 4;
    int ch = (int)(i4 & (Cc - 1));
    ushort4 u1 = *(const ushort4*)(h1preb + i4);
    ushort4 u2 = *(const ushort4*)(h2preb + i4);
    float4 s1m = *(const float4*)(stats + ch);
    float4 s1q = *(const float4*)(stats + 256 + ch);
    float4 s2m = *(const float4*)(stats + 512 + ch);
    float4 s2q = *(const float4*)(stats + 768 + ch);
    float4 G1 = *(const float4*)(g1 + ch),  B1 = *(const float4*)(be1 + ch);
    float4 G2 = *(const float4*)(g2 + ch),  B2 = *(const float4*)(be2 + ch);
    ushort4 pk;
    #define BN12C(comp, ucomp) { \
        float m1 = s1m.comp * (1.f / BNn), v1 = s1q.comp * (1.f / BNn) - m1 * m1; \
        float m2 = s2m.comp * (1.f / BNn), v2 = s2q.comp * (1.f / BNn) - m2 * m2; \
        float o = (b2f(u1.ucomp) - m1) * rsqrtf(v1 + EPSV) * G1.comp + B1.comp \
                + (b2f(u2.ucomp) - m2) * rsqrtf(v2 + EPSV) * G2.comp + B2.comp; \
        pk.ucomp = f2b(o); }
    BN12C(x, x) BN12C(y, y) BN12C(z, z) BN12C(w, w)
    #undef BN12C
    *(ushort4*)(outb + i4) = pk;
}

// ---------------- launch ----------------
extern "C" void kernel_launch(void* const* d_in, const int* in_sizes, int n_in,
                              void* d_out, int out_size, void* d_ws, size_t ws_size,
                              hipStream_t stream)
{
    const float* x   = (const float*)d_in[0];
    const int*   ei  = (const int*)  d_in[1];
    const float* sph = (const float*)d_in[2];
    const float* Wr  = (const float*)d_in[3];
    const float* Wn  = (const float*)d_in[4];
    const float* Wq  = (const float*)d_in[5];
    const float* bq  = (const float*)d_in[6];
    const float* Wk  = (const float*)d_in[7];
    const float* bk  = (const float*)d_in[8];
    const float* Wv  = (const float*)d_in[9];
    const float* bv  = (const float*)d_in[10];
    const float* Wo  = (const float*)d_in[11];
    const float* bo  = (const float*)d_in[12];
    const float* W1  = (const float*)d_in[13];
    const float* b1  = (const float*)d_in[14];
    const float* W2  = (const float*)d_in[15];
    const float* b2  = (const float*)d_in[16];
    const float* g1  = (const float*)d_in[17];
    const float* be1 = (const float*)d_in[18];
    const float* g2  = (const float*)d_in[19];
    const float* be2 = (const float*)d_in[20];
    const float* g3  = (const float*)d_in[21];
    const float* be3 = (const float*)d_in[22];
    float* out = (float*)d_out;

    const size_t SL = (size_t)BNn * Cc;  // 2M elements

    float* ws = (float*)d_ws;
    float* s1 = ws;                  // op0b (bf16, 4MB)
    float* s2 = s1 + SL;             // h1preb (bf16) then out2 (fp32)
    float* s3 = s2 + SL;             // h2preb (bf16)

    int*   deg      = (int*)(s3 + SL);          // 8192
    float* statsAll = (float*)(deg + 8192);     // 1536
    int*   rowst    = (int*)(statsAll + 1536);  // 8192 (+pad)
    int*   cursor   = rowst + 8256;             // 8192
    int*   eidx     = cursor + 8192;            // 131072

    unsigned short* xcat = (unsigned short*)(eidx + 131072); // [8192][512]; reused as hid
    unsigned short* qb   = xcat + 2 * SL;
    unsigned short* kb   = qb + SL;                          // reused as osb
    unsigned short* vTb  = kb + SL;
    unsigned short* osb  = kb;
    unsigned short* hid  = xcat;

    unsigned short* WcatT = vTb + SL;         // 256x512
    unsigned short* WqT   = WcatT + 131072;   // WqT|WkT|WvT contiguous = [768][256]
    unsigned short* WkT   = WqT + 65536;
    unsigned short* WvT   = WkT + 65536;
    unsigned short* WoT   = WvT + 65536;
    unsigned short* W1T   = WoT + 65536;
    unsigned short* W2T   = W1T + 131072;
    unsigned short* op0b   = (unsigned short*)s1;
    unsigned short* h1preb = (unsigned short*)s2;   // 4MB of s2; dead before out2
    unsigned short* h2preb = (unsigned short*)s3;

    dim3 gN256(4, 256);
    dim3 gN512(8, 256);

    const float QSCALE = 0.17677669529663687f * 1.4426950408889634f;

    // 1) zero deg + all BN stats in one memset
    hipMemsetAsync(deg, 0, (8192 + 1536) * sizeof(float), stream);
    // 2) fused converts + histogram
    prep_k<<<5120, 256, 0, stream>>>(x, xcat, Wr, Wn, Wq, Wk, Wv, Wo, W1, W2,
                                     WcatT, WqT, WkT, WvT, WoT, W1T, W2T, ei, deg);
    // 3-4) CSR scan / place
    scan_k<<<1, 256, 0, stream>>>(deg, rowst, cursor);
    place_k<<<Ee / 256, 256, 0, stream>>>(ei, cursor, eidx);
    // 5) gather (xcat hi, bf16 source) || QKV GEMM (xcat lo -> qb,kb,vTb)
    gather_qkv_k<<<5120, 256, 0, stream>>>(x, rowst, deg, eidx, xcat,
                                           WqT, bq, bk, bv, qb, kb, vTb, QSCALE);
    // 6) attention (K reg-pipeline, V-hoist, T14 sph) || h1pre GEMM — 768 blocks
    attn_h1_k<<<768, 512, 0, stream>>>(qb, kb, vTb, sph, op0b,
                                       xcat, WcatT, x, h1preb,
                                       statsAll, statsAll + 256);
    // 7) h2pre = O @ Wo + bo + x -> bf16, + BN2 stats
    gemm_attnA_k<<<gN256, 256, 0, stream>>>(op0b, WoT, bo, x,
                                            h2preb, statsAll + 512, statsAll + 768);
    // 8) osb = bn1(h1pre) + bn2(h2pre)   (bf16 in/out, 12 MB pass)
    bn_apply12_k<<<(int)(SL / 1024), 256, 0, stream>>>(h1preb, h2preb, statsAll,
                                                       g1, be1, g2, be2, osb);
    // 9) hidden = relu(osb @ W1 + b1) -> hid (bf16)
    gemm_mfma_k<1><<<gN512, 256, 0, stream>>>(osb, W1T, b1, nullptr,
                                              nullptr, hid, nullptr, nullptr,
                                              BNn, Cc, Cc, 2 * Cc, 1, 1.f);
    // 10) out2 = hid @ W2 + b2 + osb(residual, bf16) -> s2 fp32, + BN3 stats
    gemm_mfma_k<2><<<gN256, 256, 0, stream>>>(hid, W2T, b2, osb,
                                              s2, nullptr, statsAll + 1024, statsAll + 1280,
                                              BNn, 2 * Cc, 2 * Cc, Cc, 0, 1.f);
    // 11) d_out = BN3(out2)
    bn_apply_k<<<(int)(SL / 1024), 256, 0, stream>>>(s2, statsAll + 1024,
                                                     statsAll + 1280, g3, be3, out);
}

// Round 14
// 335.238 us; speedup vs baseline: 1.1095x; 1.0696x over previous
//
#include <hip/hip_runtime.h>
#include <hip/hip_bf16.h>

// ---------------- problem constants ----------------
constexpr int Bg  = 8;       // graphs
constexpr int Nn  = 1024;    // nodes per graph
constexpr int Cc  = 256;     // channels
constexpr int Hh  = 8;       // heads
constexpr int DKh = 32;      // head dim
constexpr int Ee  = 131072;  // edges
constexpr int BNn = Bg * Nn; // 8192 total nodes
#define EPSV 1e-5f

typedef __attribute__((ext_vector_type(8))) short bf16x8;
typedef __attribute__((ext_vector_type(4))) float f32x4;

static __device__ __forceinline__ unsigned short f2b(float v) {
    __hip_bfloat16 h = __float2bfloat16(v);
    return __builtin_bit_cast(unsigned short, h);
}
static __device__ __forceinline__ float b2f(unsigned short u) {
    unsigned int x = ((unsigned int)u) << 16;
    return __builtin_bit_cast(float, x);
}
static __device__ __forceinline__ bf16x8 ldb8(const unsigned short* p) {
    return *(const bf16x8*)p;
}

// ---------------- fused prep: xconv + wconv + hist ----------------
__global__ __launch_bounds__(256) void prep_k(
    const float* __restrict__ x, unsigned short* __restrict__ xcat,
    const float* __restrict__ Wr, const float* __restrict__ Wn,
    const float* __restrict__ Wq, const float* __restrict__ Wk,
    const float* __restrict__ Wv, const float* __restrict__ Wo,
    const float* __restrict__ W1, const float* __restrict__ W2,
    unsigned short* __restrict__ WcatT,
    unsigned short* __restrict__ WqT, unsigned short* __restrict__ WkT,
    unsigned short* __restrict__ WvT, unsigned short* __restrict__ WoT,
    unsigned short* __restrict__ W1T, unsigned short* __restrict__ W2T,
    const int* __restrict__ ei, int* __restrict__ deg)
{
    int blk = blockIdx.x;
    if (blk < 2048) {
        int i = (blk * 256 + threadIdx.x) * 4;
        float4 v = *(const float4*)(x + i);
        int r = i >> 8, c = i & 255;
        ushort4 pk;
        pk.x = f2b(v.x); pk.y = f2b(v.y); pk.z = f2b(v.z); pk.w = f2b(v.w);
        *(ushort4*)(xcat + (size_t)r * 512 + c) = pk;
    } else if (blk < 4608) {
        int idx = (blk - 2048) * 256 + threadIdx.x;
        if (idx < 131072) {                      // WcatT [256][512]
            int n = idx >> 9, k = idx & 511;
            float v = (k < 256) ? Wr[k * 256 + n] : Wn[(k - 256) * 256 + n];
            WcatT[(size_t)n * 512 + k] = f2b(v);
        } else if (idx < 393216) {               // q,k,v,o
            int l = idx - 131072;
            int wsel = l >> 16; l &= 65535;
            int n = l >> 8, kk = l & 255;
            const float* S = wsel == 0 ? Wq : wsel == 1 ? Wk : wsel == 2 ? Wv : Wo;
            unsigned short* D = wsel == 0 ? WqT : wsel == 1 ? WkT : wsel == 2 ? WvT : WoT;
            D[n * 256 + kk] = f2b(S[kk * 256 + n]);
        } else if (idx < 524288) {               // W1 [256][512] -> W1T [512][256]
            int l = idx - 393216;
            int n = l >> 8, kk = l & 255;
            W1T[l] = f2b(W1[kk * 512 + n]);
        } else {                                 // W2 [512][256] -> W2T [256][512]
            int l = idx - 524288;
            int n = l >> 9, kk = l & 511;
            W2T[l] = f2b(W2[kk * 256 + n]);
        }
    } else {
        int e = (blk - 4608) * 256 + threadIdx.x;
        atomicAdd(&deg[ei[Ee + e]], 1);
    }
}

// ---------------- CSR scan (coalesced, interleaved buckets) ----------------
__global__ __launch_bounds__(256) void scan_k(
    const int* __restrict__ deg, int* __restrict__ rowst, int* __restrict__ cursor)
{
    __shared__ int partial[256];
    int t = threadIdx.x;
    int local[32];
    int s = 0;
    #pragma unroll
    for (int i = 0; i < 32; ++i) { local[i] = deg[i * 256 + t]; s += local[i]; }
    partial[t] = s;
    __syncthreads();
    for (int off = 1; off < 256; off <<= 1) {
        int v = (t >= off) ? partial[t - off] : 0;
        __syncthreads();
        partial[t] += v;
        __syncthreads();
    }
    int base = partial[t] - s;
    #pragma unroll
    for (int i = 0; i < 32; ++i) {
        int n = i * 256 + t;
        rowst[n] = base;
        cursor[n] = base;
        base += local[i];
    }
}

__global__ __launch_bounds__(256) void place_k(
    const int* __restrict__ ei, int* __restrict__ cursor, int* __restrict__ eidx)
{
    int e = blockIdx.x * 256 + threadIdx.x;
    int s = ei[e], d = ei[Ee + e];
    int pos = atomicAdd(&cursor[d], 1);
    eidx[pos] = s;
}

// ---------------- merged gather (blocks 0..2047) + QKV GEMM (2048..5119) ----------------
// R29: K and V are now written in FRAGMENT-READY layouts so attention wave
// loads are fully coalesced (1KB contiguous per wave instead of 16x64B
// gathers — the 16-way address divergence is the last-standing theory for
// the invariant ~92us attn floor; it is vector-memory TRANSACTION
// throughput, untouched by every barrier/traffic/occupancy/prefetch lever).
//   kf[b][mt=m/16][h][tl=16][c=32]   (1KB per (mt,h) tile)
//   vf[b][h][mt64=m/64][ks][cg][tl=16][g=4][m8=8]  (1KB per (ks,cg) subtile)
// Values per lane are bit-identical to the old layout; only addresses moved.
__global__ __launch_bounds__(256, 4) void gather_qkv_k(
    const float* __restrict__ x, const int* __restrict__ rowst,
    const int* __restrict__ deg, const int* __restrict__ eidx,
    unsigned short* __restrict__ xcat,
    const unsigned short* __restrict__ WT,
    const float* __restrict__ bq, const float* __restrict__ bk,
    const float* __restrict__ bv,
    unsigned short* __restrict__ qb, unsigned short* __restrict__ kb,
    unsigned short* __restrict__ vTb, float qscale)
{
    __shared__ unsigned short vtile[64][40];
    int blk = blockIdx.x;

    if (blk < 2048) {
        // gather: 4 nodes per block, one 64-lane wave each (bf16 source)
        int n = blk * 4 + (threadIdx.x >> 6);
        int c4 = (threadIdx.x & 63) * 4;
        int b0 = rowst[n], d = deg[n];
        float4 acc = {0.f, 0.f, 0.f, 0.f};
        int i = 0;
        for (; i + 4 <= d; i += 4) {
            int s0 = eidx[b0 + i], s1 = eidx[b0 + i + 1];
            int s2 = eidx[b0 + i + 2], s3 = eidx[b0 + i + 3];
            ushort4 a0 = *(const ushort4*)(xcat + (size_t)s0 * 512 + c4);
            ushort4 a1 = *(const ushort4*)(xcat + (size_t)s1 * 512 + c4);
            ushort4 a2 = *(const ushort4*)(xcat + (size_t)s2 * 512 + c4);
            ushort4 a3 = *(const ushort4*)(xcat + (size_t)s3 * 512 + c4);
            acc.x += (b2f(a0.x) + b2f(a1.x)) + (b2f(a2.x) + b2f(a3.x));
            acc.y += (b2f(a0.y) + b2f(a1.y)) + (b2f(a2.y) + b2f(a3.y));
            acc.z += (b2f(a0.z) + b2f(a1.z)) + (b2f(a2.z) + b2f(a3.z));
            acc.w += (b2f(a0.w) + b2f(a1.w)) + (b2f(a2.w) + b2f(a3.w));
        }
        for (; i < d; ++i) {
            int s = eidx[b0 + i];
            ushort4 a = *(const ushort4*)(xcat + (size_t)s * 512 + c4);
            acc.x += b2f(a.x); acc.y += b2f(a.y);
            acc.z += b2f(a.z); acc.w += b2f(a.w);
        }
        ushort4 pk;
        pk.x = f2b(acc.x); pk.y = f2b(acc.y); pk.z = f2b(acc.z); pk.w = f2b(acc.w);
        *(ushort4*)(xcat + (size_t)n * 512 + 256 + c4) = pk;
        return;
    }

    // QKV GEMM, N=768 = [q|k|v]; reads xcat low half only (lda=512, K=256)
    int qblk = blk - 2048;
    const int n0 = (qblk % 12) * 64;
    const int m0 = (qblk / 12) * 32;
    const int t = threadIdx.x;
    const int wave = t >> 6, lane = t & 63;
    const int tl = lane & 15, g = lane >> 4;
    const int wr = wave >> 1, wc = wave & 1;
    const int which = n0 >> 8;               // 0:q 1:k 2:v
    const int K = 256, lda = 512;

    f32x4 acc[2] = {};

    const unsigned short* a0 = xcat + (size_t)(m0 + wr * 16 + tl) * lda + g * 8;
    const unsigned short* b0 = WT + (size_t)(n0 + wc * 32 + tl) * K + g * 8;
    const unsigned short* b1 = b0 + (size_t)16 * K;

    for (int k0 = 0; k0 < K; k0 += 32) {
        bf16x8 af  = ldb8(a0 + k0);
        bf16x8 bf0 = ldb8(b0 + k0), bf1 = ldb8(b1 + k0);
        acc[0] = __builtin_amdgcn_mfma_f32_16x16x32_bf16(af, bf0, acc[0], 0, 0, 0);
        acc[1] = __builtin_amdgcn_mfma_f32_16x16x32_bf16(af, bf1, acc[1], 0, 0, 0);
    }

    const float* bias = which == 0 ? bq : which == 1 ? bk : bv;
    const float sc = which == 0 ? qscale : 1.f;

    if (which == 0) {
        #pragma unroll
        for (int c16 = 0; c16 < 2; ++c16)
            #pragma unroll
            for (int reg = 0; reg < 4; ++reg) {
                int row = m0 + wr * 16 + g * 4 + reg;
                int col = (n0 & 255) + wc * 32 + c16 * 16 + tl;
                qb[(size_t)row * Cc + col] = f2b((acc[c16][reg] + bias[col]) * sc);
            }
    } else if (which == 1) {
        // K fragment layout: kf[(row>>4)*8 + (col>>5)][row&15][col&31]
        #pragma unroll
        for (int c16 = 0; c16 < 2; ++c16)
            #pragma unroll
            for (int reg = 0; reg < 4; ++reg) {
                int row = m0 + wr * 16 + g * 4 + reg;
                int col = (n0 & 255) + wc * 32 + c16 * 16 + tl;
                kb[((size_t)(row >> 4) * 8 + (col >> 5)) * 512
                   + (row & 15) * 32 + (col & 31)] = f2b(acc[c16][reg] + bias[col]);
            }
    } else {
        #pragma unroll
        for (int c16 = 0; c16 < 2; ++c16)
            #pragma unroll
            for (int reg = 0; reg < 4; ++reg) {
                int colL = wc * 32 + c16 * 16 + tl;
                int rowL = wr * 16 + g * 4 + reg;
                vtile[colL][rowL] = f2b(acc[c16][reg] + bias[(n0 & 255) + colL]);
            }
        __syncthreads();
        // V fragment layout: vf[b][h][m/64][ks][cg][tl][g][m8]
        int clocal = t >> 2, q4 = t & 3;
        int colg = (n0 & 255) + clocal;
        int hh = colg >> 5, dd = colg & 31;
        int bg = m0 >> 10;
        int m_loc = (m0 & 1023) + q4 * 8;          // 8 consecutive m, 8-aligned
        int mt64 = m_loc >> 6, ks = (m_loc >> 5) & 1, gg = (m_loc >> 3) & 3;
        int cg = dd >> 4, tlv = dd & 15;
        ushort4 u0 = *(ushort4*)&vtile[clocal][q4 * 8];
        ushort4 u1 = *(ushort4*)&vtile[clocal][q4 * 8 + 4];
        unsigned short* dst = vTb
            + (((size_t)(bg * Hh + hh) * 16 + mt64) * 2048)
            + ((size_t)((ks * 2 + cg) * 16 + tlv) * 32) + gg * 8;
        *(ushort4*)dst = u0;
        *(ushort4*)(dst + 4) = u1;
    }
}

// ---------------- merged attention (blocks 0..511) + h1pre GEMM (512..767) ----------------
// R29 attn: identical math/schedule to R26/R27 (m-step 128, dbuf sph, raw
// v_exp, XCD pin) but K/V loads now hit the fragment-ready layouts: each
// wave load is ONE contiguous 1KB transaction (lane offset = lane*16B)
// instead of a 16-segment gather. 16x fewer TA/L2 transactions per MFMA.
__global__ __launch_bounds__(512, 8) void attn_h1_k(
    const unsigned short* __restrict__ q, const unsigned short* __restrict__ k,
    const unsigned short* __restrict__ vT, const float* __restrict__ sph,
    unsigned short* __restrict__ op0,
    const unsigned short* __restrict__ xcat, const unsigned short* __restrict__ WcatT,
    const float* __restrict__ x, unsigned short* __restrict__ h1preb,
    float* __restrict__ gsum, float* __restrict__ gsq)
{
    __shared__ float Sph[2][16][132];          // 16896 B
    __shared__ unsigned short Ps[Hh][16][72];  // 18432 B
    float* csum = (float*)&Ps[0][0][0];     // [256], aliased (gemm branch only)
    float* csq  = csum + 256;

    const int blk = blockIdx.x;
    const int t = threadIdx.x;
    const int wave = t >> 6;
    const int lane = t & 63;
    const int tl = lane & 15, g = lane >> 4;

    if (blk < 512) {
        // ---------- attention: 16 q-rows, full m-range, graph pinned to XCD ----------
        const int b  = blk & 7;             // graph == XCD (round-robin dispatch)
        const int n0 = (blk >> 3) * 16;     // 64 row-tiles per graph
        const int w  = wave;

        bf16x8 qf = ldb8(q + ((size_t)(b * Nn + n0 + tl)) * Cc + w * DKh + g * 8);

        float lsum = 0.f;
        f32x4 oacc[2] = {};

        // coalesced fragment bases: lane offset = (tl*4+g)*16B within each 1KB tile
        const unsigned short* kfb = k + ((size_t)(b * 512 + w)) * 512 + tl * 32 + g * 8;
        const unsigned short* vfb = vT + ((size_t)(b * Hh + w) * 16) * 2048
                                     + (size_t)tl * 32 + g * 8;
        const float* sbase = sph + ((size_t)b * Nn + n0) * Nn;

        // prologue: stage sph tile 0 (16x128) into buffer 0; 256 thr x 2 float4
        if (t < 256) {
            int r1 = t >> 4, c1 = (t & 15) * 8;
            const float* src = sbase + (size_t)r1 * Nn + c1;
            *(float4*)&Sph[0][r1][c1]     = *(const float4*)src;
            *(float4*)&Sph[0][r1][c1 + 4] = *(const float4*)(src + 4);
        }
        __syncthreads();

        int cur = 0;
        for (int it = 0; it < 8; ++it) {
            const int m0 = it * 128;
            // stage NEXT 16x128 tile into the other buffer
            if (it < 7 && t < 256) {
                int r1 = t >> 4, c1 = (t & 15) * 8;
                const float* src = sbase + (size_t)r1 * Nn + m0 + 128 + c1;
                *(float4*)&Sph[cur ^ 1][r1][c1]     = *(const float4*)src;
                *(float4*)&Sph[cur ^ 1][r1][c1 + 4] = *(const float4*)(src + 4);
            }

            #pragma unroll
            for (int half = 0; half < 2; ++half) {
                const int mh = m0 + half * 64;

                f32x4 st[4];
                #pragma unroll
                for (int mg = 0; mg < 4; ++mg) {
                    bf16x8 ka = ldb8(kfb + (size_t)((mh >> 4) + mg) * 4096);
                    f32x4 z = {0.f, 0.f, 0.f, 0.f};
                    st[mg] = __builtin_amdgcn_mfma_f32_16x16x32_bf16(ka, qf, z, 0, 0, 0);
                }

                #pragma unroll
                for (int mg = 0; mg < 4; ++mg) {
                    float4 sp = *(const float4*)&Sph[cur][tl][half * 64 + mg * 16 + g * 4];
                    float p0 = __builtin_amdgcn_exp2f(st[mg][0] * sp.x);
                    float p1 = __builtin_amdgcn_exp2f(st[mg][1] * sp.y);
                    float p2 = __builtin_amdgcn_exp2f(st[mg][2] * sp.z);
                    float p3 = __builtin_amdgcn_exp2f(st[mg][3] * sp.w);
                    lsum += (p0 + p1) + (p2 + p3);
                    ushort4 pk;
                    pk.x = f2b(p0); pk.y = f2b(p1); pk.z = f2b(p2); pk.w = f2b(p3);
                    *(ushort4*)&Ps[w][tl][mg * 16 + g * 4] = pk;
                }

                const unsigned short* vtile64 = vfb + (size_t)(mh >> 6) * 2048;
                #pragma unroll
                for (int ks = 0; ks < 2; ++ks) {
                    bf16x8 pa = ldb8(&Ps[w][tl][ks * 32 + g * 8]);
                    #pragma unroll
                    for (int cg = 0; cg < 2; ++cg) {
                        bf16x8 vb = ldb8(vtile64 + (size_t)(ks * 2 + cg) * 512);
                        oacc[cg] = __builtin_amdgcn_mfma_f32_16x16x32_bf16(pa, vb, oacc[cg], 0, 0, 0);
                    }
                }
            }

            __syncthreads();   // staging writes visible; Sph[cur]/Ps reads complete
            cur ^= 1;
        }

        // full-row softmax denominator -> normalize O in-register.
        lsum += __shfl_xor(lsum, 16);
        lsum += __shfl_xor(lsum, 32);      // every lane: sum for q-row tl
        float* shl = (float*)&Ps[w][0][0]; // per-wave scratch (Ps dead now)
        if (g == 0) shl[tl] = lsum;        // wave-local write->read, no barrier
        #pragma unroll
        for (int r = 0; r < 4; ++r) {
            float inv = 1.f / shl[g * 4 + r];   // O row = g*4+r
            #pragma unroll
            for (int cg = 0; cg < 2; ++cg)
                op0[((size_t)(b * Nn + n0 + g * 4 + r)) * Cc + w * DKh + cg * 16 + tl]
                    = f2b(oacc[cg][r] * inv);
        }
        return;
    }

    // ---------- h1pre GEMM: one 32x256 tile per block (A read once) ----------
    const int wrg = wave >> 2;              // 0..1 row group
    const int wcg = wave & 3;               // 0..3 col group (64 cols each)
    const int m0g = (blk - 512) * 32;
    const int K = 512, N = Cc;

    if (t < 256) { csum[t] = 0.f; csq[t] = 0.f; }
    __syncthreads();

    f32x4 acc[4] = {};

    const unsigned short* a0 = xcat + (size_t)(m0g + wrg * 16 + tl) * 512 + g * 8;
    const unsigned short* bb = WcatT + (size_t)(wcg * 64 + tl) * K + g * 8;

    for (int k0 = 0; k0 < K; k0 += 32) {
        bf16x8 af = ldb8(a0 + k0);
        #pragma unroll
        for (int c16 = 0; c16 < 4; ++c16) {
            bf16x8 bf = ldb8(bb + (size_t)(c16 * 16) * K + k0);
            acc[c16] = __builtin_amdgcn_mfma_f32_16x16x32_bf16(af, bf, acc[c16], 0, 0, 0);
        }
    }

    #pragma unroll
    for (int c16 = 0; c16 < 4; ++c16) {
        int col = wcg * 64 + c16 * 16 + tl;
        float ls = 0.f, lq = 0.f;
        #pragma unroll
        for (int reg = 0; reg < 4; ++reg) {
            int row = m0g + wrg * 16 + g * 4 + reg;
            size_t idx = (size_t)row * N + col;
            float v = acc[c16][reg] + x[idx];
            ls += v; lq += v * v;               // stats in fp32 (pre-rounding)
            h1preb[idx] = f2b(v);
        }
        atomicAdd(&csum[col], ls);
        atomicAdd(&csq[col],  lq);
    }
    __syncthreads();
    if (t < 256) {
        atomicAdd(&gsum[t], csum[t]);
        atomicAdd(&gsq[t],  csq[t]);
    }
}

// ---------------- MFMA GEMM, 32x64 tile, optional bf16 residual + BN-stats ----------------
// TAG: 1 = mlp1 (N=512), 2 = mlp2 (K=512, bf16 residual addb = osb).
template<int TAG>
__global__ __launch_bounds__(256, 4) void gemm_mfma_k(
    const unsigned short* __restrict__ A, const unsigned short* __restrict__ WT,
    const float* __restrict__ bias, const unsigned short* __restrict__ addb,
    float* __restrict__ outf, unsigned short* __restrict__ outb,
    float* __restrict__ gsum, float* __restrict__ gsq,
    int M, int K, int lda, int N, int relu, float oscale)
{
    const int t = threadIdx.x;
    const int wave = t >> 6, lane = t & 63;
    const int tl = lane & 15, g = lane >> 4;
    const int wr = wave >> 1, wc = wave & 1;
    const int m0 = blockIdx.y * 32, n0 = blockIdx.x * 64;

    __shared__ float csum[64], csq[64];
    if (gsum) {
        if (t < 64) { csum[t] = 0.f; csq[t] = 0.f; }
        __syncthreads();
    }

    f32x4 acc[2] = {};

    const unsigned short* a0 = A  + (size_t)(m0 + wr * 16 + tl) * lda + g * 8;
    const unsigned short* b0 = WT + (size_t)(n0 + wc * 32 + tl) * K + g * 8;
    const unsigned short* b1 = b0 + (size_t)16 * K;

    for (int k0 = 0; k0 < K; k0 += 32) {
        bf16x8 af  = ldb8(a0 + k0);
        bf16x8 bf0 = ldb8(b0 + k0), bf1 = ldb8(b1 + k0);
        acc[0] = __builtin_amdgcn_mfma_f32_16x16x32_bf16(af, bf0, acc[0], 0, 0, 0);
        acc[1] = __builtin_amdgcn_mfma_f32_16x16x32_bf16(af, bf1, acc[1], 0, 0, 0);
    }

    #pragma unroll
    for (int c16 = 0; c16 < 2; ++c16) {
        int colL = wc * 32 + c16 * 16 + tl;
        int col  = n0 + colL;
        float ls = 0.f, lq = 0.f;
        #pragma unroll
        for (int reg = 0; reg < 4; ++reg) {
            int row = m0 + wr * 16 + g * 4 + reg;
            float v = acc[c16][reg];
            if (bias) v += bias[col];
            v *= oscale;
            size_t idx = (size_t)row * N + col;
            if (addb) v += b2f(addb[idx]);
            ls += v; lq += v * v;
            if (relu) v = fmaxf(v, 0.f);
            if (outf) outf[idx] = v;
            if (outb) outb[idx] = f2b(v);
        }
        if (gsum) { atomicAdd(&csum[colL], ls); atomicAdd(&csq[colL], lq); }
    }
    if (gsum) {
        __syncthreads();
        if (t < 64) {
            atomicAdd(&gsum[n0 + t], csum[t]);
            atomicAdd(&gsq[n0 + t],  csq[t]);
        }
    }
}

// ---------------- Wo GEMM (A = normalized bf16 O) + fp32 residual + BN2 stats ----------------
__global__ __launch_bounds__(256, 4) void gemm_attnA_k(
    const unsigned short* __restrict__ op0,
    const unsigned short* __restrict__ WT, const float* __restrict__ bias,
    const float* __restrict__ add1, unsigned short* __restrict__ h2preb,
    float* __restrict__ gsum, float* __restrict__ gsq)
{
    const int K = Cc, N = Cc;
    const int t = threadIdx.x;
    const int wave = t >> 6, lane = t & 63;
    const int tl = lane & 15, g = lane >> 4;
    const int wr = wave >> 1, wc = wave & 1;
    const int m0 = blockIdx.y * 32, n0 = blockIdx.x * 64;

    __shared__ float csum[64], csq[64];
    if (t < 64) { csum[t] = 0.f; csq[t] = 0.f; }
    __syncthreads();

    f32x4 acc[2] = {};

    const int arow = m0 + wr * 16 + tl;
    const unsigned short* a0b = op0 + (size_t)arow * K + g * 8;
    const unsigned short* b0 = WT + (size_t)(n0 + wc * 32 + tl) * K + g * 8;
    const unsigned short* b1 = b0 + (size_t)16 * K;

    for (int k0 = 0; k0 < K; k0 += 32) {
        bf16x8 af  = ldb8(a0b + k0);
        bf16x8 bf0 = ldb8(b0 + k0), bf1 = ldb8(b1 + k0);
        acc[0] = __builtin_amdgcn_mfma_f32_16x16x32_bf16(af, bf0, acc[0], 0, 0, 0);
        acc[1] = __builtin_amdgcn_mfma_f32_16x16x32_bf16(af, bf1, acc[1], 0, 0, 0);
    }

    #pragma unroll
    for (int c16 = 0; c16 < 2; ++c16) {
        int colL = wc * 32 + c16 * 16 + tl;
        int col  = n0 + colL;
        float ls = 0.f, lq = 0.f;
        #pragma unroll
        for (int reg = 0; reg < 4; ++reg) {
            int row = m0 + wr * 16 + g * 4 + reg;
            float v = acc[c16][reg] + bias[col];
            size_t idx = (size_t)row * N + col;
            v += add1[idx];
            ls += v; lq += v * v;               // stats in fp32 (pre-rounding)
            h2preb[idx] = f2b(v);
        }
        atomicAdd(&csum[colL], ls); atomicAdd(&csq[colL], lq);
    }
    __syncthreads();
    if (t < 64) {
        atomicAdd(&gsum[n0 + t], csum[t]);
        atomicAdd(&gsq[n0 + t],  csq[t]);
    }
}

// ---------------- BN apply (single, float4) ----------------
__global__ __launch_bounds__(256) void bn_apply_k(
    const float* __restrict__ h, const float* __restrict__ gsum,
    const float* __restrict__ gsq, const float* __restrict__ gamma,
    const float* __restrict__ beta, float* __restrict__ outf)
{
    size_t i4 = ((size_t)blockIdx.x * 256 + threadIdx.x) * 4;
    int ch = (int)(i4 & (Cc - 1));
    float4 hv = *(const float4*)(h + i4);
    float4 sm = *(const float4*)(gsum + ch);
    float4 sq = *(const float4*)(gsq + ch);
    float4 ga = *(const float4*)(gamma + ch);
    float4 be = *(const float4*)(beta + ch);
    float4 o;
    {
        float m = sm.x * (1.f / BNn), var = sq.x * (1.f / BNn) - m * m;
        o.x = (hv.x - m) * rsqrtf(var + EPSV) * ga.x + be.x;
    }
    {
        float m = sm.y * (1.f / BNn), var = sq.y * (1.f / BNn) - m * m;
        o.y = (hv.y - m) * rsqrtf(var + EPSV) * ga.y + be.y;
    }
    {
        float m = sm.z * (1.f / BNn), var = sq.z * (1.f / BNn) - m * m;
        o.z = (hv.z - m) * rsqrtf(var + EPSV) * ga.z + be.z;
    }
    {
        float m = sm.w * (1.f / BNn), var = sq.w * (1.f / BNn) - m * m;
        o.w = (hv.w - m) * rsqrtf(var + EPSV) * ga.w + be.w;
    }
    *(float4*)(outf + i4) = o;
}

// ---------------- fused BN1+BN2 apply (bf16 in / bf16 out, 12 MB total) ----------------
__global__ __launch_bounds__(256) void bn_apply12_k(
    const unsigned short* __restrict__ h1preb, const unsigned short* __restrict__ h2preb,
    const float* __restrict__ stats,
    const float* __restrict__ g1, const float* __restrict__ be1,
    const float* __restrict__ g2, const float* __restrict__ be2,
    unsigned short* __restrict__ outb)
{
    size_t i4 = ((size_t)blockIdx.x * 256 + threadIdx.x) * 4;
    int ch = (int)(i4 & (Cc - 1));
    ushort4 u1 = *(const ushort4*)(h1preb + i4);
    ushort4 u2 = *(const ushort4*)(h2preb + i4);
    float4 s1m = *(const float4*)(stats + ch);
    float4 s1q = *(const float4*)(stats + 256 + ch);
    float4 s2m = *(const float4*)(stats + 512 + ch);
    float4 s2q = *(const float4*)(stats + 768 + ch);
    float4 G1 = *(const float4*)(g1 + ch),  B1 = *(const float4*)(be1 + ch);
    float4 G2 = *(const float4*)(g2 + ch),  B2 = *(const float4*)(be2 + ch);
    ushort4 pk;
    #define BN12C(comp, ucomp) { \
        float m1 = s1m.comp * (1.f / BNn), v1 = s1q.comp * (1.f / BNn) - m1 * m1; \
        float m2 = s2m.comp * (1.f / BNn), v2 = s2q.comp * (1.f / BNn) - m2 * m2; \
        float o = (b2f(u1.ucomp) - m1) * rsqrtf(v1 + EPSV) * G1.comp + B1.comp \
                + (b2f(u2.ucomp) - m2) * rsqrtf(v2 + EPSV) * G2.comp + B2.comp; \
        pk.ucomp = f2b(o); }
    BN12C(x, x) BN12C(y, y) BN12C(z, z) BN12C(w, w)
    #undef BN12C
    *(ushort4*)(outb + i4) = pk;
}

// ---------------- launch ----------------
extern "C" void kernel_launch(void* const* d_in, const int* in_sizes, int n_in,
                              void* d_out, int out_size, void* d_ws, size_t ws_size,
                              hipStream_t stream)
{
    const float* x   = (const float*)d_in[0];
    const int*   ei  = (const int*)  d_in[1];
    const float* sph = (const float*)d_in[2];
    const float* Wr  = (const float*)d_in[3];
    const float* Wn  = (const float*)d_in[4];
    const float* Wq  = (const float*)d_in[5];
    const float* bq  = (const float*)d_in[6];
    const float* Wk  = (const float*)d_in[7];
    const float* bk  = (const float*)d_in[8];
    const float* Wv  = (const float*)d_in[9];
    const float* bv  = (const float*)d_in[10];
    const float* Wo  = (const float*)d_in[11];
    const float* bo  = (const float*)d_in[12];
    const float* W1  = (const float*)d_in[13];
    const float* b1  = (const float*)d_in[14];
    const float* W2  = (const float*)d_in[15];
    const float* b2  = (const float*)d_in[16];
    const float* g1  = (const float*)d_in[17];
    const float* be1 = (const float*)d_in[18];
    const float* g2  = (const float*)d_in[19];
    const float* be2 = (const float*)d_in[20];
    const float* g3  = (const float*)d_in[21];
    const float* be3 = (const float*)d_in[22];
    float* out = (float*)d_out;

    const size_t SL = (size_t)BNn * Cc;  // 2M elements

    float* ws = (float*)d_ws;
    float* s1 = ws;                  // op0b (bf16, 4MB)
    float* s2 = s1 + SL;             // h1preb (bf16) then out2 (fp32)
    float* s3 = s2 + SL;             // h2preb (bf16)

    int*   deg      = (int*)(s3 + SL);          // 8192
    float* statsAll = (float*)(deg + 8192);     // 1536
    int*   rowst    = (int*)(statsAll + 1536);  // 8192 (+pad)
    int*   cursor   = rowst + 8256;             // 8192
    int*   eidx     = cursor + 8192;            // 131072

    unsigned short* xcat = (unsigned short*)(eidx + 131072); // [8192][512]; reused as hid
    unsigned short* qb   = xcat + 2 * SL;
    unsigned short* kb   = qb + SL;                          // reused as osb
    unsigned short* vTb  = kb + SL;
    unsigned short* osb  = kb;
    unsigned short* hid  = xcat;

    unsigned short* WcatT = vTb + SL;         // 256x512
    unsigned short* WqT   = WcatT + 131072;   // WqT|WkT|WvT contiguous = [768][256]
    unsigned short* WkT   = WqT + 65536;
    unsigned short* WvT   = WkT + 65536;
    unsigned short* WoT   = WvT + 65536;
    unsigned short* W1T   = WoT + 65536;
    unsigned short* W2T   = W1T + 131072;
    unsigned short* op0b   = (unsigned short*)s1;
    unsigned short* h1preb = (unsigned short*)s2;   // 4MB of s2; dead before out2
    unsigned short* h2preb = (unsigned short*)s3;

    dim3 gN256(4, 256);
    dim3 gN512(8, 256);

    const float QSCALE = 0.17677669529663687f * 1.4426950408889634f;

    // 1) zero deg + all BN stats in one memset
    hipMemsetAsync(deg, 0, (8192 + 1536) * sizeof(float), stream);
    // 2) fused converts + histogram
    prep_k<<<5120, 256, 0, stream>>>(x, xcat, Wr, Wn, Wq, Wk, Wv, Wo, W1, W2,
                                     WcatT, WqT, WkT, WvT, WoT, W1T, W2T, ei, deg);
    // 3-4) CSR scan / place
    scan_k<<<1, 256, 0, stream>>>(deg, rowst, cursor);
    place_k<<<Ee / 256, 256, 0, stream>>>(ei, cursor, eidx);
    // 5) gather (xcat hi, bf16 source) || QKV GEMM (fragment K/V layouts)
    gather_qkv_k<<<5120, 256, 0, stream>>>(x, rowst, deg, eidx, xcat,
                                           WqT, bq, bk, bv, qb, kb, vTb, QSCALE);
    // 6) attention (coalesced fragment K/V loads) || h1pre GEMM — 768 blocks
    attn_h1_k<<<768, 512, 0, stream>>>(qb, kb, vTb, sph, op0b,
                                       xcat, WcatT, x, h1preb,
                                       statsAll, statsAll + 256);
    // 7) h2pre = O @ Wo + bo + x -> bf16, + BN2 stats
    gemm_attnA_k<<<gN256, 256, 0, stream>>>(op0b, WoT, bo, x,
                                            h2preb, statsAll + 512, statsAll + 768);
    // 8) osb = bn1(h1pre) + bn2(h2pre)   (bf16 in/out, 12 MB pass)
    bn_apply12_k<<<(int)(SL / 1024), 256, 0, stream>>>(h1preb, h2preb, statsAll,
                                                       g1, be1, g2, be2, osb);
    // 9) hidden = relu(osb @ W1 + b1) -> hid (bf16)
    gemm_mfma_k<1><<<gN512, 256, 0, stream>>>(osb, W1T, b1, nullptr,
                                              nullptr, hid, nullptr, nullptr,
                                              BNn, Cc, Cc, 2 * Cc, 1, 1.f);
    // 10) out2 = hid @ W2 + b2 + osb(residual, bf16) -> s2 fp32, + BN3 stats
    gemm_mfma_k<2><<<gN256, 256, 0, stream>>>(hid, W2T, b2, osb,
                                              s2, nullptr, statsAll + 1024, statsAll + 1280,
                                              BNn, 2 * Cc, 2 * Cc, Cc, 0, 1.f);
    // 11) d_out = BN3(out2)
    bn_apply_k<<<(int)(SL / 1024), 256, 0, stream>>>(s2, statsAll + 1024,
                                                     statsAll + 1280, g3, be3, out);
}

// Round 15
// 302.085 us; speedup vs baseline: 1.2313x; 1.1097x over previous
//
#include <hip/hip_runtime.h>
#include <hip/hip_bf16.h>

// ---------------- problem constants ----------------
constexpr int Bg  = 8;       // graphs
constexpr int Nn  = 1024;    // nodes per graph
constexpr int Cc  = 256;     // channels
constexpr int Hh  = 8;       // heads
constexpr int DKh = 32;      // head dim
constexpr int Ee  = 131072;  // edges
constexpr int BNn = Bg * Nn; // 8192 total nodes
#define EPSV 1e-5f

typedef __attribute__((ext_vector_type(8))) short bf16x8;
typedef __attribute__((ext_vector_type(4))) float f32x4;

static __device__ __forceinline__ unsigned short f2b(float v) {
    __hip_bfloat16 h = __float2bfloat16(v);
    return __builtin_bit_cast(unsigned short, h);
}
static __device__ __forceinline__ float b2f(unsigned short u) {
    unsigned int x = ((unsigned int)u) << 16;
    return __builtin_bit_cast(float, x);
}
static __device__ __forceinline__ bf16x8 ldb8(const unsigned short* p) {
    return *(const bf16x8*)p;
}

// ---------------- fused prep: xconv + wconv + hist ----------------
// R30: ALL weight matrices now stored FRAGMENT-READY (validated by R29's
// 92->70us win on K/V): WF[nt=col/16][kt=k/32][col&15][k&31] — each wave
// B-load is one contiguous 1KB transaction instead of a 16-segment gather.
// Pure permutation; per-lane values bit-identical.
__global__ __launch_bounds__(256) void prep_k(
    const float* __restrict__ x, unsigned short* __restrict__ xcat,
    const float* __restrict__ Wr, const float* __restrict__ Wn,
    const float* __restrict__ Wq, const float* __restrict__ Wk,
    const float* __restrict__ Wv, const float* __restrict__ Wo,
    const float* __restrict__ W1, const float* __restrict__ W2,
    unsigned short* __restrict__ WcatT,
    unsigned short* __restrict__ WqT, unsigned short* __restrict__ WkT,
    unsigned short* __restrict__ WvT, unsigned short* __restrict__ WoT,
    unsigned short* __restrict__ W1T, unsigned short* __restrict__ W2T,
    const int* __restrict__ ei, int* __restrict__ deg)
{
    int blk = blockIdx.x;
    if (blk < 2048) {
        int i = (blk * 256 + threadIdx.x) * 4;
        float4 v = *(const float4*)(x + i);
        int r = i >> 8, c = i & 255;
        ushort4 pk;
        pk.x = f2b(v.x); pk.y = f2b(v.y); pk.z = f2b(v.z); pk.w = f2b(v.w);
        *(ushort4*)(xcat + (size_t)r * 512 + c) = pk;
    } else if (blk < 4608) {
        int idx = (blk - 2048) * 256 + threadIdx.x;
        if (idx < 131072) {                      // WcatT frag [n/16][k/32][16][32], K=512
            int n = idx >> 9, k = idx & 511;
            float v = (k < 256) ? Wr[k * 256 + n] : Wn[(k - 256) * 256 + n];
            WcatT[((size_t)(n >> 4) * 16 + (k >> 5)) * 512 + (n & 15) * 32 + (k & 31)] = f2b(v);
        } else if (idx < 393216) {               // q,k,v,o frag, K=256
            int l = idx - 131072;
            int wsel = l >> 16; l &= 65535;
            int n = l >> 8, kk = l & 255;
            const float* S = wsel == 0 ? Wq : wsel == 1 ? Wk : wsel == 2 ? Wv : Wo;
            unsigned short* D = wsel == 0 ? WqT : wsel == 1 ? WkT : wsel == 2 ? WvT : WoT;
            D[((size_t)(n >> 4) * 8 + (kk >> 5)) * 512 + (n & 15) * 32 + (kk & 31)]
                = f2b(S[kk * 256 + n]);
        } else if (idx < 524288) {               // W1 frag [512 cols], K=256
            int l = idx - 393216;
            int n = l >> 8, kk = l & 255;
            W1T[((size_t)(n >> 4) * 8 + (kk >> 5)) * 512 + (n & 15) * 32 + (kk & 31)]
                = f2b(W1[kk * 512 + n]);
        } else {                                 // W2 frag [256 cols], K=512
            int l = idx - 524288;
            int n = l >> 9, kk = l & 511;
            W2T[((size_t)(n >> 4) * 16 + (kk >> 5)) * 512 + (n & 15) * 32 + (kk & 31)]
                = f2b(W2[kk * 256 + n]);
        }
    } else {
        int e = (blk - 4608) * 256 + threadIdx.x;
        atomicAdd(&deg[ei[Ee + e]], 1);
    }
}

// ---------------- CSR scan (coalesced, interleaved buckets) ----------------
__global__ __launch_bounds__(256) void scan_k(
    const int* __restrict__ deg, int* __restrict__ rowst, int* __restrict__ cursor)
{
    __shared__ int partial[256];
    int t = threadIdx.x;
    int local[32];
    int s = 0;
    #pragma unroll
    for (int i = 0; i < 32; ++i) { local[i] = deg[i * 256 + t]; s += local[i]; }
    partial[t] = s;
    __syncthreads();
    for (int off = 1; off < 256; off <<= 1) {
        int v = (t >= off) ? partial[t - off] : 0;
        __syncthreads();
        partial[t] += v;
        __syncthreads();
    }
    int base = partial[t] - s;
    #pragma unroll
    for (int i = 0; i < 32; ++i) {
        int n = i * 256 + t;
        rowst[n] = base;
        cursor[n] = base;
        base += local[i];
    }
}

__global__ __launch_bounds__(256) void place_k(
    const int* __restrict__ ei, int* __restrict__ cursor, int* __restrict__ eidx)
{
    int e = blockIdx.x * 256 + threadIdx.x;
    int s = ei[e], d = ei[Ee + e];
    int pos = atomicAdd(&cursor[d], 1);
    eidx[pos] = s;
}

// ---------------- merged gather (blocks 0..2047) + QKV GEMM (2048..5119) ----------------
// R29 K/V fragment layouts kept; R30 adds fragment B-loads for the QKV GEMM.
__global__ __launch_bounds__(256, 4) void gather_qkv_k(
    const float* __restrict__ x, const int* __restrict__ rowst,
    const int* __restrict__ deg, const int* __restrict__ eidx,
    unsigned short* __restrict__ xcat,
    const unsigned short* __restrict__ WT,
    const float* __restrict__ bq, const float* __restrict__ bk,
    const float* __restrict__ bv,
    unsigned short* __restrict__ qb, unsigned short* __restrict__ kb,
    unsigned short* __restrict__ vTb, float qscale)
{
    __shared__ unsigned short vtile[64][40];
    int blk = blockIdx.x;

    if (blk < 2048) {
        // gather: 4 nodes per block, one 64-lane wave each (bf16 source)
        int n = blk * 4 + (threadIdx.x >> 6);
        int c4 = (threadIdx.x & 63) * 4;
        int b0 = rowst[n], d = deg[n];
        float4 acc = {0.f, 0.f, 0.f, 0.f};
        int i = 0;
        for (; i + 4 <= d; i += 4) {
            int s0 = eidx[b0 + i], s1 = eidx[b0 + i + 1];
            int s2 = eidx[b0 + i + 2], s3 = eidx[b0 + i + 3];
            ushort4 a0 = *(const ushort4*)(xcat + (size_t)s0 * 512 + c4);
            ushort4 a1 = *(const ushort4*)(xcat + (size_t)s1 * 512 + c4);
            ushort4 a2 = *(const ushort4*)(xcat + (size_t)s2 * 512 + c4);
            ushort4 a3 = *(const ushort4*)(xcat + (size_t)s3 * 512 + c4);
            acc.x += (b2f(a0.x) + b2f(a1.x)) + (b2f(a2.x) + b2f(a3.x));
            acc.y += (b2f(a0.y) + b2f(a1.y)) + (b2f(a2.y) + b2f(a3.y));
            acc.z += (b2f(a0.z) + b2f(a1.z)) + (b2f(a2.z) + b2f(a3.z));
            acc.w += (b2f(a0.w) + b2f(a1.w)) + (b2f(a2.w) + b2f(a3.w));
        }
        for (; i < d; ++i) {
            int s = eidx[b0 + i];
            ushort4 a = *(const ushort4*)(xcat + (size_t)s * 512 + c4);
            acc.x += b2f(a.x); acc.y += b2f(a.y);
            acc.z += b2f(a.z); acc.w += b2f(a.w);
        }
        ushort4 pk;
        pk.x = f2b(acc.x); pk.y = f2b(acc.y); pk.z = f2b(acc.z); pk.w = f2b(acc.w);
        *(ushort4*)(xcat + (size_t)n * 512 + 256 + c4) = pk;
        return;
    }

    // QKV GEMM, N=768 = [q|k|v]; fragment B (combined [768] cols, K=256)
    int qblk = blk - 2048;
    const int n0 = (qblk % 12) * 64;
    const int m0 = (qblk / 12) * 32;
    const int t = threadIdx.x;
    const int wave = t >> 6, lane = t & 63;
    const int tl = lane & 15, g = lane >> 4;
    const int wr = wave >> 1, wc = wave & 1;
    const int which = n0 >> 8;               // 0:q 1:k 2:v
    const int lda = 512;

    f32x4 acc[2] = {};

    const unsigned short* a0 = xcat + (size_t)(m0 + wr * 16 + tl) * lda + g * 8;
    const unsigned short* b0 = WT + ((size_t)(n0 >> 4) + wc * 2) * 8 * 512 + tl * 32 + g * 8;
    const unsigned short* b1 = b0 + 8 * 512;

    for (int k0 = 0; k0 < 256; k0 += 32) {
        bf16x8 af  = ldb8(a0 + k0);
        bf16x8 bf0 = ldb8(b0 + (k0 >> 5) * 512), bf1 = ldb8(b1 + (k0 >> 5) * 512);
        acc[0] = __builtin_amdgcn_mfma_f32_16x16x32_bf16(af, bf0, acc[0], 0, 0, 0);
        acc[1] = __builtin_amdgcn_mfma_f32_16x16x32_bf16(af, bf1, acc[1], 0, 0, 0);
    }

    const float* bias = which == 0 ? bq : which == 1 ? bk : bv;
    const float sc = which == 0 ? qscale : 1.f;

    if (which == 0) {
        #pragma unroll
        for (int c16 = 0; c16 < 2; ++c16)
            #pragma unroll
            for (int reg = 0; reg < 4; ++reg) {
                int row = m0 + wr * 16 + g * 4 + reg;
                int col = (n0 & 255) + wc * 32 + c16 * 16 + tl;
                qb[(size_t)row * Cc + col] = f2b((acc[c16][reg] + bias[col]) * sc);
            }
    } else if (which == 1) {
        // K fragment layout: kf[(row>>4)*8 + (col>>5)][row&15][col&31]
        #pragma unroll
        for (int c16 = 0; c16 < 2; ++c16)
            #pragma unroll
            for (int reg = 0; reg < 4; ++reg) {
                int row = m0 + wr * 16 + g * 4 + reg;
                int col = (n0 & 255) + wc * 32 + c16 * 16 + tl;
                kb[((size_t)(row >> 4) * 8 + (col >> 5)) * 512
                   + (row & 15) * 32 + (col & 31)] = f2b(acc[c16][reg] + bias[col]);
            }
    } else {
        #pragma unroll
        for (int c16 = 0; c16 < 2; ++c16)
            #pragma unroll
            for (int reg = 0; reg < 4; ++reg) {
                int colL = wc * 32 + c16 * 16 + tl;
                int rowL = wr * 16 + g * 4 + reg;
                vtile[colL][rowL] = f2b(acc[c16][reg] + bias[(n0 & 255) + colL]);
            }
        __syncthreads();
        // V fragment layout: vf[b][h][m/64][ks][cg][tl][g][m8]
        int clocal = t >> 2, q4 = t & 3;
        int colg = (n0 & 255) + clocal;
        int hh = colg >> 5, dd = colg & 31;
        int bg = m0 >> 10;
        int m_loc = (m0 & 1023) + q4 * 8;
        int mt64 = m_loc >> 6, ks = (m_loc >> 5) & 1, gg = (m_loc >> 3) & 3;
        int cg = dd >> 4, tlv = dd & 15;
        ushort4 u0 = *(ushort4*)&vtile[clocal][q4 * 8];
        ushort4 u1 = *(ushort4*)&vtile[clocal][q4 * 8 + 4];
        unsigned short* dst = vTb
            + (((size_t)(bg * Hh + hh) * 16 + mt64) * 2048)
            + ((size_t)((ks * 2 + cg) * 16 + tlv) * 32) + gg * 8;
        *(ushort4*)dst = u0;
        *(ushort4*)(dst + 4) = u1;
    }
}

// ---------------- merged attention (blocks 0..511) + h1pre GEMM (512..767) ----------------
// R30: attn side unchanged from R29 (coalesced fragment K/V). h1pre GEMM
// B-loads now hit fragment WcatT: 4 B-transactions/iter instead of 64.
__global__ __launch_bounds__(512, 8) void attn_h1_k(
    const unsigned short* __restrict__ q, const unsigned short* __restrict__ k,
    const unsigned short* __restrict__ vT, const float* __restrict__ sph,
    unsigned short* __restrict__ op0,
    const unsigned short* __restrict__ xcat, const unsigned short* __restrict__ WcatT,
    const float* __restrict__ x, unsigned short* __restrict__ h1preb,
    float* __restrict__ gsum, float* __restrict__ gsq)
{
    __shared__ float Sph[2][16][132];          // 16896 B
    __shared__ unsigned short Ps[Hh][16][72];  // 18432 B
    float* csum = (float*)&Ps[0][0][0];     // [256], aliased (gemm branch only)
    float* csq  = csum + 256;

    const int blk = blockIdx.x;
    const int t = threadIdx.x;
    const int wave = t >> 6;
    const int lane = t & 63;
    const int tl = lane & 15, g = lane >> 4;

    if (blk < 512) {
        // ---------- attention: 16 q-rows, full m-range, graph pinned to XCD ----------
        const int b  = blk & 7;             // graph == XCD (round-robin dispatch)
        const int n0 = (blk >> 3) * 16;     // 64 row-tiles per graph
        const int w  = wave;

        bf16x8 qf = ldb8(q + ((size_t)(b * Nn + n0 + tl)) * Cc + w * DKh + g * 8);

        float lsum = 0.f;
        f32x4 oacc[2] = {};

        // coalesced fragment bases: lane offset = (tl*4+g)*16B within each 1KB tile
        const unsigned short* kfb = k + ((size_t)(b * 512 + w)) * 512 + tl * 32 + g * 8;
        const unsigned short* vfb = vT + ((size_t)(b * Hh + w) * 16) * 2048
                                     + (size_t)tl * 32 + g * 8;
        const float* sbase = sph + ((size_t)b * Nn + n0) * Nn;

        // prologue: stage sph tile 0 (16x128) into buffer 0; 256 thr x 2 float4
        if (t < 256) {
            int r1 = t >> 4, c1 = (t & 15) * 8;
            const float* src = sbase + (size_t)r1 * Nn + c1;
            *(float4*)&Sph[0][r1][c1]     = *(const float4*)src;
            *(float4*)&Sph[0][r1][c1 + 4] = *(const float4*)(src + 4);
        }
        __syncthreads();

        int cur = 0;
        for (int it = 0; it < 8; ++it) {
            const int m0 = it * 128;
            // stage NEXT 16x128 tile into the other buffer
            if (it < 7 && t < 256) {
                int r1 = t >> 4, c1 = (t & 15) * 8;
                const float* src = sbase + (size_t)r1 * Nn + m0 + 128 + c1;
                *(float4*)&Sph[cur ^ 1][r1][c1]     = *(const float4*)src;
                *(float4*)&Sph[cur ^ 1][r1][c1 + 4] = *(const float4*)(src + 4);
            }

            #pragma unroll
            for (int half = 0; half < 2; ++half) {
                const int mh = m0 + half * 64;

                f32x4 st[4];
                #pragma unroll
                for (int mg = 0; mg < 4; ++mg) {
                    bf16x8 ka = ldb8(kfb + (size_t)((mh >> 4) + mg) * 4096);
                    f32x4 z = {0.f, 0.f, 0.f, 0.f};
                    st[mg] = __builtin_amdgcn_mfma_f32_16x16x32_bf16(ka, qf, z, 0, 0, 0);
                }

                #pragma unroll
                for (int mg = 0; mg < 4; ++mg) {
                    float4 sp = *(const float4*)&Sph[cur][tl][half * 64 + mg * 16 + g * 4];
                    float p0 = __builtin_amdgcn_exp2f(st[mg][0] * sp.x);
                    float p1 = __builtin_amdgcn_exp2f(st[mg][1] * sp.y);
                    float p2 = __builtin_amdgcn_exp2f(st[mg][2] * sp.z);
                    float p3 = __builtin_amdgcn_exp2f(st[mg][3] * sp.w);
                    lsum += (p0 + p1) + (p2 + p3);
                    ushort4 pk;
                    pk.x = f2b(p0); pk.y = f2b(p1); pk.z = f2b(p2); pk.w = f2b(p3);
                    *(ushort4*)&Ps[w][tl][mg * 16 + g * 4] = pk;
                }

                const unsigned short* vtile64 = vfb + (size_t)(mh >> 6) * 2048;
                #pragma unroll
                for (int ks = 0; ks < 2; ++ks) {
                    bf16x8 pa = ldb8(&Ps[w][tl][ks * 32 + g * 8]);
                    #pragma unroll
                    for (int cg = 0; cg < 2; ++cg) {
                        bf16x8 vb = ldb8(vtile64 + (size_t)(ks * 2 + cg) * 512);
                        oacc[cg] = __builtin_amdgcn_mfma_f32_16x16x32_bf16(pa, vb, oacc[cg], 0, 0, 0);
                    }
                }
            }

            __syncthreads();   // staging writes visible; Sph[cur]/Ps reads complete
            cur ^= 1;
        }

        // full-row softmax denominator -> normalize O in-register.
        lsum += __shfl_xor(lsum, 16);
        lsum += __shfl_xor(lsum, 32);      // every lane: sum for q-row tl
        float* shl = (float*)&Ps[w][0][0]; // per-wave scratch (Ps dead now)
        if (g == 0) shl[tl] = lsum;        // wave-local write->read, no barrier
        #pragma unroll
        for (int r = 0; r < 4; ++r) {
            float inv = 1.f / shl[g * 4 + r];   // O row = g*4+r
            #pragma unroll
            for (int cg = 0; cg < 2; ++cg)
                op0[((size_t)(b * Nn + n0 + g * 4 + r)) * Cc + w * DKh + cg * 16 + tl]
                    = f2b(oacc[cg][r] * inv);
        }
        return;
    }

    // ---------- h1pre GEMM: one 32x256 tile per block (A once, frag B) ----------
    const int wrg = wave >> 2;              // 0..1 row group
    const int wcg = wave & 3;               // 0..3 col group (64 cols each)
    const int m0g = (blk - 512) * 32;
    const int N = Cc;

    if (t < 256) { csum[t] = 0.f; csq[t] = 0.f; }
    __syncthreads();

    f32x4 acc[4] = {};

    const unsigned short* a0 = xcat + (size_t)(m0g + wrg * 16 + tl) * 512 + g * 8;
    const unsigned short* bb = WcatT + (size_t)(wcg * 4) * 16 * 512 + tl * 32 + g * 8;

    for (int k0 = 0; k0 < 512; k0 += 32) {
        bf16x8 af = ldb8(a0 + k0);
        #pragma unroll
        for (int c16 = 0; c16 < 4; ++c16) {
            bf16x8 bf = ldb8(bb + ((size_t)c16 * 16 + (k0 >> 5)) * 512);
            acc[c16] = __builtin_amdgcn_mfma_f32_16x16x32_bf16(af, bf, acc[c16], 0, 0, 0);
        }
    }

    #pragma unroll
    for (int c16 = 0; c16 < 4; ++c16) {
        int col = wcg * 64 + c16 * 16 + tl;
        float ls = 0.f, lq = 0.f;
        #pragma unroll
        for (int reg = 0; reg < 4; ++reg) {
            int row = m0g + wrg * 16 + g * 4 + reg;
            size_t idx = (size_t)row * N + col;
            float v = acc[c16][reg] + x[idx];
            ls += v; lq += v * v;               // stats in fp32 (pre-rounding)
            h1preb[idx] = f2b(v);
        }
        atomicAdd(&csum[col], ls);
        atomicAdd(&csq[col],  lq);
    }
    __syncthreads();
    if (t < 256) {
        atomicAdd(&gsum[t], csum[t]);
        atomicAdd(&gsq[t],  csq[t]);
    }
}

// ---------------- MFMA GEMM, 32x64 tile, fragment B, optional bf16 residual + BN-stats ----------------
// TAG: 1 = mlp1 (N=512, K=256), 2 = mlp2 (K=512, bf16 residual addb = osb).
template<int TAG>
__global__ __launch_bounds__(256, 4) void gemm_mfma_k(
    const unsigned short* __restrict__ A, const unsigned short* __restrict__ WT,
    const float* __restrict__ bias, const unsigned short* __restrict__ addb,
    float* __restrict__ outf, unsigned short* __restrict__ outb,
    float* __restrict__ gsum, float* __restrict__ gsq,
    int M, int K, int lda, int N, int relu, float oscale)
{
    const int t = threadIdx.x;
    const int wave = t >> 6, lane = t & 63;
    const int tl = lane & 15, g = lane >> 4;
    const int wr = wave >> 1, wc = wave & 1;
    const int m0 = blockIdx.y * 32, n0 = blockIdx.x * 64;

    __shared__ float csum[64], csq[64];
    if (gsum) {
        if (t < 64) { csum[t] = 0.f; csq[t] = 0.f; }
        __syncthreads();
    }

    f32x4 acc[2] = {};

    const int kt = K >> 5;  // k-tiles
    const unsigned short* a0 = A  + (size_t)(m0 + wr * 16 + tl) * lda + g * 8;
    const unsigned short* b0 = WT + ((size_t)(n0 >> 4) + wc * 2) * kt * 512 + tl * 32 + g * 8;
    const unsigned short* b1 = b0 + (size_t)kt * 512;

    for (int k0 = 0; k0 < K; k0 += 32) {
        bf16x8 af  = ldb8(a0 + k0);
        bf16x8 bf0 = ldb8(b0 + (k0 >> 5) * 512), bf1 = ldb8(b1 + (k0 >> 5) * 512);
        acc[0] = __builtin_amdgcn_mfma_f32_16x16x32_bf16(af, bf0, acc[0], 0, 0, 0);
        acc[1] = __builtin_amdgcn_mfma_f32_16x16x32_bf16(af, bf1, acc[1], 0, 0, 0);
    }

    #pragma unroll
    for (int c16 = 0; c16 < 2; ++c16) {
        int colL = wc * 32 + c16 * 16 + tl;
        int col  = n0 + colL;
        float ls = 0.f, lq = 0.f;
        #pragma unroll
        for (int reg = 0; reg < 4; ++reg) {
            int row = m0 + wr * 16 + g * 4 + reg;
            float v = acc[c16][reg];
            if (bias) v += bias[col];
            v *= oscale;
            size_t idx = (size_t)row * N + col;
            if (addb) v += b2f(addb[idx]);
            ls += v; lq += v * v;
            if (relu) v = fmaxf(v, 0.f);
            if (outf) outf[idx] = v;
            if (outb) outb[idx] = f2b(v);
        }
        if (gsum) { atomicAdd(&csum[colL], ls); atomicAdd(&csq[colL], lq); }
    }
    if (gsum) {
        __syncthreads();
        if (t < 64) {
            atomicAdd(&gsum[n0 + t], csum[t]);
            atomicAdd(&gsq[n0 + t],  csq[t]);
        }
    }
}

// ---------------- Wo GEMM (A = normalized bf16 O, frag B) + fp32 residual + BN2 stats ----------------
__global__ __launch_bounds__(256, 4) void gemm_attnA_k(
    const unsigned short* __restrict__ op0,
    const unsigned short* __restrict__ WT, const float* __restrict__ bias,
    const float* __restrict__ add1, unsigned short* __restrict__ h2preb,
    float* __restrict__ gsum, float* __restrict__ gsq)
{
    const int K = Cc, N = Cc;
    const int t = threadIdx.x;
    const int wave = t >> 6, lane = t & 63;
    const int tl = lane & 15, g = lane >> 4;
    const int wr = wave >> 1, wc = wave & 1;
    const int m0 = blockIdx.y * 32, n0 = blockIdx.x * 64;

    __shared__ float csum[64], csq[64];
    if (t < 64) { csum[t] = 0.f; csq[t] = 0.f; }
    __syncthreads();

    f32x4 acc[2] = {};

    const int arow = m0 + wr * 16 + tl;
    const unsigned short* a0b = op0 + (size_t)arow * K + g * 8;
    const unsigned short* b0 = WT + ((size_t)(n0 >> 4) + wc * 2) * 8 * 512 + tl * 32 + g * 8;
    const unsigned short* b1 = b0 + 8 * 512;

    for (int k0 = 0; k0 < K; k0 += 32) {
        bf16x8 af  = ldb8(a0b + k0);
        bf16x8 bf0 = ldb8(b0 + (k0 >> 5) * 512), bf1 = ldb8(b1 + (k0 >> 5) * 512);
        acc[0] = __builtin_amdgcn_mfma_f32_16x16x32_bf16(af, bf0, acc[0], 0, 0, 0);
        acc[1] = __builtin_amdgcn_mfma_f32_16x16x32_bf16(af, bf1, acc[1], 0, 0, 0);
    }

    #pragma unroll
    for (int c16 = 0; c16 < 2; ++c16) {
        int colL = wc * 32 + c16 * 16 + tl;
        int col  = n0 + colL;
        float ls = 0.f, lq = 0.f;
        #pragma unroll
        for (int reg = 0; reg < 4; ++reg) {
            int row = m0 + wr * 16 + g * 4 + reg;
            float v = acc[c16][reg] + bias[col];
            size_t idx = (size_t)row * N + col;
            v += add1[idx];
            ls += v; lq += v * v;               // stats in fp32 (pre-rounding)
            h2preb[idx] = f2b(v);
        }
        atomicAdd(&csum[colL], ls); atomicAdd(&csq[colL], lq);
    }
    __syncthreads();
    if (t < 64) {
        atomicAdd(&gsum[n0 + t], csum[t]);
        atomicAdd(&gsq[n0 + t],  csq[t]);
    }
}

// ---------------- BN apply (single, float4) ----------------
__global__ __launch_bounds__(256) void bn_apply_k(
    const float* __restrict__ h, const float* __restrict__ gsum,
    const float* __restrict__ gsq, const float* __restrict__ gamma,
    const float* __restrict__ beta, float* __restrict__ outf)
{
    size_t i4 = ((size_t)blockIdx.x * 256 + threadIdx.x) * 4;
    int ch = (int)(i4 & (Cc - 1));
    float4 hv = *(const float4*)(h + i4);
    float4 sm = *(const float4*)(gsum + ch);
    float4 sq = *(const float4*)(gsq + ch);
    float4 ga = *(const float4*)(gamma + ch);
    float4 be = *(const float4*)(beta + ch);
    float4 o;
    {
        float m = sm.x * (1.f / BNn), var = sq.x * (1.f / BNn) - m * m;
        o.x = (hv.x - m) * rsqrtf(var + EPSV) * ga.x + be.x;
    }
    {
        float m = sm.y * (1.f / BNn), var = sq.y * (1.f / BNn) - m * m;
        o.y = (hv.y - m) * rsqrtf(var + EPSV) * ga.y + be.y;
    }
    {
        float m = sm.z * (1.f / BNn), var = sq.z * (1.f / BNn) - m * m;
        o.z = (hv.z - m) * rsqrtf(var + EPSV) * ga.z + be.z;
    }
    {
        float m = sm.w * (1.f / BNn), var = sq.w * (1.f / BNn) - m * m;
        o.w = (hv.w - m) * rsqrtf(var + EPSV) * ga.w + be.w;
    }
    *(float4*)(outf + i4) = o;
}

// ---------------- fused BN1+BN2 apply (bf16 in / bf16 out, 12 MB total) ----------------
__global__ __launch_bounds__(256) void bn_apply12_k(
    const unsigned short* __restrict__ h1preb, const unsigned short* __restrict__ h2preb,
    const float* __restrict__ stats,
    const float* __restrict__ g1, const float* __restrict__ be1,
    const float* __restrict__ g2, const float* __restrict__ be2,
    unsigned short* __restrict__ outb)
{
    size_t i4 = ((size_t)blockIdx.x * 256 + threadIdx.x) * 4;
    int ch = (int)(i4 & (Cc - 1));
    ushort4 u1 = *(const ushort4*)(h1preb + i4);
    ushort4 u2 = *(const ushort4*)(h2preb + i4);
    float4 s1m = *(const float4*)(stats + ch);
    float4 s1q = *(const float4*)(stats + 256 + ch);
    float4 s2m = *(const float4*)(stats + 512 + ch);
    float4 s2q = *(const float4*)(stats + 768 + ch);
    float4 G1 = *(const float4*)(g1 + ch),  B1 = *(const float4*)(be1 + ch);
    float4 G2 = *(const float4*)(g2 + ch),  B2 = *(const float4*)(be2 + ch);
    ushort4 pk;
    #define BN12C(comp, ucomp) { \
        float m1 = s1m.comp * (1.f / BNn), v1 = s1q.comp * (1.f / BNn) - m1 * m1; \
        float m2 = s2m.comp * (1.f / BNn), v2 = s2q.comp * (1.f / BNn) - m2 * m2; \
        float o = (b2f(u1.ucomp) - m1) * rsqrtf(v1 + EPSV) * G1.comp + B1.comp \
                + (b2f(u2.ucomp) - m2) * rsqrtf(v2 + EPSV) * G2.comp + B2.comp; \
        pk.ucomp = f2b(o); }
    BN12C(x, x) BN12C(y, y) BN12C(z, z) BN12C(w, w)
    #undef BN12C
    *(ushort4*)(outb + i4) = pk;
}

// ---------------- launch ----------------
extern "C" void kernel_launch(void* const* d_in, const int* in_sizes, int n_in,
                              void* d_out, int out_size, void* d_ws, size_t ws_size,
                              hipStream_t stream)
{
    const float* x   = (const float*)d_in[0];
    const int*   ei  = (const int*)  d_in[1];
    const float* sph = (const float*)d_in[2];
    const float* Wr  = (const float*)d_in[3];
    const float* Wn  = (const float*)d_in[4];
    const float* Wq  = (const float*)d_in[5];
    const float* bq  = (const float*)d_in[6];
    const float* Wk  = (const float*)d_in[7];
    const float* bk  = (const float*)d_in[8];
    const float* Wv  = (const float*)d_in[9];
    const float* bv  = (const float*)d_in[10];
    const float* Wo  = (const float*)d_in[11];
    const float* bo  = (const float*)d_in[12];
    const float* W1  = (const float*)d_in[13];
    const float* b1  = (const float*)d_in[14];
    const float* W2  = (const float*)d_in[15];
    const float* b2  = (const float*)d_in[16];
    const float* g1  = (const float*)d_in[17];
    const float* be1 = (const float*)d_in[18];
    const float* g2  = (const float*)d_in[19];
    const float* be2 = (const float*)d_in[20];
    const float* g3  = (const float*)d_in[21];
    const float* be3 = (const float*)d_in[22];
    float* out = (float*)d_out;

    const size_t SL = (size_t)BNn * Cc;  // 2M elements

    float* ws = (float*)d_ws;
    float* s1 = ws;                  // op0b (bf16, 4MB)
    float* s2 = s1 + SL;             // h1preb (bf16) then out2 (fp32)
    float* s3 = s2 + SL;             // h2preb (bf16)

    int*   deg      = (int*)(s3 + SL);          // 8192
    float* statsAll = (float*)(deg + 8192);     // 1536
    int*   rowst    = (int*)(statsAll + 1536);  // 8192 (+pad)
    int*   cursor   = rowst + 8256;             // 8192
    int*   eidx     = cursor + 8192;            // 131072

    unsigned short* xcat = (unsigned short*)(eidx + 131072); // [8192][512]; reused as hid
    unsigned short* qb   = xcat + 2 * SL;
    unsigned short* kb   = qb + SL;                          // reused as osb
    unsigned short* vTb  = kb + SL;
    unsigned short* osb  = kb;
    unsigned short* hid  = xcat;

    unsigned short* WcatT = vTb + SL;         // 256x512
    unsigned short* WqT   = WcatT + 131072;   // WqT|WkT|WvT contiguous = [768][256]
    unsigned short* WkT   = WqT + 65536;
    unsigned short* WvT   = WkT + 65536;
    unsigned short* WoT   = WvT + 65536;
    unsigned short* W1T   = WoT + 65536;
    unsigned short* W2T   = W1T + 131072;
    unsigned short* op0b   = (unsigned short*)s1;
    unsigned short* h1preb = (unsigned short*)s2;   // 4MB of s2; dead before out2
    unsigned short* h2preb = (unsigned short*)s3;

    dim3 gN256(4, 256);
    dim3 gN512(8, 256);

    const float QSCALE = 0.17677669529663687f * 1.4426950408889634f;

    // 1) zero deg + all BN stats in one memset
    hipMemsetAsync(deg, 0, (8192 + 1536) * sizeof(float), stream);
    // 2) fused converts + histogram (fragment weight layouts)
    prep_k<<<5120, 256, 0, stream>>>(x, xcat, Wr, Wn, Wq, Wk, Wv, Wo, W1, W2,
                                     WcatT, WqT, WkT, WvT, WoT, W1T, W2T, ei, deg);
    // 3-4) CSR scan / place
    scan_k<<<1, 256, 0, stream>>>(deg, rowst, cursor);
    place_k<<<Ee / 256, 256, 0, stream>>>(ei, cursor, eidx);
    // 5) gather (xcat hi, bf16 source) || QKV GEMM (frag B + frag K/V out)
    gather_qkv_k<<<5120, 256, 0, stream>>>(x, rowst, deg, eidx, xcat,
                                           WqT, bq, bk, bv, qb, kb, vTb, QSCALE);
    // 6) attention (coalesced frag K/V) || h1pre GEMM (frag B) — 768 blocks
    attn_h1_k<<<768, 512, 0, stream>>>(qb, kb, vTb, sph, op0b,
                                       xcat, WcatT, x, h1preb,
                                       statsAll, statsAll + 256);
    // 7) h2pre = O @ Wo + bo + x -> bf16, + BN2 stats
    gemm_attnA_k<<<gN256, 256, 0, stream>>>(op0b, WoT, bo, x,
                                            h2preb, statsAll + 512, statsAll + 768);
    // 8) osb = bn1(h1pre) + bn2(h2pre)   (bf16 in/out, 12 MB pass)
    bn_apply12_k<<<(int)(SL / 1024), 256, 0, stream>>>(h1preb, h2preb, statsAll,
                                                       g1, be1, g2, be2, osb);
    // 9) hidden = relu(osb @ W1 + b1) -> hid (bf16)
    gemm_mfma_k<1><<<gN512, 256, 0, stream>>>(osb, W1T, b1, nullptr,
                                              nullptr, hid, nullptr, nullptr,
                                              BNn, Cc, Cc, 2 * Cc, 1, 1.f);
    // 10) out2 = hid @ W2 + b2 + osb(residual, bf16) -> s2 fp32, + BN3 stats
    gemm_mfma_k<2><<<gN256, 256, 0, stream>>>(hid, W2T, b2, osb,
                                              s2, nullptr, statsAll + 1024, statsAll + 1280,
                                              BNn, 2 * Cc, 2 * Cc, Cc, 0, 1.f);
    // 11) d_out = BN3(out2)
    bn_apply_k<<<(int)(SL / 1024), 256, 0, stream>>>(s2, statsAll + 1024,
                                                     statsAll + 1280, g3, be3, out);
}

// Round 16
// 285.204 us; speedup vs baseline: 1.3042x; 1.0592x over previous
//
#include <hip/hip_runtime.h>
#include <hip/hip_bf16.h>

// ---------------- problem constants ----------------
constexpr int Bg  = 8;       // graphs
constexpr int Nn  = 1024;    // nodes per graph
constexpr int Cc  = 256;     // channels
constexpr int Hh  = 8;       // heads
constexpr int DKh = 32;      // head dim
constexpr int Ee  = 131072;  // edges
constexpr int BNn = Bg * Nn; // 8192 total nodes
#define EPSV 1e-5f

// R31: ALL dynamic GEMM A-operands now fragment-ready too (R29/R30 validated
// the model: wave address divergence = transaction throughput = the pipeline
// pole). Universal fragment formula, KT = K/32 tiles per row-tile:
//   idx(row,col) = ((row>>4)*KT + (col>>5))*512 + (row&15)*32 + (col&31)
// xf (KT=16), op0 (KT=8), osb (KT=8), hid (KT=16). A row-major copy xlo
// keeps the gather's random row reads 1-segment.

typedef __attribute__((ext_vector_type(8))) short bf16x8;
typedef __attribute__((ext_vector_type(4))) float f32x4;

static __device__ __forceinline__ unsigned short f2b(float v) {
    __hip_bfloat16 h = __float2bfloat16(v);
    return __builtin_bit_cast(unsigned short, h);
}
static __device__ __forceinline__ float b2f(unsigned short u) {
    unsigned int x = ((unsigned int)u) << 16;
    return __builtin_bit_cast(float, x);
}
static __device__ __forceinline__ bf16x8 ldb8(const unsigned short* p) {
    return *(const bf16x8*)p;
}

// ---------------- fused prep: xconv + wconv + hist ----------------
__global__ __launch_bounds__(256) void prep_k(
    const float* __restrict__ x, unsigned short* __restrict__ xf,
    unsigned short* __restrict__ xlo,
    const float* __restrict__ Wr, const float* __restrict__ Wn,
    const float* __restrict__ Wq, const float* __restrict__ Wk,
    const float* __restrict__ Wv, const float* __restrict__ Wo,
    const float* __restrict__ W1, const float* __restrict__ W2,
    unsigned short* __restrict__ WcatT,
    unsigned short* __restrict__ WqT, unsigned short* __restrict__ WkT,
    unsigned short* __restrict__ WvT, unsigned short* __restrict__ WoT,
    unsigned short* __restrict__ W1T, unsigned short* __restrict__ W2T,
    const int* __restrict__ ei, int* __restrict__ deg)
{
    int blk = blockIdx.x;
    if (blk < 2048) {
        int i = (blk * 256 + threadIdx.x) * 4;
        float4 v = *(const float4*)(x + i);
        int r = i >> 8, c = i & 255;
        ushort4 pk;
        pk.x = f2b(v.x); pk.y = f2b(v.y); pk.z = f2b(v.z); pk.w = f2b(v.w);
        *(ushort4*)(xlo + (size_t)r * 256 + c) = pk;       // row-major (gather src)
        *(ushort4*)(xf + ((size_t)(r >> 4) * 16 + (c >> 5)) * 512
                    + (r & 15) * 32 + (c & 31)) = pk;      // fragment (GEMM A)
    } else if (blk < 4608) {
        int idx = (blk - 2048) * 256 + threadIdx.x;
        if (idx < 131072) {                      // WcatT frag [n/16][k/32][16][32], K=512
            int n = idx >> 9, k = idx & 511;
            float v = (k < 256) ? Wr[k * 256 + n] : Wn[(k - 256) * 256 + n];
            WcatT[((size_t)(n >> 4) * 16 + (k >> 5)) * 512 + (n & 15) * 32 + (k & 31)] = f2b(v);
        } else if (idx < 393216) {               // q,k,v,o frag, K=256
            int l = idx - 131072;
            int wsel = l >> 16; l &= 65535;
            int n = l >> 8, kk = l & 255;
            const float* S = wsel == 0 ? Wq : wsel == 1 ? Wk : wsel == 2 ? Wv : Wo;
            unsigned short* D = wsel == 0 ? WqT : wsel == 1 ? WkT : wsel == 2 ? WvT : WoT;
            D[((size_t)(n >> 4) * 8 + (kk >> 5)) * 512 + (n & 15) * 32 + (kk & 31)]
                = f2b(S[kk * 256 + n]);
        } else if (idx < 524288) {               // W1 frag [512 cols], K=256
            int l = idx - 393216;
            int n = l >> 8, kk = l & 255;
            W1T[((size_t)(n >> 4) * 8 + (kk >> 5)) * 512 + (n & 15) * 32 + (kk & 31)]
                = f2b(W1[kk * 512 + n]);
        } else {                                 // W2 frag [256 cols], K=512
            int l = idx - 524288;
            int n = l >> 9, kk = l & 511;
            W2T[((size_t)(n >> 4) * 16 + (kk >> 5)) * 512 + (n & 15) * 32 + (kk & 31)]
                = f2b(W2[kk * 256 + n]);
        }
    } else {
        int e = (blk - 4608) * 256 + threadIdx.x;
        atomicAdd(&deg[ei[Ee + e]], 1);
    }
}

// ---------------- CSR scan (coalesced, interleaved buckets) ----------------
__global__ __launch_bounds__(256) void scan_k(
    const int* __restrict__ deg, int* __restrict__ rowst, int* __restrict__ cursor)
{
    __shared__ int partial[256];
    int t = threadIdx.x;
    int local[32];
    int s = 0;
    #pragma unroll
    for (int i = 0; i < 32; ++i) { local[i] = deg[i * 256 + t]; s += local[i]; }
    partial[t] = s;
    __syncthreads();
    for (int off = 1; off < 256; off <<= 1) {
        int v = (t >= off) ? partial[t - off] : 0;
        __syncthreads();
        partial[t] += v;
        __syncthreads();
    }
    int base = partial[t] - s;
    #pragma unroll
    for (int i = 0; i < 32; ++i) {
        int n = i * 256 + t;
        rowst[n] = base;
        cursor[n] = base;
        base += local[i];
    }
}

__global__ __launch_bounds__(256) void place_k(
    const int* __restrict__ ei, int* __restrict__ cursor, int* __restrict__ eidx)
{
    int e = blockIdx.x * 256 + threadIdx.x;
    int s = ei[e], d = ei[Ee + e];
    int pos = atomicAdd(&cursor[d], 1);
    eidx[pos] = s;
}

// ---------------- merged gather (blocks 0..2047) + QKV GEMM (2048..5119) ----------------
__global__ __launch_bounds__(256, 4) void gather_qkv_k(
    const unsigned short* __restrict__ xlo, const int* __restrict__ rowst,
    const int* __restrict__ deg, const int* __restrict__ eidx,
    unsigned short* __restrict__ xf,
    const unsigned short* __restrict__ WT,
    const float* __restrict__ bq, const float* __restrict__ bk,
    const float* __restrict__ bv,
    unsigned short* __restrict__ qb, unsigned short* __restrict__ kb,
    unsigned short* __restrict__ vTb, float qscale)
{
    __shared__ unsigned short vtile[64][40];
    int blk = blockIdx.x;

    if (blk < 2048) {
        // gather: 4 nodes per block, one 64-lane wave each (bf16 row-major src)
        int n = blk * 4 + (threadIdx.x >> 6);
        int c4 = (threadIdx.x & 63) * 4;
        int b0 = rowst[n], d = deg[n];
        float4 acc = {0.f, 0.f, 0.f, 0.f};
        int i = 0;
        for (; i + 4 <= d; i += 4) {
            int s0 = eidx[b0 + i], s1 = eidx[b0 + i + 1];
            int s2 = eidx[b0 + i + 2], s3 = eidx[b0 + i + 3];
            ushort4 a0 = *(const ushort4*)(xlo + (size_t)s0 * 256 + c4);
            ushort4 a1 = *(const ushort4*)(xlo + (size_t)s1 * 256 + c4);
            ushort4 a2 = *(const ushort4*)(xlo + (size_t)s2 * 256 + c4);
            ushort4 a3 = *(const ushort4*)(xlo + (size_t)s3 * 256 + c4);
            acc.x += (b2f(a0.x) + b2f(a1.x)) + (b2f(a2.x) + b2f(a3.x));
            acc.y += (b2f(a0.y) + b2f(a1.y)) + (b2f(a2.y) + b2f(a3.y));
            acc.z += (b2f(a0.z) + b2f(a1.z)) + (b2f(a2.z) + b2f(a3.z));
            acc.w += (b2f(a0.w) + b2f(a1.w)) + (b2f(a2.w) + b2f(a3.w));
        }
        for (; i < d; ++i) {
            int s = eidx[b0 + i];
            ushort4 a = *(const ushort4*)(xlo + (size_t)s * 256 + c4);
            acc.x += b2f(a.x); acc.y += b2f(a.y);
            acc.z += b2f(a.z); acc.w += b2f(a.w);
        }
        ushort4 pk;
        pk.x = f2b(acc.x); pk.y = f2b(acc.y); pk.z = f2b(acc.z); pk.w = f2b(acc.w);
        int cg2 = 256 + c4;                    // agg occupies cols 256..511 of xf
        *(ushort4*)(xf + ((size_t)(n >> 4) * 16 + (cg2 >> 5)) * 512
                    + (n & 15) * 32 + (cg2 & 31)) = pk;
        return;
    }

    // QKV GEMM, N=768 = [q|k|v]; fragment A (xf kts 0..7) + fragment B
    int qblk = blk - 2048;
    const int n0 = (qblk % 12) * 64;
    const int m0 = (qblk / 12) * 32;
    const int t = threadIdx.x;
    const int wave = t >> 6, lane = t & 63;
    const int tl = lane & 15, g = lane >> 4;
    const int wr = wave >> 1, wc = wave & 1;
    const int which = n0 >> 8;               // 0:q 1:k 2:v

    f32x4 acc[2] = {};

    const unsigned short* a0 = xf + (size_t)((m0 >> 4) + wr) * 16 * 512 + tl * 32 + g * 8;
    const unsigned short* b0 = WT + ((size_t)(n0 >> 4) + wc * 2) * 8 * 512 + tl * 32 + g * 8;
    const unsigned short* b1 = b0 + 8 * 512;

    for (int k0 = 0; k0 < 256; k0 += 32) {
        bf16x8 af  = ldb8(a0 + (k0 >> 5) * 512);
        bf16x8 bf0 = ldb8(b0 + (k0 >> 5) * 512), bf1 = ldb8(b1 + (k0 >> 5) * 512);
        acc[0] = __builtin_amdgcn_mfma_f32_16x16x32_bf16(af, bf0, acc[0], 0, 0, 0);
        acc[1] = __builtin_amdgcn_mfma_f32_16x16x32_bf16(af, bf1, acc[1], 0, 0, 0);
    }

    const float* bias = which == 0 ? bq : which == 1 ? bk : bv;
    const float sc = which == 0 ? qscale : 1.f;

    if (which == 0) {
        #pragma unroll
        for (int c16 = 0; c16 < 2; ++c16)
            #pragma unroll
            for (int reg = 0; reg < 4; ++reg) {
                int row = m0 + wr * 16 + g * 4 + reg;
                int col = (n0 & 255) + wc * 32 + c16 * 16 + tl;
                qb[(size_t)row * Cc + col] = f2b((acc[c16][reg] + bias[col]) * sc);
            }
    } else if (which == 1) {
        // K fragment layout: kf[(row>>4)*8 + (col>>5)][row&15][col&31]
        #pragma unroll
        for (int c16 = 0; c16 < 2; ++c16)
            #pragma unroll
            for (int reg = 0; reg < 4; ++reg) {
                int row = m0 + wr * 16 + g * 4 + reg;
                int col = (n0 & 255) + wc * 32 + c16 * 16 + tl;
                kb[((size_t)(row >> 4) * 8 + (col >> 5)) * 512
                   + (row & 15) * 32 + (col & 31)] = f2b(acc[c16][reg] + bias[col]);
            }
    } else {
        #pragma unroll
        for (int c16 = 0; c16 < 2; ++c16)
            #pragma unroll
            for (int reg = 0; reg < 4; ++reg) {
                int colL = wc * 32 + c16 * 16 + tl;
                int rowL = wr * 16 + g * 4 + reg;
                vtile[colL][rowL] = f2b(acc[c16][reg] + bias[(n0 & 255) + colL]);
            }
        __syncthreads();
        // V fragment layout: vf[b][h][m/64][ks][cg][tl][g][m8]
        int clocal = t >> 2, q4 = t & 3;
        int colg = (n0 & 255) + clocal;
        int hh = colg >> 5, dd = colg & 31;
        int bg = m0 >> 10;
        int m_loc = (m0 & 1023) + q4 * 8;
        int mt64 = m_loc >> 6, ks = (m_loc >> 5) & 1, gg = (m_loc >> 3) & 3;
        int cg = dd >> 4, tlv = dd & 15;
        ushort4 u0 = *(ushort4*)&vtile[clocal][q4 * 8];
        ushort4 u1 = *(ushort4*)&vtile[clocal][q4 * 8 + 4];
        unsigned short* dst = vTb
            + (((size_t)(bg * Hh + hh) * 16 + mt64) * 2048)
            + ((size_t)((ks * 2 + cg) * 16 + tlv) * 32) + gg * 8;
        *(ushort4*)dst = u0;
        *(ushort4*)(dst + 4) = u1;
    }
}

// ---------------- merged attention (blocks 0..511) + h1pre GEMM (512..767) ----------------
__global__ __launch_bounds__(512, 8) void attn_h1_k(
    const unsigned short* __restrict__ q, const unsigned short* __restrict__ k,
    const unsigned short* __restrict__ vT, const float* __restrict__ sph,
    unsigned short* __restrict__ op0,
    const unsigned short* __restrict__ xf, const unsigned short* __restrict__ WcatT,
    const float* __restrict__ x, unsigned short* __restrict__ h1preb,
    float* __restrict__ gsum, float* __restrict__ gsq)
{
    __shared__ float Sph[2][16][132];          // 16896 B
    __shared__ unsigned short Ps[Hh][16][72];  // 18432 B
    float* csum = (float*)&Ps[0][0][0];     // [256], aliased (gemm branch only)
    float* csq  = csum + 256;

    const int blk = blockIdx.x;
    const int t = threadIdx.x;
    const int wave = t >> 6;
    const int lane = t & 63;
    const int tl = lane & 15, g = lane >> 4;

    if (blk < 512) {
        // ---------- attention: 16 q-rows, full m-range, graph pinned to XCD ----------
        const int b  = blk & 7;             // graph == XCD (round-robin dispatch)
        const int n0 = (blk >> 3) * 16;     // 64 row-tiles per graph
        const int w  = wave;

        bf16x8 qf = ldb8(q + ((size_t)(b * Nn + n0 + tl)) * Cc + w * DKh + g * 8);

        float lsum = 0.f;
        f32x4 oacc[2] = {};

        // coalesced fragment bases: lane offset = (tl*4+g)*16B within each 1KB tile
        const unsigned short* kfb = k + ((size_t)(b * 512 + w)) * 512 + tl * 32 + g * 8;
        const unsigned short* vfb = vT + ((size_t)(b * Hh + w) * 16) * 2048
                                     + (size_t)tl * 32 + g * 8;
        const float* sbase = sph + ((size_t)b * Nn + n0) * Nn;

        // prologue: stage sph tile 0 (16x128) into buffer 0; 256 thr x 2 float4
        if (t < 256) {
            int r1 = t >> 4, c1 = (t & 15) * 8;
            const float* src = sbase + (size_t)r1 * Nn + c1;
            *(float4*)&Sph[0][r1][c1]     = *(const float4*)src;
            *(float4*)&Sph[0][r1][c1 + 4] = *(const float4*)(src + 4);
        }
        __syncthreads();

        int cur = 0;
        for (int it = 0; it < 8; ++it) {
            const int m0 = it * 128;
            // stage NEXT 16x128 tile into the other buffer
            if (it < 7 && t < 256) {
                int r1 = t >> 4, c1 = (t & 15) * 8;
                const float* src = sbase + (size_t)r1 * Nn + m0 + 128 + c1;
                *(float4*)&Sph[cur ^ 1][r1][c1]     = *(const float4*)src;
                *(float4*)&Sph[cur ^ 1][r1][c1 + 4] = *(const float4*)(src + 4);
            }

            #pragma unroll
            for (int half = 0; half < 2; ++half) {
                const int mh = m0 + half * 64;

                f32x4 st[4];
                #pragma unroll
                for (int mg = 0; mg < 4; ++mg) {
                    bf16x8 ka = ldb8(kfb + (size_t)((mh >> 4) + mg) * 4096);
                    f32x4 z = {0.f, 0.f, 0.f, 0.f};
                    st[mg] = __builtin_amdgcn_mfma_f32_16x16x32_bf16(ka, qf, z, 0, 0, 0);
                }

                #pragma unroll
                for (int mg = 0; mg < 4; ++mg) {
                    float4 sp = *(const float4*)&Sph[cur][tl][half * 64 + mg * 16 + g * 4];
                    float p0 = __builtin_amdgcn_exp2f(st[mg][0] * sp.x);
                    float p1 = __builtin_amdgcn_exp2f(st[mg][1] * sp.y);
                    float p2 = __builtin_amdgcn_exp2f(st[mg][2] * sp.z);
                    float p3 = __builtin_amdgcn_exp2f(st[mg][3] * sp.w);
                    lsum += (p0 + p1) + (p2 + p3);
                    ushort4 pk;
                    pk.x = f2b(p0); pk.y = f2b(p1); pk.z = f2b(p2); pk.w = f2b(p3);
                    *(ushort4*)&Ps[w][tl][mg * 16 + g * 4] = pk;
                }

                const unsigned short* vtile64 = vfb + (size_t)(mh >> 6) * 2048;
                #pragma unroll
                for (int ks = 0; ks < 2; ++ks) {
                    bf16x8 pa = ldb8(&Ps[w][tl][ks * 32 + g * 8]);
                    #pragma unroll
                    for (int cg = 0; cg < 2; ++cg) {
                        bf16x8 vb = ldb8(vtile64 + (size_t)(ks * 2 + cg) * 512);
                        oacc[cg] = __builtin_amdgcn_mfma_f32_16x16x32_bf16(pa, vb, oacc[cg], 0, 0, 0);
                    }
                }
            }

            __syncthreads();   // staging writes visible; Sph[cur]/Ps reads complete
            cur ^= 1;
        }

        // full-row softmax denominator -> normalize O in-register.
        lsum += __shfl_xor(lsum, 16);
        lsum += __shfl_xor(lsum, 32);      // every lane: sum for q-row tl
        float* shl = (float*)&Ps[w][0][0]; // per-wave scratch (Ps dead now)
        if (g == 0) shl[tl] = lsum;        // wave-local write->read, no barrier
        // O written in fragment layout (KT=8): read coalesced by Wo GEMM.
        const size_t rt = (size_t)((b * Nn + n0) >> 4);
        #pragma unroll
        for (int r = 0; r < 4; ++r) {
            float inv = 1.f / shl[g * 4 + r];   // O row = g*4+r
            #pragma unroll
            for (int cg = 0; cg < 2; ++cg)
                op0[(rt * 8 + w) * 512 + (g * 4 + r) * 32 + cg * 16 + tl]
                    = f2b(oacc[cg][r] * inv);
        }
        return;
    }

    // ---------- h1pre GEMM: one 32x256 tile per block (frag A + frag B) ----------
    const int wrg = wave >> 2;              // 0..1 row group
    const int wcg = wave & 3;               // 0..3 col group (64 cols each)
    const int m0g = (blk - 512) * 32;
    const int N = Cc;

    if (t < 256) { csum[t] = 0.f; csq[t] = 0.f; }
    __syncthreads();

    f32x4 acc[4] = {};

    const unsigned short* a0 = xf + (size_t)((m0g >> 4) + wrg) * 16 * 512 + tl * 32 + g * 8;
    const unsigned short* bb = WcatT + (size_t)(wcg * 4) * 16 * 512 + tl * 32 + g * 8;

    for (int k0 = 0; k0 < 512; k0 += 32) {
        bf16x8 af = ldb8(a0 + (k0 >> 5) * 512);
        #pragma unroll
        for (int c16 = 0; c16 < 4; ++c16) {
            bf16x8 bf = ldb8(bb + ((size_t)c16 * 16 + (k0 >> 5)) * 512);
            acc[c16] = __builtin_amdgcn_mfma_f32_16x16x32_bf16(af, bf, acc[c16], 0, 0, 0);
        }
    }

    #pragma unroll
    for (int c16 = 0; c16 < 4; ++c16) {
        int col = wcg * 64 + c16 * 16 + tl;
        float ls = 0.f, lq = 0.f;
        #pragma unroll
        for (int reg = 0; reg < 4; ++reg) {
            int row = m0g + wrg * 16 + g * 4 + reg;
            size_t idx = (size_t)row * N + col;
            float v = acc[c16][reg] + x[idx];
            ls += v; lq += v * v;               // stats in fp32 (pre-rounding)
            h1preb[idx] = f2b(v);
        }
        atomicAdd(&csum[col], ls);
        atomicAdd(&csq[col],  lq);
    }
    __syncthreads();
    if (t < 256) {
        atomicAdd(&gsum[t], csum[t]);
        atomicAdd(&gsq[t],  csq[t]);
    }
}

// ---------------- mlp1: hid = relu(osb @ W1 + b1), frag A + frag B + frag out ----------------
__global__ __launch_bounds__(256, 4) void mlp1_k(
    const unsigned short* __restrict__ A,      // osb fragment, KT=8
    const unsigned short* __restrict__ WT,     // W1 fragment, KT=8, 512 cols
    const float* __restrict__ bias,
    unsigned short* __restrict__ outb)         // hid fragment, KT=16
{
    const int t = threadIdx.x;
    const int wave = t >> 6, lane = t & 63;
    const int tl = lane & 15, g = lane >> 4;
    const int wr = wave >> 1, wc = wave & 1;
    const int m0 = blockIdx.y * 32, n0 = blockIdx.x * 64;

    f32x4 acc[2] = {};

    const unsigned short* a0 = A  + (size_t)((m0 >> 4) + wr) * 8 * 512 + tl * 32 + g * 8;
    const unsigned short* b0 = WT + ((size_t)(n0 >> 4) + wc * 2) * 8 * 512 + tl * 32 + g * 8;
    const unsigned short* b1 = b0 + 8 * 512;

    for (int k0 = 0; k0 < 256; k0 += 32) {
        bf16x8 af  = ldb8(a0 + (k0 >> 5) * 512);
        bf16x8 bf0 = ldb8(b0 + (k0 >> 5) * 512), bf1 = ldb8(b1 + (k0 >> 5) * 512);
        acc[0] = __builtin_amdgcn_mfma_f32_16x16x32_bf16(af, bf0, acc[0], 0, 0, 0);
        acc[1] = __builtin_amdgcn_mfma_f32_16x16x32_bf16(af, bf1, acc[1], 0, 0, 0);
    }

    const size_t rtO = (size_t)(m0 >> 4) + wr;
    #pragma unroll
    for (int c16 = 0; c16 < 2; ++c16) {
        int col  = n0 + wc * 32 + c16 * 16 + tl;
        int ktO  = col >> 5;
        #pragma unroll
        for (int reg = 0; reg < 4; ++reg) {
            float v = fmaxf(acc[c16][reg] + bias[col], 0.f);
            outb[(rtO * 16 + ktO) * 512 + (g * 4 + reg) * 32 + (col & 31)] = f2b(v);
        }
    }
}

// ---------------- mlp2: out2 = hid @ W2 + b2 + osb, frag A/B/residual + BN3 stats ----------------
__global__ __launch_bounds__(256, 4) void mlp2_k(
    const unsigned short* __restrict__ A,      // hid fragment, KT=16
    const unsigned short* __restrict__ WT,     // W2 fragment, KT=16, 256 cols
    const float* __restrict__ bias,
    const unsigned short* __restrict__ addb,   // osb fragment, KT=8
    float* __restrict__ outf,                  // row-major fp32
    float* __restrict__ gsum, float* __restrict__ gsq)
{
    const int N = Cc;
    const int t = threadIdx.x;
    const int wave = t >> 6, lane = t & 63;
    const int tl = lane & 15, g = lane >> 4;
    const int wr = wave >> 1, wc = wave & 1;
    const int m0 = blockIdx.y * 32, n0 = blockIdx.x * 64;

    __shared__ float csum[64], csq[64];
    if (t < 64) { csum[t] = 0.f; csq[t] = 0.f; }
    __syncthreads();

    f32x4 acc[2] = {};

    const unsigned short* a0 = A  + (size_t)((m0 >> 4) + wr) * 16 * 512 + tl * 32 + g * 8;
    const unsigned short* b0 = WT + ((size_t)(n0 >> 4) + wc * 2) * 16 * 512 + tl * 32 + g * 8;
    const unsigned short* b1 = b0 + 16 * 512;

    for (int k0 = 0; k0 < 512; k0 += 32) {
        bf16x8 af  = ldb8(a0 + (k0 >> 5) * 512);
        bf16x8 bf0 = ldb8(b0 + (k0 >> 5) * 512), bf1 = ldb8(b1 + (k0 >> 5) * 512);
        acc[0] = __builtin_amdgcn_mfma_f32_16x16x32_bf16(af, bf0, acc[0], 0, 0, 0);
        acc[1] = __builtin_amdgcn_mfma_f32_16x16x32_bf16(af, bf1, acc[1], 0, 0, 0);
    }

    const size_t rtR = (size_t)(m0 >> 4) + wr;
    #pragma unroll
    for (int c16 = 0; c16 < 2; ++c16) {
        int colL = wc * 32 + c16 * 16 + tl;
        int col  = n0 + colL;
        int ktR  = col >> 5;
        float ls = 0.f, lq = 0.f;
        #pragma unroll
        for (int reg = 0; reg < 4; ++reg) {
            int row = m0 + wr * 16 + g * 4 + reg;
            float v = acc[c16][reg] + bias[col]
                    + b2f(addb[(rtR * 8 + ktR) * 512 + (g * 4 + reg) * 32 + (col & 31)]);
            ls += v; lq += v * v;
            outf[(size_t)row * N + col] = v;
        }
        atomicAdd(&csum[colL], ls); atomicAdd(&csq[colL], lq);
    }
    __syncthreads();
    if (t < 64) {
        atomicAdd(&gsum[n0 + t], csum[t]);
        atomicAdd(&gsq[n0 + t],  csq[t]);
    }
}

// ---------------- Wo GEMM (A = op0 fragment) + fp32 residual + BN2 stats ----------------
__global__ __launch_bounds__(256, 4) void gemm_attnA_k(
    const unsigned short* __restrict__ op0,    // fragment, KT=8
    const unsigned short* __restrict__ WT, const float* __restrict__ bias,
    const float* __restrict__ add1, unsigned short* __restrict__ h2preb,
    float* __restrict__ gsum, float* __restrict__ gsq)
{
    const int N = Cc;
    const int t = threadIdx.x;
    const int wave = t >> 6, lane = t & 63;
    const int tl = lane & 15, g = lane >> 4;
    const int wr = wave >> 1, wc = wave & 1;
    const int m0 = blockIdx.y * 32, n0 = blockIdx.x * 64;

    __shared__ float csum[64], csq[64];
    if (t < 64) { csum[t] = 0.f; csq[t] = 0.f; }
    __syncthreads();

    f32x4 acc[2] = {};

    const unsigned short* a0b = op0 + (size_t)((m0 >> 4) + wr) * 8 * 512 + tl * 32 + g * 8;
    const unsigned short* b0 = WT + ((size_t)(n0 >> 4) + wc * 2) * 8 * 512 + tl * 32 + g * 8;
    const unsigned short* b1 = b0 + 8 * 512;

    for (int k0 = 0; k0 < 256; k0 += 32) {
        bf16x8 af  = ldb8(a0b + (k0 >> 5) * 512);
        bf16x8 bf0 = ldb8(b0 + (k0 >> 5) * 512), bf1 = ldb8(b1 + (k0 >> 5) * 512);
        acc[0] = __builtin_amdgcn_mfma_f32_16x16x32_bf16(af, bf0, acc[0], 0, 0, 0);
        acc[1] = __builtin_amdgcn_mfma_f32_16x16x32_bf16(af, bf1, acc[1], 0, 0, 0);
    }

    #pragma unroll
    for (int c16 = 0; c16 < 2; ++c16) {
        int colL = wc * 32 + c16 * 16 + tl;
        int col  = n0 + colL;
        float ls = 0.f, lq = 0.f;
        #pragma unroll
        for (int reg = 0; reg < 4; ++reg) {
            int row = m0 + wr * 16 + g * 4 + reg;
            float v = acc[c16][reg] + bias[col];
            size_t idx = (size_t)row * N + col;
            v += add1[idx];
            ls += v; lq += v * v;               // stats in fp32 (pre-rounding)
            h2preb[idx] = f2b(v);
        }
        atomicAdd(&csum[colL], ls); atomicAdd(&csq[colL], lq);
    }
    __syncthreads();
    if (t < 64) {
        atomicAdd(&gsum[n0 + t], csum[t]);
        atomicAdd(&gsq[n0 + t],  csq[t]);
    }
}

// ---------------- BN apply (single, float4) ----------------
__global__ __launch_bounds__(256) void bn_apply_k(
    const float* __restrict__ h, const float* __restrict__ gsum,
    const float* __restrict__ gsq, const float* __restrict__ gamma,
    const float* __restrict__ beta, float* __restrict__ outf)
{
    size_t i4 = ((size_t)blockIdx.x * 256 + threadIdx.x) * 4;
    int ch = (int)(i4 & (Cc - 1));
    float4 hv = *(const float4*)(h + i4);
    float4 sm = *(const float4*)(gsum + ch);
    float4 sq = *(const float4*)(gsq + ch);
    float4 ga = *(const float4*)(gamma + ch);
    float4 be = *(const float4*)(beta + ch);
    float4 o;
    {
        float m = sm.x * (1.f / BNn), var = sq.x * (1.f / BNn) - m * m;
        o.x = (hv.x - m) * rsqrtf(var + EPSV) * ga.x + be.x;
    }
    {
        float m = sm.y * (1.f / BNn), var = sq.y * (1.f / BNn) - m * m;
        o.y = (hv.y - m) * rsqrtf(var + EPSV) * ga.y + be.y;
    }
    {
        float m = sm.z * (1.f / BNn), var = sq.z * (1.f / BNn) - m * m;
        o.z = (hv.z - m) * rsqrtf(var + EPSV) * ga.z + be.z;
    }
    {
        float m = sm.w * (1.f / BNn), var = sq.w * (1.f / BNn) - m * m;
        o.w = (hv.w - m) * rsqrtf(var + EPSV) * ga.w + be.w;
    }
    *(float4*)(outf + i4) = o;
}

// ---------------- fused BN1+BN2 apply -> osb in FRAGMENT layout ----------------
__global__ __launch_bounds__(256) void bn_apply12_k(
    const unsigned short* __restrict__ h1preb, const unsigned short* __restrict__ h2preb,
    const float* __restrict__ stats,
    const float* __restrict__ g1, const float* __restrict__ be1,
    const float* __restrict__ g2, const float* __restrict__ be2,
    unsigned short* __restrict__ outb)         // osb fragment, KT=8
{
    size_t i4 = ((size_t)blockIdx.x * 256 + threadIdx.x) * 4;
    int ch = (int)(i4 & (Cc - 1));
    ushort4 u1 = *(const ushort4*)(h1preb + i4);
    ushort4 u2 = *(const ushort4*)(h2preb + i4);
    float4 s1m = *(const float4*)(stats + ch);
    float4 s1q = *(const float4*)(stats + 256 + ch);
    float4 s2m = *(const float4*)(stats + 512 + ch);
    float4 s2q = *(const float4*)(stats + 768 + ch);
    float4 G1 = *(const float4*)(g1 + ch),  B1 = *(const float4*)(be1 + ch);
    float4 G2 = *(const float4*)(g2 + ch),  B2 = *(const float4*)(be2 + ch);
    ushort4 pk;
    #define BN12C(comp, ucomp) { \
        float m1 = s1m.comp * (1.f / BNn), v1 = s1q.comp * (1.f / BNn) - m1 * m1; \
        float m2 = s2m.comp * (1.f / BNn), v2 = s2q.comp * (1.f / BNn) - m2 * m2; \
        float o = (b2f(u1.ucomp) - m1) * rsqrtf(v1 + EPSV) * G1.comp + B1.comp \
                + (b2f(u2.ucomp) - m2) * rsqrtf(v2 + EPSV) * G2.comp + B2.comp; \
        pk.ucomp = f2b(o); }
    BN12C(x, x) BN12C(y, y) BN12C(z, z) BN12C(w, w)
    #undef BN12C
    int row = (int)(i4 >> 8), col = ch;        // col 4-aligned, stays in one 32-tile
    *(ushort4*)(outb + ((size_t)(row >> 4) * 8 + (col >> 5)) * 512
                + (row & 15) * 32 + (col & 31)) = pk;
}

// ---------------- launch ----------------
extern "C" void kernel_launch(void* const* d_in, const int* in_sizes, int n_in,
                              void* d_out, int out_size, void* d_ws, size_t ws_size,
                              hipStream_t stream)
{
    const float* x   = (const float*)d_in[0];
    const int*   ei  = (const int*)  d_in[1];
    const float* sph = (const float*)d_in[2];
    const float* Wr  = (const float*)d_in[3];
    const float* Wn  = (const float*)d_in[4];
    const float* Wq  = (const float*)d_in[5];
    const float* bq  = (const float*)d_in[6];
    const float* Wk  = (const float*)d_in[7];
    const float* bk  = (const float*)d_in[8];
    const float* Wv  = (const float*)d_in[9];
    const float* bv  = (const float*)d_in[10];
    const float* Wo  = (const float*)d_in[11];
    const float* bo  = (const float*)d_in[12];
    const float* W1  = (const float*)d_in[13];
    const float* b1  = (const float*)d_in[14];
    const float* W2  = (const float*)d_in[15];
    const float* b2  = (const float*)d_in[16];
    const float* g1  = (const float*)d_in[17];
    const float* be1 = (const float*)d_in[18];
    const float* g2  = (const float*)d_in[19];
    const float* be2 = (const float*)d_in[20];
    const float* g3  = (const float*)d_in[21];
    const float* be3 = (const float*)d_in[22];
    float* out = (float*)d_out;

    const size_t SL = (size_t)BNn * Cc;  // 2M elements

    float* ws = (float*)d_ws;
    float* s1 = ws;                  // op0b (bf16 fragment, 4MB)
    float* s2 = s1 + SL;             // h1preb (bf16) then out2 (fp32)
    float* s3 = s2 + SL;             // h2preb (bf16)

    int*   deg      = (int*)(s3 + SL);          // 8192
    float* statsAll = (float*)(deg + 8192);     // 1536
    int*   rowst    = (int*)(statsAll + 1536);  // 8192 (+pad)
    int*   cursor   = rowst + 8256;             // 8192
    int*   eidx     = cursor + 8192;            // 131072

    unsigned short* xf  = (unsigned short*)(eidx + 131072); // fragment [512rt][16kt][16][32]; reused as hid
    unsigned short* qb  = xf + 2 * SL;
    unsigned short* kb  = qb + SL;                           // reused as osb (fragment)
    unsigned short* vTb = kb + SL;
    unsigned short* osb = kb;
    unsigned short* hid = xf;

    unsigned short* WcatT = vTb + SL;         // fragment
    unsigned short* WqT   = WcatT + 131072;   // fragment [768 cols][256 K]
    unsigned short* WkT   = WqT + 65536;
    unsigned short* WvT   = WkT + 65536;
    unsigned short* WoT   = WvT + 65536;
    unsigned short* W1T   = WoT + 65536;
    unsigned short* W2T   = W1T + 131072;
    unsigned short* xlo   = W2T + 131072;     // row-major bf16 x copy [8192][256]
    unsigned short* op0b   = (unsigned short*)s1;
    unsigned short* h1preb = (unsigned short*)s2;   // 4MB of s2; dead before out2
    unsigned short* h2preb = (unsigned short*)s3;

    dim3 gN256(4, 256);
    dim3 gN512(8, 256);

    const float QSCALE = 0.17677669529663687f * 1.4426950408889634f;

    // 1) zero deg + all BN stats in one memset
    hipMemsetAsync(deg, 0, (8192 + 1536) * sizeof(float), stream);
    // 2) fused converts + histogram (fragment weight layouts + xlo copy)
    prep_k<<<5120, 256, 0, stream>>>(x, xf, xlo, Wr, Wn, Wq, Wk, Wv, Wo, W1, W2,
                                     WcatT, WqT, WkT, WvT, WoT, W1T, W2T, ei, deg);
    // 3-4) CSR scan / place
    scan_k<<<1, 256, 0, stream>>>(deg, rowst, cursor);
    place_k<<<Ee / 256, 256, 0, stream>>>(ei, cursor, eidx);
    // 5) gather (xlo -> xf hi kts) || QKV GEMM (frag A/B + frag K/V out)
    gather_qkv_k<<<5120, 256, 0, stream>>>(xlo, rowst, deg, eidx, xf,
                                           WqT, bq, bk, bv, qb, kb, vTb, QSCALE);
    // 6) attention (frag K/V, frag O out) || h1pre GEMM (frag A/B) — 768 blocks
    attn_h1_k<<<768, 512, 0, stream>>>(qb, kb, vTb, sph, op0b,
                                       xf, WcatT, x, h1preb,
                                       statsAll, statsAll + 256);
    // 7) h2pre = O @ Wo + bo + x -> bf16, + BN2 stats (frag A)
    gemm_attnA_k<<<gN256, 256, 0, stream>>>(op0b, WoT, bo, x,
                                            h2preb, statsAll + 512, statsAll + 768);
    // 8) osb(frag) = bn1(h1pre) + bn2(h2pre)
    bn_apply12_k<<<(int)(SL / 1024), 256, 0, stream>>>(h1preb, h2preb, statsAll,
                                                       g1, be1, g2, be2, osb);
    // 9) hid(frag) = relu(osb @ W1 + b1)
    mlp1_k<<<gN512, 256, 0, stream>>>(osb, W1T, b1, hid);
    // 10) out2 = hid @ W2 + b2 + osb(frag residual) -> s2 fp32, + BN3 stats
    mlp2_k<<<gN256, 256, 0, stream>>>(hid, W2T, b2, osb, s2,
                                      statsAll + 1024, statsAll + 1280);
    // 11) d_out = BN3(out2)
    bn_apply_k<<<(int)(SL / 1024), 256, 0, stream>>>(s2, statsAll + 1024,
                                                     statsAll + 1280, g3, be3, out);
}